// Round 1
// baseline (5606.524 us; speedup 1.0000x reference)
//
#include <hip/hip_runtime.h>
#include <math.h>

#define NB   16
#define SS   256
#define DIMV 41
#define NDV  42
#define NKD  128
#define NHD  4
#define DH   32
#define NLAY 3
#define TOT  (SS*NDV)   // 10752, divisible by 256

// ---------------------------------------------------------------------------
// Compaction: stable argsort(-mask_f) truncated to L, per batch.
// Produces tind/cind/mk/uval/uind and writes target_U_ / target_mask_ outputs.
// ---------------------------------------------------------------------------
__global__ __launch_bounds__(256)
void compact_kernel(const float* __restrict__ cx, const float* __restrict__ value,
                    const float* __restrict__ maskp, const float* __restrict__ tval,
                    const float* __restrict__ tmaskp, const float* __restrict__ w0p,
                    const float* __restrict__ b0p, int L,
                    int* __restrict__ tind, int* __restrict__ cind,
                    float* __restrict__ mkb, float* __restrict__ uval,
                    float* __restrict__ uind,
                    float* __restrict__ outTU, float* __restrict__ outTM)
{
    const int b = blockIdx.x;
    const int tid = threadIdx.x;
    const int lane = tid & 63;
    const int wv = tid >> 6;
    __shared__ int redc[4];
    __shared__ int wsum[4];
    __shared__ int s_base;
    const float w0 = w0p[0], b0 = b0p[0];

    // pass A: count valid entries in this batch
    int cl = 0;
    for (int base = 0; base < TOT; base += 256) {
        int idx = base + tid;
        int s = idx / NDV, c = idx % NDV;
        float m = (c < DIMV) ? maskp[((size_t)b*SS + s)*DIMV + c] : 1.0f;
        cl += (m != 0.0f) ? 1 : 0;
    }
    #pragma unroll
    for (int off = 32; off; off >>= 1) cl += __shfl_down(cl, off);
    if (lane == 0) redc[wv] = cl;
    __syncthreads();
    const int cnt = redc[0] + redc[1] + redc[2] + redc[3];
    if (tid == 0) s_base = 0;
    __syncthreads();

    // pass B: stable scatter (valid entries first, then invalid, index order)
    for (int base = 0; base < TOT; base += 256) {
        int idx = base + tid;
        int s = idx / NDV, c = idx % NDV;
        float mval = (c < DIMV) ? maskp[((size_t)b*SS + s)*DIMV + c] : 1.0f;
        int m = (mval != 0.0f) ? 1 : 0;
        // wave-inclusive scan
        int x = m;
        #pragma unroll
        for (int off = 1; off < 64; off <<= 1) {
            int y = __shfl_up(x, off);
            if (lane >= off) x += y;
        }
        if (lane == 63) wsum[wv] = x;
        __syncthreads();
        int wbase = 0;
        for (int w = 0; w < wv; w++) wbase += wsum[w];
        int incl = x + wbase;
        int excl = incl - m;
        int chunk_total = wsum[0] + wsum[1] + wsum[2] + wsum[3];
        int vbase = s_base;
        int valids_before = vbase + excl;
        int pos = m ? valids_before : (cnt + (idx - valids_before));
        if (pos < L) {
            float te = w0 * cx[(size_t)b*SS + s] + b0;
            float vf, tvf, tmf;
            if (c < DIMV) {
                size_t o = ((size_t)b*SS + s)*DIMV + c;
                vf = value[o]; tvf = tval[o]; tmf = tmaskp[o];
            } else { vf = te; tvf = te; tmf = 0.0f; }
            size_t p = (size_t)b*L + pos;
            if (m) {
                tind[p] = s; cind[p] = c; mkb[p] = 1.0f;
                uval[p] = vf; uind[p] = tmf;
                outTU[p] = tvf; outTM[p] = tmf;
            } else {
                tind[p] = 0; cind[p] = 0; mkb[p] = 0.0f;
                uval[p] = 0.0f; uind[p] = 1.0f;
                outTU[p] = 0.0f; outTM[p] = 0.0f;
            }
        }
        __syncthreads();
        if (tid == 0) s_base = vbase + chunk_total;
        __syncthreads();
    }
}

// ---------------------------------------------------------------------------
// Init kernels
// ---------------------------------------------------------------------------
__global__ __launch_bounds__(256)
void initT_kernel(const float* __restrict__ cx, const float* __restrict__ tw,
                  const float* __restrict__ tb, float* __restrict__ T)
{
    int i = blockIdx.x * 256 + threadIdx.x;     // one float4 each
    if (i >= NB*SS*32) return;
    int row = i >> 5;
    int k = (i & 31) << 2;
    float t = cx[row];
    float4 r;
    r.x = sinf(t*tw[k+0] + tb[k+0]);
    r.y = sinf(t*tw[k+1] + tb[k+1]);
    r.z = sinf(t*tw[k+2] + tb[k+2]);
    r.w = sinf(t*tw[k+3] + tb[k+3]);
    *(float4*)(T + (size_t)row*NKD + k) = r;
}

__global__ __launch_bounds__(256)
void initC_kernel(const float* __restrict__ cw, const float* __restrict__ cb,
                  float* __restrict__ C)
{
    int i = blockIdx.x * 256 + threadIdx.x;
    if (i >= NB*NDV*32) return;
    int row = i >> 5;
    int c = row % NDV;
    int k = (i & 31) << 2;
    float4 r;
    r.x = fmaxf(cw[(size_t)c*NKD + k+0] + cb[k+0], 0.f);
    r.y = fmaxf(cw[(size_t)c*NKD + k+1] + cb[k+1], 0.f);
    r.z = fmaxf(cw[(size_t)c*NKD + k+2] + cb[k+2], 0.f);
    r.w = fmaxf(cw[(size_t)c*NKD + k+3] + cb[k+3], 0.f);
    *(float4*)(C + (size_t)row*NKD + k) = r;
}

__global__ __launch_bounds__(256)
void initU_kernel(const float* __restrict__ uval, const float* __restrict__ uind,
                  const float* __restrict__ mkb, const float* __restrict__ ew,
                  const float* __restrict__ eb, float* __restrict__ U, int BL)
{
    int i = blockIdx.x * 256 + threadIdx.x;
    if (i >= BL*32) return;
    int row = i >> 5;
    int k = (i & 31) << 2;
    float uv = uval[row], ui = uind[row], m = mkb[row];
    float4 r;
    r.x = fmaxf(uv*ew[k+0] + ui*ew[NKD+k+0] + eb[k+0], 0.f) * m;
    r.y = fmaxf(uv*ew[k+1] + ui*ew[NKD+k+1] + eb[k+1], 0.f) * m;
    r.z = fmaxf(uv*ew[k+2] + ui*ew[NKD+k+2] + eb[k+2], 0.f) * m;
    r.w = fmaxf(uv*ew[k+3] + ui*ew[NKD+k+3] + eb[k+3], 0.f) * m;
    *(float4*)(U + (size_t)row*NKD + k) = r;
}

// ---------------------------------------------------------------------------
// Gather rows: dst[b,l,:] = src[b, ind[b,l], :]
// ---------------------------------------------------------------------------
__global__ __launch_bounds__(256)
void gather_kernel(const float* __restrict__ src, float* __restrict__ dst,
                   const int* __restrict__ ind, int L, int ns)
{
    size_t i = (size_t)blockIdx.x * 256 + threadIdx.x;
    size_t total = (size_t)NB * L * 32;
    if (i >= total) return;
    size_t row = i >> 5;
    int k = ((int)(i & 31)) << 2;
    int b = (int)(row / L);
    int id = ind[row];
    float4 v = *(const float4*)(src + ((size_t)(b*ns + id))*NKD + k);
    *(float4*)(dst + row*NKD + k) = v;
}

// ---------------------------------------------------------------------------
// GEMM: D[m,n] = epilogue( concat(A0,A1,A2)[m,:] @ W[:,n] + bias[n] )
// N=128 fixed, K = NSEG*128, ldw = 128.
// MODE 0: D = acc + b
// MODE 2: D = A0[m,n] + relu(acc + b)          (MAB2 wo epilogue)
// MODE 3: D = relu(A0[m,n] + acc + b) * mk[m]  (edge-MLP update)
// ---------------------------------------------------------------------------
template<int NSEG, int MODE>
__global__ __launch_bounds__(256)
void gemm_k(const float* __restrict__ A0, const float* __restrict__ A1,
            const float* __restrict__ A2, const float* __restrict__ W,
            const float* __restrict__ bias, float* __restrict__ D,
            int M, const float* __restrict__ mkp)
{
    __shared__ float As[16][68];
    __shared__ __align__(16) float Bs[16][64];
    const int bm = blockIdx.y * 64;
    const int bn = blockIdx.x * 64;
    const int tid = threadIdx.x;
    const int tm = (tid >> 4) << 2;
    const int tn = (tid & 15) << 2;
    float acc[4][4] = {};
    const int K = NSEG * 128;
    for (int k0 = 0; k0 < K; k0 += 16) {
        const float* Ap;
        if (NSEG == 1) Ap = A0;
        else if (NSEG == 2) Ap = (k0 < 128) ? A0 : A1;
        else Ap = (k0 < 128) ? A0 : ((k0 < 256) ? A1 : A2);
        const int ks = k0 & 127;
        {
            const int row = tid >> 2;
            const int col = (tid & 3) << 2;
            const int gm = bm + row;
            float4 av = make_float4(0.f, 0.f, 0.f, 0.f);
            if (gm < M) av = *(const float4*)(Ap + (size_t)gm*NKD + ks + col);
            As[col+0][row] = av.x; As[col+1][row] = av.y;
            As[col+2][row] = av.z; As[col+3][row] = av.w;
        }
        {
            const int row = tid >> 4;
            const int col = (tid & 15) << 2;
            *(float4*)&Bs[row][col] = *(const float4*)(W + (size_t)(k0+row)*NKD + bn + col);
        }
        __syncthreads();
        #pragma unroll
        for (int kk = 0; kk < 16; kk++) {
            float av[4], bv[4];
            #pragma unroll
            for (int i = 0; i < 4; i++) av[i] = As[kk][tm+i];
            #pragma unroll
            for (int j = 0; j < 4; j++) bv[j] = Bs[kk][tn+j];
            #pragma unroll
            for (int i = 0; i < 4; i++)
                #pragma unroll
                for (int j = 0; j < 4; j++)
                    acc[i][j] += av[i] * bv[j];
        }
        __syncthreads();
    }
    #pragma unroll
    for (int i = 0; i < 4; i++) {
        int gm = bm + tm + i;
        if (gm >= M) break;
        #pragma unroll
        for (int j = 0; j < 4; j++) {
            int gn = bn + tn + j;
            float r = acc[i][j] + bias[gn];
            float val;
            if (MODE == 0) val = r;
            else if (MODE == 2) val = A0[(size_t)gm*NKD + gn] + fmaxf(r, 0.f);
            else val = fmaxf(A0[(size_t)gm*NKD + gn] + r, 0.f) * mkp[gm];
            D[(size_t)gm*NKD + gn] = val;
        }
    }
}

// ---------------------------------------------------------------------------
// Attention: o[b,q,h*32+d] = qh + softmax(qh.kh/sqrt(128), mask) @ vh
// one block per (b,h,qrow); scores in dynamic LDS.
// mask: valid iff ind[b,l]==qi && mk[b,l]!=0; ind==nullptr -> no mask.
// ---------------------------------------------------------------------------
__global__ __launch_bounds__(256)
void attn_kernel(const float* __restrict__ q, const float* __restrict__ k,
                 const float* __restrict__ v, float* __restrict__ o,
                 int nq, int nkv, const int* __restrict__ ind,
                 const float* __restrict__ mkp)
{
    extern __shared__ float sm[];
    float* scores = sm;
    float* red = sm + nkv;       // [0..3] max, [4..7] sum, [8..135] o partials
    const int bid = blockIdx.x;
    const int qi = bid % nq;
    const int h = (bid / nq) % NHD;
    const int b = bid / (nq * NHD);
    const int tid = threadIdx.x;
    const int lane = tid & 63;
    const int wv = tid >> 6;
    const float scale = 0.088388347648318447f;   // 1/sqrt(128)

    const float* qrow = q + ((size_t)(b*nq + qi))*NKD + h*DH;
    float qreg[DH];
    #pragma unroll
    for (int d = 0; d < DH; d++) qreg[d] = qrow[d];

    const float* kb = k + (size_t)b*nkv*NKD + h*DH;
    const float* vb = v + (size_t)b*nkv*NKD + h*DH;

    float lmax = -INFINITY;
    for (int l = tid; l < nkv; l += 256) {
        const float* kr = kb + (size_t)l*NKD;
        float s = 0.f;
        #pragma unroll
        for (int d = 0; d < DH; d++) s += qreg[d] * kr[d];
        s *= scale;
        if (ind) {
            bool valid = (ind[(size_t)b*nkv + l] == qi) && (mkp[(size_t)b*nkv + l] != 0.0f);
            if (!valid) s = -1e10f;
        }
        scores[l] = s;
        lmax = fmaxf(lmax, s);
    }
    #pragma unroll
    for (int off = 32; off; off >>= 1) lmax = fmaxf(lmax, __shfl_down(lmax, off));
    if (lane == 0) red[wv] = lmax;
    __syncthreads();
    const float mx = fmaxf(fmaxf(red[0], red[1]), fmaxf(red[2], red[3]));

    float lsum = 0.f;
    float op[DH];
    #pragma unroll
    for (int d = 0; d < DH; d++) op[d] = 0.f;
    for (int l = tid; l < nkv; l += 256) {
        float pw = expf(scores[l] - mx);
        lsum += pw;
        const float* vr = vb + (size_t)l*NKD;
        #pragma unroll
        for (int d = 0; d < DH; d++) op[d] += pw * vr[d];
    }
    #pragma unroll
    for (int off = 32; off; off >>= 1) lsum += __shfl_down(lsum, off);
    if (lane == 0) red[4 + wv] = lsum;
    __syncthreads();
    const float ssum = red[4] + red[5] + red[6] + red[7];

    #pragma unroll
    for (int d = 0; d < DH; d++) {
        #pragma unroll
        for (int off = 32; off; off >>= 1) op[d] += __shfl_down(op[d], off);
    }
    float* ro = red + 8;
    if (lane == 0) {
        #pragma unroll
        for (int d = 0; d < DH; d++) ro[wv*DH + d] = op[d];
    }
    __syncthreads();
    if (tid < DH) {
        float s = ro[tid] + ro[DH + tid] + ro[2*DH + tid] + ro[3*DH + tid];
        o[((size_t)(b*nq + qi))*NKD + h*DH + tid] = qreg[tid] + s / ssum;
    }
}

// ---------------------------------------------------------------------------
// Final head: out[b,l] = concat(U,kt,kc)[b,l,:] @ out_w + out_b   (one wave/row)
// ---------------------------------------------------------------------------
__global__ __launch_bounds__(256)
void out_kernel(const float* __restrict__ U, const float* __restrict__ kt,
                const float* __restrict__ kc, const float* __restrict__ ow,
                const float* __restrict__ obp, float* __restrict__ out, int BL)
{
    int row = blockIdx.x * 4 + (threadIdx.x >> 6);
    int lane = threadIdx.x & 63;
    if (row >= BL) return;
    const float* u = U + (size_t)row*NKD;
    const float* a = kt + (size_t)row*NKD;
    const float* c = kc + (size_t)row*NKD;
    float s = u[lane]*ow[lane]       + u[lane+64]*ow[lane+64]
            + a[lane]*ow[128+lane]   + a[lane+64]*ow[192+lane]
            + c[lane]*ow[256+lane]   + c[lane+64]*ow[320+lane];
    #pragma unroll
    for (int off = 32; off; off >>= 1) s += __shfl_down(s, off);
    if (lane == 0) out[row] = s + obp[0];
}

// ---------------------------------------------------------------------------
extern "C" void kernel_launch(void* const* d_in, const int* in_sizes, int n_in,
                              void* d_out, int out_size, void* d_ws, size_t ws_size,
                              hipStream_t stream)
{
    const float* cx     = (const float*)d_in[0];
    const float* value  = (const float*)d_in[1];
    const float* maskp  = (const float*)d_in[2];
    const float* tval   = (const float*)d_in[3];
    const float* tmaskp = (const float*)d_in[4];
    const float* w0     = (const float*)d_in[5];
    const float* b0     = (const float*)d_in[6];
    const float* edge_w = (const float*)d_in[7];
    const float* edge_b = (const float*)d_in[8];
    const float* chan_w = (const float*)d_in[9];
    const float* chan_b = (const float*)d_in[10];
    const float* time_w = (const float*)d_in[11];
    const float* time_b = (const float*)d_in[12];
    const float* ct_wq = (const float*)d_in[13];
    const float* ct_bq = (const float*)d_in[14];
    const float* ct_wk = (const float*)d_in[15];
    const float* ct_bk = (const float*)d_in[16];
    const float* ct_wv = (const float*)d_in[17];
    const float* ct_bv = (const float*)d_in[18];
    const float* ct_wo = (const float*)d_in[19];
    const float* ct_bo = (const float*)d_in[20];
    const float* tc_wq = (const float*)d_in[21];
    const float* tc_bq = (const float*)d_in[22];
    const float* tc_wk = (const float*)d_in[23];
    const float* tc_bk = (const float*)d_in[24];
    const float* tc_wv = (const float*)d_in[25];
    const float* tc_bv = (const float*)d_in[26];
    const float* tc_wo = (const float*)d_in[27];
    const float* tc_bo = (const float*)d_in[28];
    const float* ca_wq = (const float*)d_in[29];
    const float* ca_bq = (const float*)d_in[30];
    const float* ca_wk = (const float*)d_in[31];
    const float* ca_bk = (const float*)d_in[32];
    const float* ca_wv = (const float*)d_in[33];
    const float* ca_bv = (const float*)d_in[34];
    const float* ca_wo = (const float*)d_in[35];
    const float* ca_bo = (const float*)d_in[36];
    const float* en_w  = (const float*)d_in[37];
    const float* en_b  = (const float*)d_in[38];
    const float* out_w = (const float*)d_in[39];
    const float* out_b = (const float*)d_in[40];

    const int BL = out_size / 3;     // B * full_len
    const int L  = BL / NB;

    char* p = (char*)d_ws;
    auto alloc = [&](size_t n) { char* r = p; p += (n + 255) & ~(size_t)255; return r; };
    int*   tind = (int*)  alloc((size_t)BL*4);
    int*   cind = (int*)  alloc((size_t)BL*4);
    float* mkb  = (float*)alloc((size_t)BL*4);
    float* uval = (float*)alloc((size_t)BL*4);
    float* uind = (float*)alloc((size_t)BL*4);
    float* U    = (float*)alloc((size_t)BL*NKD*4);
    float* Unew = (float*)alloc((size_t)BL*NKD*4);
    float* kt   = (float*)alloc((size_t)BL*NKD*4);
    float* kc   = (float*)alloc((size_t)BL*NKD*4);
    float* Kb   = (float*)alloc((size_t)BL*NKD*4);
    float* Vb   = (float*)alloc((size_t)BL*NKD*4);
    float* T1   = (float*)alloc((size_t)NB*SS*NKD*4);
    float* T2b  = (float*)alloc((size_t)NB*SS*NKD*4);
    float* qT   = (float*)alloc((size_t)NB*SS*NKD*4);
    float* oT   = (float*)alloc((size_t)NB*SS*NKD*4);
    float* C1   = (float*)alloc((size_t)NB*NDV*NKD*4);
    float* C2   = (float*)alloc((size_t)NB*NDV*NKD*4);
    float* qC   = (float*)alloc((size_t)NB*NDV*NKD*4);
    float* kCa  = (float*)alloc((size_t)NB*NDV*NKD*4);
    float* vCa  = (float*)alloc((size_t)NB*NDV*NKD*4);
    float* oC   = (float*)alloc((size_t)NB*NDV*NKD*4);

    float* outMain = (float*)d_out;
    float* outTU = outMain + BL;
    float* outTM = outMain + 2*BL;

    compact_kernel<<<NB, 256, 0, stream>>>(cx, value, maskp, tval, tmaskp, w0, b0, L,
                                           tind, cind, mkb, uval, uind, outTU, outTM);
    initT_kernel<<<(NB*SS*32 + 255)/256, 256, 0, stream>>>(cx, time_w, time_b, T1);
    initC_kernel<<<(NB*NDV*32 + 255)/256, 256, 0, stream>>>(chan_w, chan_b, C1);
    initU_kernel<<<(BL*32 + 255)/256, 256, 0, stream>>>(uval, uind, mkb, edge_w, edge_b, U, BL);

    const int gGather = (int)(((size_t)BL*32 + 255)/256);
    const dim3 gBL(2, (BL + 63)/64);
    const dim3 gC(2, (NB*NDV + 63)/64);
    const dim3 gT(2, (NB*SS + 63)/64);
    const size_t smL  = ((size_t)L + 160)*4;
    const size_t smC  = ((size_t)NDV + 160)*4;

    for (int i = 0; i < NLAY; i++) {
        const size_t wOff = (size_t)i*NKD*NKD, bOff = (size_t)i*NKD;
        const size_t wkOff = (size_t)i*2*NKD*NKD, enOff = (size_t)i*3*NKD*NKD;

        // k_t = gather(T_)
        gather_kernel<<<gGather, 256, 0, stream>>>(T1, kt, tind, L, SS);
        // ct: k,v = concat(k_t,U) @ wk/wv ; q = C_ @ wq
        gemm_k<2,0><<<gBL, 256, 0, stream>>>(kt, U, nullptr, ct_wk + wkOff, ct_bk + bOff, Kb, BL, nullptr);
        gemm_k<2,0><<<gBL, 256, 0, stream>>>(kt, U, nullptr, ct_wv + wkOff, ct_bv + bOff, Vb, BL, nullptr);
        gemm_k<1,0><<<gC, 256, 0, stream>>>(C1, nullptr, nullptr, ct_wq + wOff, ct_bq + bOff, qC, NB*NDV, nullptr);
        attn_kernel<<<NB*NHD*NDV, 256, smL, stream>>>(qC, Kb, Vb, oC, NDV, L, cind, mkb);
        gemm_k<1,2><<<gC, 256, 0, stream>>>(oC, nullptr, nullptr, ct_wo + wOff, ct_bo + bOff, C2, NB*NDV, nullptr);

        // k_c = gather(C_)
        gather_kernel<<<gGather, 256, 0, stream>>>(C1, kc, cind, L, NDV);
        // tc: k,v = concat(k_c,U) @ wk/wv ; q = T_ @ wq
        gemm_k<2,0><<<gBL, 256, 0, stream>>>(kc, U, nullptr, tc_wk + wkOff, tc_bk + bOff, Kb, BL, nullptr);
        gemm_k<2,0><<<gBL, 256, 0, stream>>>(kc, U, nullptr, tc_wv + wkOff, tc_bv + bOff, Vb, BL, nullptr);
        gemm_k<1,0><<<gT, 256, 0, stream>>>(T1, nullptr, nullptr, tc_wq + wOff, tc_bq + bOff, qT, NB*SS, nullptr);
        attn_kernel<<<NB*NHD*SS, 256, smL, stream>>>(qT, Kb, Vb, oT, SS, L, tind, mkb);
        gemm_k<1,2><<<gT, 256, 0, stream>>>(oT, nullptr, nullptr, tc_wo + wOff, tc_bo + bOff, T2b, NB*SS, nullptr);

        // U = relu(U + concat(U,k_t,k_c)@en_w + en_b) * mk
        gemm_k<3,3><<<gBL, 256, 0, stream>>>(U, kt, kc, en_w + enOff, en_b + bOff, Unew, BL, mkb);

        // ca: C_ = mab2(C2, C2)
        gemm_k<1,0><<<gC, 256, 0, stream>>>(C2, nullptr, nullptr, ca_wq + wOff, ca_bq + bOff, qC, NB*NDV, nullptr);
        gemm_k<1,0><<<gC, 256, 0, stream>>>(C2, nullptr, nullptr, ca_wk + wOff, ca_bk + bOff, kCa, NB*NDV, nullptr);
        gemm_k<1,0><<<gC, 256, 0, stream>>>(C2, nullptr, nullptr, ca_wv + wOff, ca_bv + bOff, vCa, NB*NDV, nullptr);
        attn_kernel<<<NB*NHD*NDV, 256, smC, stream>>>(qC, kCa, vCa, oC, NDV, NDV, nullptr, nullptr);
        gemm_k<1,2><<<gC, 256, 0, stream>>>(oC, nullptr, nullptr, ca_wo + wOff, ca_bo + bOff, C1, NB*NDV, nullptr);

        // swap U<->Unew, T1<->T2b
        float* t = U;  U = Unew; Unew = t;
        t = T1; T1 = T2b; T2b = t;
    }

    gather_kernel<<<gGather, 256, 0, stream>>>(T1, kt, tind, L, SS);
    gather_kernel<<<gGather, 256, 0, stream>>>(C1, kc, cind, L, NDV);
    out_kernel<<<(BL + 3)/4, 256, 0, stream>>>(U, kt, kc, out_w, out_b, outMain, BL);
}

// Round 2
// 2313.080 us; speedup vs baseline: 2.4238x; 2.4238x over previous
//
#include <hip/hip_runtime.h>
#include <math.h>

#define NB   16
#define SS   256
#define DIMV 41
#define NDV  42
#define NKD  128
#define NHD  4
#define DH   32
#define NLAY 3
#define TOT  (SS*NDV)   // 10752, divisible by 256

// ---------------------------------------------------------------------------
// Compaction: stable argsort(-mask_f) truncated to L, per batch.
// Padding rows get ind = -1 (sentinel for attention mask); gather clamps to 0.
// ---------------------------------------------------------------------------
__global__ __launch_bounds__(256)
void compact_kernel(const float* __restrict__ cx, const float* __restrict__ value,
                    const float* __restrict__ maskp, const float* __restrict__ tval,
                    const float* __restrict__ tmaskp, const float* __restrict__ w0p,
                    const float* __restrict__ b0p, int L,
                    int* __restrict__ tind, int* __restrict__ cind,
                    float* __restrict__ mkb, float* __restrict__ uval,
                    float* __restrict__ uind,
                    float* __restrict__ outTU, float* __restrict__ outTM)
{
    const int b = blockIdx.x;
    const int tid = threadIdx.x;
    const int lane = tid & 63;
    const int wv = tid >> 6;
    __shared__ int redc[4];
    __shared__ int wsum[4];
    __shared__ int s_base;
    const float w0 = w0p[0], b0 = b0p[0];

    // pass A: count valid entries in this batch
    int cl = 0;
    for (int base = 0; base < TOT; base += 256) {
        int idx = base + tid;
        int s = idx / NDV, c = idx % NDV;
        float m = (c < DIMV) ? maskp[((size_t)b*SS + s)*DIMV + c] : 1.0f;
        cl += (m != 0.0f) ? 1 : 0;
    }
    #pragma unroll
    for (int off = 32; off; off >>= 1) cl += __shfl_down(cl, off);
    if (lane == 0) redc[wv] = cl;
    __syncthreads();
    const int cnt = redc[0] + redc[1] + redc[2] + redc[3];
    if (tid == 0) s_base = 0;
    __syncthreads();

    // pass B: stable scatter (valid entries first, then invalid, index order)
    for (int base = 0; base < TOT; base += 256) {
        int idx = base + tid;
        int s = idx / NDV, c = idx % NDV;
        float mval = (c < DIMV) ? maskp[((size_t)b*SS + s)*DIMV + c] : 1.0f;
        int m = (mval != 0.0f) ? 1 : 0;
        int x = m;
        #pragma unroll
        for (int off = 1; off < 64; off <<= 1) {
            int y = __shfl_up(x, off);
            if (lane >= off) x += y;
        }
        if (lane == 63) wsum[wv] = x;
        __syncthreads();
        int wbase = 0;
        for (int w = 0; w < wv; w++) wbase += wsum[w];
        int incl = x + wbase;
        int excl = incl - m;
        int chunk_total = wsum[0] + wsum[1] + wsum[2] + wsum[3];
        int vbase = s_base;
        int valids_before = vbase + excl;
        int pos = m ? valids_before : (cnt + (idx - valids_before));
        if (pos < L) {
            float te = w0 * cx[(size_t)b*SS + s] + b0;
            float vf, tvf, tmf;
            if (c < DIMV) {
                size_t o = ((size_t)b*SS + s)*DIMV + c;
                vf = value[o]; tvf = tval[o]; tmf = tmaskp[o];
            } else { vf = te; tvf = te; tmf = 0.0f; }
            size_t p = (size_t)b*L + pos;
            if (m) {
                tind[p] = s; cind[p] = c; mkb[p] = 1.0f;
                uval[p] = vf; uind[p] = tmf;
                outTU[p] = tvf; outTM[p] = tmf;
            } else {
                tind[p] = -1; cind[p] = -1; mkb[p] = 0.0f;
                uval[p] = 0.0f; uind[p] = 1.0f;
                outTU[p] = 0.0f; outTM[p] = 0.0f;
            }
        }
        __syncthreads();
        if (tid == 0) s_base = vbase + chunk_total;
        __syncthreads();
    }
}

// ---------------------------------------------------------------------------
// Init kernels
// ---------------------------------------------------------------------------
__global__ __launch_bounds__(256)
void initT_kernel(const float* __restrict__ cx, const float* __restrict__ tw,
                  const float* __restrict__ tb, float* __restrict__ T)
{
    int i = blockIdx.x * 256 + threadIdx.x;
    if (i >= NB*SS*32) return;
    int row = i >> 5;
    int k = (i & 31) << 2;
    float t = cx[row];
    float4 r;
    r.x = sinf(t*tw[k+0] + tb[k+0]);
    r.y = sinf(t*tw[k+1] + tb[k+1]);
    r.z = sinf(t*tw[k+2] + tb[k+2]);
    r.w = sinf(t*tw[k+3] + tb[k+3]);
    *(float4*)(T + (size_t)row*NKD + k) = r;
}

__global__ __launch_bounds__(256)
void initC_kernel(const float* __restrict__ cw, const float* __restrict__ cb,
                  float* __restrict__ C)
{
    int i = blockIdx.x * 256 + threadIdx.x;
    if (i >= NB*NDV*32) return;
    int row = i >> 5;
    int c = row % NDV;
    int k = (i & 31) << 2;
    float4 r;
    r.x = fmaxf(cw[(size_t)c*NKD + k+0] + cb[k+0], 0.f);
    r.y = fmaxf(cw[(size_t)c*NKD + k+1] + cb[k+1], 0.f);
    r.z = fmaxf(cw[(size_t)c*NKD + k+2] + cb[k+2], 0.f);
    r.w = fmaxf(cw[(size_t)c*NKD + k+3] + cb[k+3], 0.f);
    *(float4*)(C + (size_t)row*NKD + k) = r;
}

__global__ __launch_bounds__(256)
void initU_kernel(const float* __restrict__ uval, const float* __restrict__ uind,
                  const float* __restrict__ mkb, const float* __restrict__ ew,
                  const float* __restrict__ eb, float* __restrict__ U, int BL)
{
    int i = blockIdx.x * 256 + threadIdx.x;
    if (i >= BL*32) return;
    int row = i >> 5;
    int k = (i & 31) << 2;
    float uv = uval[row], ui = uind[row], m = mkb[row];
    float4 r;
    r.x = fmaxf(uv*ew[k+0] + ui*ew[NKD+k+0] + eb[k+0], 0.f) * m;
    r.y = fmaxf(uv*ew[k+1] + ui*ew[NKD+k+1] + eb[k+1], 0.f) * m;
    r.z = fmaxf(uv*ew[k+2] + ui*ew[NKD+k+2] + eb[k+2], 0.f) * m;
    r.w = fmaxf(uv*ew[k+3] + ui*ew[NKD+k+3] + eb[k+3], 0.f) * m;
    *(float4*)(U + (size_t)row*NKD + k) = r;
}

// ---------------------------------------------------------------------------
// Gather rows: dst[b,l,:] = src[b, max(ind[b,l],0), :]
// ---------------------------------------------------------------------------
__global__ __launch_bounds__(256)
void gather_kernel(const float* __restrict__ src, float* __restrict__ dst,
                   const int* __restrict__ ind, int L, int ns)
{
    size_t i = (size_t)blockIdx.x * 256 + threadIdx.x;
    size_t total = (size_t)NB * L * 32;
    if (i >= total) return;
    size_t row = i >> 5;
    int k = ((int)(i & 31)) << 2;
    int b = (int)(row / L);
    int id = ind[row];
    if (id < 0) id = 0;
    float4 v = *(const float4*)(src + ((size_t)(b*ns + id))*NKD + k);
    *(float4*)(dst + row*NKD + k) = v;
}

// ---------------------------------------------------------------------------
// GEMM: D[m,n] = epilogue( concat(A0,A1,A2)[m,:] @ W[:,n] + bias[n] )
// ---------------------------------------------------------------------------
template<int NSEG, int MODE>
__global__ __launch_bounds__(256)
void gemm_k(const float* __restrict__ A0, const float* __restrict__ A1,
            const float* __restrict__ A2, const float* __restrict__ W,
            const float* __restrict__ bias, float* __restrict__ D,
            int M, const float* __restrict__ mkp)
{
    __shared__ float As[16][68];
    __shared__ __align__(16) float Bs[16][64];
    const int bm = blockIdx.y * 64;
    const int bn = blockIdx.x * 64;
    const int tid = threadIdx.x;
    const int tm = (tid >> 4) << 2;
    const int tn = (tid & 15) << 2;
    float acc[4][4] = {};
    const int K = NSEG * 128;
    for (int k0 = 0; k0 < K; k0 += 16) {
        const float* Ap;
        if (NSEG == 1) Ap = A0;
        else if (NSEG == 2) Ap = (k0 < 128) ? A0 : A1;
        else Ap = (k0 < 128) ? A0 : ((k0 < 256) ? A1 : A2);
        const int ks = k0 & 127;
        {
            const int row = tid >> 2;
            const int col = (tid & 3) << 2;
            const int gm = bm + row;
            float4 av = make_float4(0.f, 0.f, 0.f, 0.f);
            if (gm < M) av = *(const float4*)(Ap + (size_t)gm*NKD + ks + col);
            As[col+0][row] = av.x; As[col+1][row] = av.y;
            As[col+2][row] = av.z; As[col+3][row] = av.w;
        }
        {
            const int row = tid >> 4;
            const int col = (tid & 15) << 2;
            *(float4*)&Bs[row][col] = *(const float4*)(W + (size_t)(k0+row)*NKD + bn + col);
        }
        __syncthreads();
        #pragma unroll
        for (int kk = 0; kk < 16; kk++) {
            float av[4], bv[4];
            #pragma unroll
            for (int i = 0; i < 4; i++) av[i] = As[kk][tm+i];
            #pragma unroll
            for (int j = 0; j < 4; j++) bv[j] = Bs[kk][tn+j];
            #pragma unroll
            for (int i = 0; i < 4; i++)
                #pragma unroll
                for (int j = 0; j < 4; j++)
                    acc[i][j] += av[i] * bv[j];
        }
        __syncthreads();
    }
    #pragma unroll
    for (int i = 0; i < 4; i++) {
        int gm = bm + tm + i;
        if (gm >= M) break;
        #pragma unroll
        for (int j = 0; j < 4; j++) {
            int gn = bn + tn + j;
            float r = acc[i][j] + bias[gn];
            float val;
            if (MODE == 0) val = r;
            else if (MODE == 2) val = A0[(size_t)gm*NKD + gn] + fmaxf(r, 0.f);
            else val = fmaxf(A0[(size_t)gm*NKD + gn] + r, 0.f) * mkp[gm];
            D[(size_t)gm*NKD + gn] = val;
        }
    }
}

// ---------------------------------------------------------------------------
// Flash-style attention. Block = (b, h, 16-query tile); 4 waves x 4 q-rows.
// K/V staged in LDS in 64-kv chunks; K chunk cached in regs per lane.
// MASKED: valid iff indm[b,l]==qi (padding rows have indm=-1). Per-chunk
// min/max of indm lets waves skip chunks with no candidate queries (tind is
// sorted, so tc skips ~95% of chunks). Online softmax per q-row.
// ---------------------------------------------------------------------------
template<bool MASKED>
__global__ __launch_bounds__(256)
void attn2_kernel(const float* __restrict__ q, const float* __restrict__ k,
                  const float* __restrict__ v, float* __restrict__ o,
                  int nq, int nkv, int nqt, const int* __restrict__ indm)
{
    __shared__ float Ksh[64][36];
    __shared__ float Vsh[64][36];
    __shared__ float Qsh[16][36];
    __shared__ int indsh[64];
    const int bid = blockIdx.x;
    const int qt = bid % nqt;
    const int h = (bid / nqt) % NHD;
    const int b = bid / (nqt * NHD);
    const int tid = threadIdx.x;
    const int lane = tid & 63;
    const int wv = tid >> 6;
    const float scale = 0.088388347648318447f;   // 1/sqrt(128)

    {
        int row = tid >> 4;
        int col = (tid & 15) * 2;
        int qg = qt * 16 + row;
        float2 qv = make_float2(0.f, 0.f);
        if (qg < nq) qv = *(const float2*)(q + ((size_t)(b*nq + qg))*NKD + h*DH + col);
        Qsh[row][col] = qv.x; Qsh[row][col+1] = qv.y;
    }
    float m[4], lsum[4], acc[4];
    #pragma unroll
    for (int r = 0; r < 4; r++) { m[r] = -INFINITY; lsum[r] = 0.f; acc[r] = 0.f; }
    const int q0 = qt*16 + wv*4;
    const int dpos = lane & 31;
    const int kh = lane & 32;

    for (int l0 = 0; l0 < nkv; l0 += 64) {
        __syncthreads();
        {
            int row = tid >> 2;
            int c0 = (tid & 3) * 8;
            int lg = l0 + row;
            float4 k1 = make_float4(0,0,0,0), k2 = k1, v1 = k1, v2 = k1;
            if (lg < nkv) {
                const float* kp = k + ((size_t)(b*nkv + lg))*NKD + h*DH + c0;
                const float* vp = v + ((size_t)(b*nkv + lg))*NKD + h*DH + c0;
                k1 = *(const float4*)kp; k2 = *(const float4*)(kp + 4);
                v1 = *(const float4*)vp; v2 = *(const float4*)(vp + 4);
            }
            *(float4*)&Ksh[row][c0] = k1; *(float4*)&Ksh[row][c0+4] = k2;
            *(float4*)&Vsh[row][c0] = v1; *(float4*)&Vsh[row][c0+4] = v2;
            if (tid < 64) {
                int lg2 = l0 + tid;
                indsh[tid] = (lg2 < nkv) ? (MASKED ? indm[(size_t)b*nkv + lg2] : 0) : -1;
            }
        }
        __syncthreads();
        const int myind = indsh[lane];
        int cmin = 0, cmax = 0;
        if (MASKED) {
            int lo = (myind < 0) ? 0x7fffffff : myind;
            int hi = myind;
            #pragma unroll
            for (int off = 32; off; off >>= 1) {
                lo = min(lo, __shfl_xor(lo, off));
                hi = max(hi, __shfl_xor(hi, off));
            }
            cmin = lo; cmax = hi;
            if (q0 > cmax || q0 + 3 < cmin) continue;   // wave-uniform skip
        }
        float kreg[32];
        #pragma unroll
        for (int j = 0; j < 8; j++)
            *(float4*)&kreg[j*4] = *(const float4*)&Ksh[lane][j*4];
        #pragma unroll
        for (int r = 0; r < 4; r++) {
            int qg = q0 + r;
            if (qg >= nq) break;
            if (MASKED && (qg < cmin || qg > cmax)) continue;
            const int qr = wv*4 + r;
            float dot = 0.f;
            #pragma unroll
            for (int j = 0; j < 8; j++) {
                float4 qv = *(const float4*)&Qsh[qr][j*4];
                dot += kreg[j*4+0]*qv.x + kreg[j*4+1]*qv.y
                     + kreg[j*4+2]*qv.z + kreg[j*4+3]*qv.w;
            }
            bool valid = MASKED ? (myind == qg) : (myind >= 0);
            float s = valid ? dot * scale : -1e10f;
            float smax = s;
            #pragma unroll
            for (int off = 32; off; off >>= 1) smax = fmaxf(smax, __shfl_xor(smax, off));
            float m1 = fmaxf(m[r], smax);
            float alpha = __expf(m[r] - m1);
            m[r] = m1;
            float p = __expf(s - m1);
            float psum = p;
            #pragma unroll
            for (int off = 32; off; off >>= 1) psum += __shfl_xor(psum, off);
            lsum[r] = lsum[r]*alpha + psum;
            float a = acc[r]*alpha;
            #pragma unroll
            for (int j = 0; j < 32; j++) {
                float pj = __shfl(p, kh + j);
                a += pj * Vsh[kh + j][dpos];
            }
            acc[r] = a;
        }
    }
    #pragma unroll
    for (int r = 0; r < 4; r++) {
        int qg = q0 + r;
        if (qg >= nq) break;
        float af = acc[r] + __shfl_down(acc[r], 32);
        if (lane < 32) {
            float res = (lsum[r] > 0.f) ? af / lsum[r] : 0.f;
            o[((size_t)(b*nq + qg))*NKD + h*DH + lane] = Qsh[wv*4+r][lane] + res;
        }
    }
}

// ---------------------------------------------------------------------------
// Final head
// ---------------------------------------------------------------------------
__global__ __launch_bounds__(256)
void out_kernel(const float* __restrict__ U, const float* __restrict__ kt,
                const float* __restrict__ kc, const float* __restrict__ ow,
                const float* __restrict__ obp, float* __restrict__ out, int BL)
{
    int row = blockIdx.x * 4 + (threadIdx.x >> 6);
    int lane = threadIdx.x & 63;
    if (row >= BL) return;
    const float* u = U + (size_t)row*NKD;
    const float* a = kt + (size_t)row*NKD;
    const float* c = kc + (size_t)row*NKD;
    float s = u[lane]*ow[lane]       + u[lane+64]*ow[lane+64]
            + a[lane]*ow[128+lane]   + a[lane+64]*ow[192+lane]
            + c[lane]*ow[256+lane]   + c[lane+64]*ow[320+lane];
    #pragma unroll
    for (int off = 32; off; off >>= 1) s += __shfl_down(s, off);
    if (lane == 0) out[row] = s + obp[0];
}

// ---------------------------------------------------------------------------
extern "C" void kernel_launch(void* const* d_in, const int* in_sizes, int n_in,
                              void* d_out, int out_size, void* d_ws, size_t ws_size,
                              hipStream_t stream)
{
    const float* cx     = (const float*)d_in[0];
    const float* value  = (const float*)d_in[1];
    const float* maskp  = (const float*)d_in[2];
    const float* tval   = (const float*)d_in[3];
    const float* tmaskp = (const float*)d_in[4];
    const float* w0     = (const float*)d_in[5];
    const float* b0     = (const float*)d_in[6];
    const float* edge_w = (const float*)d_in[7];
    const float* edge_b = (const float*)d_in[8];
    const float* chan_w = (const float*)d_in[9];
    const float* chan_b = (const float*)d_in[10];
    const float* time_w = (const float*)d_in[11];
    const float* time_b = (const float*)d_in[12];
    const float* ct_wq = (const float*)d_in[13];
    const float* ct_bq = (const float*)d_in[14];
    const float* ct_wk = (const float*)d_in[15];
    const float* ct_bk = (const float*)d_in[16];
    const float* ct_wv = (const float*)d_in[17];
    const float* ct_bv = (const float*)d_in[18];
    const float* ct_wo = (const float*)d_in[19];
    const float* ct_bo = (const float*)d_in[20];
    const float* tc_wq = (const float*)d_in[21];
    const float* tc_bq = (const float*)d_in[22];
    const float* tc_wk = (const float*)d_in[23];
    const float* tc_bk = (const float*)d_in[24];
    const float* tc_wv = (const float*)d_in[25];
    const float* tc_bv = (const float*)d_in[26];
    const float* tc_wo = (const float*)d_in[27];
    const float* tc_bo = (const float*)d_in[28];
    const float* ca_wq = (const float*)d_in[29];
    const float* ca_bq = (const float*)d_in[30];
    const float* ca_wk = (const float*)d_in[31];
    const float* ca_bk = (const float*)d_in[32];
    const float* ca_wv = (const float*)d_in[33];
    const float* ca_bv = (const float*)d_in[34];
    const float* ca_wo = (const float*)d_in[35];
    const float* ca_bo = (const float*)d_in[36];
    const float* en_w  = (const float*)d_in[37];
    const float* en_b  = (const float*)d_in[38];
    const float* out_w = (const float*)d_in[39];
    const float* out_b = (const float*)d_in[40];

    const int BL = out_size / 3;     // B * full_len
    const int L  = BL / NB;

    char* p = (char*)d_ws;
    auto alloc = [&](size_t n) { char* r = p; p += (n + 255) & ~(size_t)255; return r; };
    int*   tind = (int*)  alloc((size_t)BL*4);
    int*   cind = (int*)  alloc((size_t)BL*4);
    float* mkb  = (float*)alloc((size_t)BL*4);
    float* uval = (float*)alloc((size_t)BL*4);
    float* uind = (float*)alloc((size_t)BL*4);
    float* U    = (float*)alloc((size_t)BL*NKD*4);
    float* Unew = (float*)alloc((size_t)BL*NKD*4);
    float* kt   = (float*)alloc((size_t)BL*NKD*4);
    float* kc   = (float*)alloc((size_t)BL*NKD*4);
    float* Kb   = (float*)alloc((size_t)BL*NKD*4);
    float* Vb   = (float*)alloc((size_t)BL*NKD*4);
    float* T1   = (float*)alloc((size_t)NB*SS*NKD*4);
    float* T2b  = (float*)alloc((size_t)NB*SS*NKD*4);
    float* qT   = (float*)alloc((size_t)NB*SS*NKD*4);
    float* oT   = (float*)alloc((size_t)NB*SS*NKD*4);
    float* C1   = (float*)alloc((size_t)NB*NDV*NKD*4);
    float* C2   = (float*)alloc((size_t)NB*NDV*NKD*4);
    float* qC   = (float*)alloc((size_t)NB*NDV*NKD*4);
    float* kCa  = (float*)alloc((size_t)NB*NDV*NKD*4);
    float* vCa  = (float*)alloc((size_t)NB*NDV*NKD*4);
    float* oC   = (float*)alloc((size_t)NB*NDV*NKD*4);

    float* outMain = (float*)d_out;
    float* outTU = outMain + BL;
    float* outTM = outMain + 2*BL;

    compact_kernel<<<NB, 256, 0, stream>>>(cx, value, maskp, tval, tmaskp, w0, b0, L,
                                           tind, cind, mkb, uval, uind, outTU, outTM);
    initT_kernel<<<(NB*SS*32 + 255)/256, 256, 0, stream>>>(cx, time_w, time_b, T1);
    initC_kernel<<<(NB*NDV*32 + 255)/256, 256, 0, stream>>>(chan_w, chan_b, C1);
    initU_kernel<<<(BL*32 + 255)/256, 256, 0, stream>>>(uval, uind, mkb, edge_w, edge_b, U, BL);

    const int gGather = (int)(((size_t)BL*32 + 255)/256);
    const dim3 gBL(2, (BL + 63)/64);
    const dim3 gC(2, (NB*NDV + 63)/64);
    const dim3 gT(2, (NB*SS + 63)/64);
    const int qtC = (NDV + 15)/16;   // 3
    const int qtT = SS/16;           // 16

    for (int i = 0; i < NLAY; i++) {
        const size_t wOff = (size_t)i*NKD*NKD, bOff = (size_t)i*NKD;
        const size_t wkOff = (size_t)i*2*NKD*NKD, enOff = (size_t)i*3*NKD*NKD;

        // k_t = gather(T_)
        gather_kernel<<<gGather, 256, 0, stream>>>(T1, kt, tind, L, SS);
        // ct: k,v = concat(k_t,U) @ wk/wv ; q = C_ @ wq
        gemm_k<2,0><<<gBL, 256, 0, stream>>>(kt, U, nullptr, ct_wk + wkOff, ct_bk + bOff, Kb, BL, nullptr);
        gemm_k<2,0><<<gBL, 256, 0, stream>>>(kt, U, nullptr, ct_wv + wkOff, ct_bv + bOff, Vb, BL, nullptr);
        gemm_k<1,0><<<gC, 256, 0, stream>>>(C1, nullptr, nullptr, ct_wq + wOff, ct_bq + bOff, qC, NB*NDV, nullptr);
        attn2_kernel<true><<<NB*NHD*qtC, 256, 0, stream>>>(qC, Kb, Vb, oC, NDV, L, qtC, cind);
        gemm_k<1,2><<<gC, 256, 0, stream>>>(oC, nullptr, nullptr, ct_wo + wOff, ct_bo + bOff, C2, NB*NDV, nullptr);

        // k_c = gather(C_)
        gather_kernel<<<gGather, 256, 0, stream>>>(C1, kc, cind, L, NDV);
        // tc: k,v = concat(k_c,U) @ wk/wv ; q = T_ @ wq
        gemm_k<2,0><<<gBL, 256, 0, stream>>>(kc, U, nullptr, tc_wk + wkOff, tc_bk + bOff, Kb, BL, nullptr);
        gemm_k<2,0><<<gBL, 256, 0, stream>>>(kc, U, nullptr, tc_wv + wkOff, tc_bv + bOff, Vb, BL, nullptr);
        gemm_k<1,0><<<gT, 256, 0, stream>>>(T1, nullptr, nullptr, tc_wq + wOff, tc_bq + bOff, qT, NB*SS, nullptr);
        attn2_kernel<true><<<NB*NHD*qtT, 256, 0, stream>>>(qT, Kb, Vb, oT, SS, L, qtT, tind);
        gemm_k<1,2><<<gT, 256, 0, stream>>>(oT, nullptr, nullptr, tc_wo + wOff, tc_bo + bOff, T2b, NB*SS, nullptr);

        // U = relu(U + concat(U,k_t,k_c)@en_w + en_b) * mk
        gemm_k<3,3><<<gBL, 256, 0, stream>>>(U, kt, kc, en_w + enOff, en_b + bOff, Unew, BL, mkb);

        // ca: C_ = mab2(C2, C2)
        gemm_k<1,0><<<gC, 256, 0, stream>>>(C2, nullptr, nullptr, ca_wq + wOff, ca_bq + bOff, qC, NB*NDV, nullptr);
        gemm_k<1,0><<<gC, 256, 0, stream>>>(C2, nullptr, nullptr, ca_wk + wOff, ca_bk + bOff, kCa, NB*NDV, nullptr);
        gemm_k<1,0><<<gC, 256, 0, stream>>>(C2, nullptr, nullptr, ca_wv + wOff, ca_bv + bOff, vCa, NB*NDV, nullptr);
        attn2_kernel<false><<<NB*NHD*qtC, 256, 0, stream>>>(qC, kCa, vCa, oC, NDV, NDV, qtC, nullptr);
        gemm_k<1,2><<<gC, 256, 0, stream>>>(oC, nullptr, nullptr, ca_wo + wOff, ca_bo + bOff, C1, NB*NDV, nullptr);

        float* t = U;  U = Unew; Unew = t;
        t = T1; T1 = T2b; T2b = t;
    }

    gather_kernel<<<gGather, 256, 0, stream>>>(T1, kt, tind, L, SS);
    gather_kernel<<<gGather, 256, 0, stream>>>(C1, kc, cind, L, NDV);
    out_kernel<<<(BL + 3)/4, 256, 0, stream>>>(U, kt, kc, out_w, out_b, outMain, BL);
}

// Round 3
// 1054.461 us; speedup vs baseline: 5.3170x; 2.1936x over previous
//
#include <hip/hip_runtime.h>
#include <math.h>

#define NB   16
#define SS   256
#define DIMV 41
#define NDV  42
#define NKD  128
#define NHD  4
#define DH   32
#define NLAY 3
#define TOT  (SS*NDV)   // 10752, divisible by 256

typedef __attribute__((ext_vector_type(8))) short short8;
typedef __attribute__((ext_vector_type(4))) float floatx4;

__device__ __forceinline__ short f2bf(float x) {
    unsigned u = __float_as_uint(x);
    u += 0x7fff + ((u >> 16) & 1);          // RNE f32 -> bf16
    return (short)(u >> 16);
}

// ---------------------------------------------------------------------------
// Compaction: stable argsort(-mask_f) truncated to L, per batch.
// Padding rows get ind = -1 sentinel.
// ---------------------------------------------------------------------------
__global__ __launch_bounds__(256)
void compact_kernel(const float* __restrict__ cx, const float* __restrict__ value,
                    const float* __restrict__ maskp, const float* __restrict__ tval,
                    const float* __restrict__ tmaskp, const float* __restrict__ w0p,
                    const float* __restrict__ b0p, int L,
                    int* __restrict__ tind, int* __restrict__ cind,
                    float* __restrict__ mkb, float* __restrict__ uval,
                    float* __restrict__ uind,
                    float* __restrict__ outTU, float* __restrict__ outTM)
{
    const int b = blockIdx.x;
    const int tid = threadIdx.x;
    const int lane = tid & 63;
    const int wv = tid >> 6;
    __shared__ int redc[4];
    __shared__ int wsum[4];
    __shared__ int s_base;
    const float w0 = w0p[0], b0 = b0p[0];

    int cl = 0;
    for (int base = 0; base < TOT; base += 256) {
        int idx = base + tid;
        int s = idx / NDV, c = idx % NDV;
        float m = (c < DIMV) ? maskp[((size_t)b*SS + s)*DIMV + c] : 1.0f;
        cl += (m != 0.0f) ? 1 : 0;
    }
    #pragma unroll
    for (int off = 32; off; off >>= 1) cl += __shfl_down(cl, off);
    if (lane == 0) redc[wv] = cl;
    __syncthreads();
    const int cnt = redc[0] + redc[1] + redc[2] + redc[3];
    if (tid == 0) s_base = 0;
    __syncthreads();

    for (int base = 0; base < TOT; base += 256) {
        int idx = base + tid;
        int s = idx / NDV, c = idx % NDV;
        float mval = (c < DIMV) ? maskp[((size_t)b*SS + s)*DIMV + c] : 1.0f;
        int m = (mval != 0.0f) ? 1 : 0;
        int x = m;
        #pragma unroll
        for (int off = 1; off < 64; off <<= 1) {
            int y = __shfl_up(x, off);
            if (lane >= off) x += y;
        }
        if (lane == 63) wsum[wv] = x;
        __syncthreads();
        int wbase = 0;
        for (int w = 0; w < wv; w++) wbase += wsum[w];
        int incl = x + wbase;
        int excl = incl - m;
        int chunk_total = wsum[0] + wsum[1] + wsum[2] + wsum[3];
        int vbase = s_base;
        int valids_before = vbase + excl;
        int pos = m ? valids_before : (cnt + (idx - valids_before));
        if (pos < L) {
            float te = w0 * cx[(size_t)b*SS + s] + b0;
            float vf, tvf, tmf;
            if (c < DIMV) {
                size_t o = ((size_t)b*SS + s)*DIMV + c;
                vf = value[o]; tvf = tval[o]; tmf = tmaskp[o];
            } else { vf = te; tvf = te; tmf = 0.0f; }
            size_t p = (size_t)b*L + pos;
            if (m) {
                tind[p] = s; cind[p] = c; mkb[p] = 1.0f;
                uval[p] = vf; uind[p] = tmf;
                outTU[p] = tvf; outTM[p] = tmf;
            } else {
                tind[p] = -1; cind[p] = -1; mkb[p] = 0.0f;
                uval[p] = 0.0f; uind[p] = 1.0f;
                outTU[p] = 0.0f; outTM[p] = 0.0f;
            }
        }
        __syncthreads();
        if (tid == 0) s_base = vbase + chunk_total;
        __syncthreads();
    }
}

// ---------------------------------------------------------------------------
// Segment range construction
// ---------------------------------------------------------------------------
__global__ __launch_bounds__(256)
void zero_ranges(int* __restrict__ lo_t, int* __restrict__ hi_t)
{
    int i = blockIdx.x*256 + threadIdx.x;
    if (i < NB*SS) { lo_t[i] = 0; hi_t[i] = 0; }
}

__global__ __launch_bounds__(256)
void trange_kernel(const int* __restrict__ tind, int* __restrict__ lo_t,
                   int* __restrict__ hi_t, int L)
{
    int p = blockIdx.x*256 + threadIdx.x;
    if (p >= NB*L) return;
    int b = p / L, l = p - b*L;
    int t = tind[p];
    if (t < 0) return;
    int tp = (l > 0) ? tind[p-1] : -999;
    int tn = (l+1 < L) ? tind[p+1] : -999;
    if (tp != t) lo_t[b*SS + t] = l;
    if (tn != t) hi_t[b*SS + t] = l+1;
}

// counting-sort rows by channel (order within a class is irrelevant: softmax
// is permutation-invariant). Produces perm + per-channel [clo,chi).
__global__ __launch_bounds__(256)
void cperm_kernel(const int* __restrict__ cind, int* __restrict__ perm,
                  int* __restrict__ clo, int* __restrict__ chi, int L)
{
    __shared__ int hist[NDV];
    __shared__ int base[NDV];
    const int b = blockIdx.x, tid = threadIdx.x;
    if (tid < NDV) hist[tid] = 0;
    __syncthreads();
    for (int l = tid; l < L; l += 256) {
        int c = cind[(size_t)b*L + l];
        if (c >= 0) atomicAdd(&hist[c], 1);
    }
    __syncthreads();
    if (tid == 0) {
        int run = 0;
        for (int c = 0; c < NDV; c++) {
            base[c] = run; clo[b*NDV + c] = run;
            run += hist[c]; chi[b*NDV + c] = run;
        }
    }
    __syncthreads();
    if (tid < NDV) hist[tid] = 0;
    __syncthreads();
    for (int l = tid; l < L; l += 256) {
        int c = cind[(size_t)b*L + l];
        if (c >= 0) {
            int pos = base[c] + atomicAdd(&hist[c], 1);
            perm[(size_t)b*L + pos] = l;
        }
    }
}

// ---------------------------------------------------------------------------
// Init kernels
// ---------------------------------------------------------------------------
__global__ __launch_bounds__(256)
void initT_kernel(const float* __restrict__ cx, const float* __restrict__ tw,
                  const float* __restrict__ tb, float* __restrict__ T)
{
    int i = blockIdx.x * 256 + threadIdx.x;
    if (i >= NB*SS*32) return;
    int row = i >> 5;
    int k = (i & 31) << 2;
    float t = cx[row];
    float4 r;
    r.x = sinf(t*tw[k+0] + tb[k+0]);
    r.y = sinf(t*tw[k+1] + tb[k+1]);
    r.z = sinf(t*tw[k+2] + tb[k+2]);
    r.w = sinf(t*tw[k+3] + tb[k+3]);
    *(float4*)(T + (size_t)row*NKD + k) = r;
}

__global__ __launch_bounds__(256)
void initC_kernel(const float* __restrict__ cw, const float* __restrict__ cb,
                  float* __restrict__ C)
{
    int i = blockIdx.x * 256 + threadIdx.x;
    if (i >= NB*NDV*32) return;
    int row = i >> 5;
    int c = row % NDV;
    int k = (i & 31) << 2;
    float4 r;
    r.x = fmaxf(cw[(size_t)c*NKD + k+0] + cb[k+0], 0.f);
    r.y = fmaxf(cw[(size_t)c*NKD + k+1] + cb[k+1], 0.f);
    r.z = fmaxf(cw[(size_t)c*NKD + k+2] + cb[k+2], 0.f);
    r.w = fmaxf(cw[(size_t)c*NKD + k+3] + cb[k+3], 0.f);
    *(float4*)(C + (size_t)row*NKD + k) = r;
}

__global__ __launch_bounds__(256)
void initU_kernel(const float* __restrict__ uval, const float* __restrict__ uind,
                  const float* __restrict__ mkb, const float* __restrict__ ew,
                  const float* __restrict__ eb, float* __restrict__ U, int BL)
{
    int i = blockIdx.x * 256 + threadIdx.x;
    if (i >= BL*32) return;
    int row = i >> 5;
    int k = (i & 31) << 2;
    float uv = uval[row], ui = uind[row], m = mkb[row];
    float4 r;
    r.x = fmaxf(uv*ew[k+0] + ui*ew[NKD+k+0] + eb[k+0], 0.f) * m;
    r.y = fmaxf(uv*ew[k+1] + ui*ew[NKD+k+1] + eb[k+1], 0.f) * m;
    r.z = fmaxf(uv*ew[k+2] + ui*ew[NKD+k+2] + eb[k+2], 0.f) * m;
    r.w = fmaxf(uv*ew[k+3] + ui*ew[NKD+k+3] + eb[k+3], 0.f) * m;
    *(float4*)(U + (size_t)row*NKD + k) = r;
}

// ---------------------------------------------------------------------------
// Gather rows: dst[b,l,:] = src[b, max(ind[b,l],0), :]
// ---------------------------------------------------------------------------
__global__ __launch_bounds__(256)
void gather_kernel(const float* __restrict__ src, float* __restrict__ dst,
                   const int* __restrict__ ind, int L, int ns)
{
    size_t i = (size_t)blockIdx.x * 256 + threadIdx.x;
    size_t total = (size_t)NB * L * 32;
    if (i >= total) return;
    size_t row = i >> 5;
    int k = ((int)(i & 31)) << 2;
    int b = (int)(row / L);
    int id = ind[row];
    if (id < 0) id = 0;
    float4 v = *(const float4*)(src + ((size_t)(b*ns + id))*NKD + k);
    *(float4*)(dst + row*NKD + k) = v;
}

// ---------------------------------------------------------------------------
// Weight prep: f32 [NL][K][128] -> bf16 transposed [NL][128][K] arena
// ---------------------------------------------------------------------------
template<int Kg>
__device__ __forceinline__ void prep1(const float* __restrict__ src,
                                      short* __restrict__ dst, int rel)
{
    const int per = Kg*128;
    int i = rel / per; int r2 = rel - i*per;
    int n = r2 / Kg;   int k = r2 - n*Kg;
    dst[rel] = f2bf(src[(size_t)i*per + (size_t)k*128 + n]);
}

#define W_TOTAL 933888
__global__ __launch_bounds__(256)
void prep_weights(const float* ctq, const float* ctk, const float* ctv, const float* cto,
                  const float* tcq, const float* tck, const float* tcv, const float* tco,
                  const float* caq, const float* cak, const float* cav, const float* cao,
                  const float* enw, short* __restrict__ arena)
{
    int idx = blockIdx.x*256 + threadIdx.x;
    if (idx >= W_TOTAL) return;
    if      (idx < 49152 ) prep1<128>(ctq, arena + 0,      idx - 0);
    else if (idx < 147456) prep1<256>(ctk, arena + 49152,  idx - 49152);
    else if (idx < 245760) prep1<256>(ctv, arena + 147456, idx - 147456);
    else if (idx < 294912) prep1<128>(cto, arena + 245760, idx - 245760);
    else if (idx < 344064) prep1<128>(tcq, arena + 294912, idx - 294912);
    else if (idx < 442368) prep1<256>(tck, arena + 344064, idx - 344064);
    else if (idx < 540672) prep1<256>(tcv, arena + 442368, idx - 442368);
    else if (idx < 589824) prep1<128>(tco, arena + 540672, idx - 540672);
    else if (idx < 638976) prep1<128>(caq, arena + 589824, idx - 589824);
    else if (idx < 688128) prep1<128>(cak, arena + 638976, idx - 638976);
    else if (idx < 737280) prep1<128>(cav, arena + 688128, idx - 688128);
    else if (idx < 786432) prep1<128>(cao, arena + 737280, idx - 737280);
    else                   prep1<384>(enw, arena + 786432, idx - 786432);
}

// ---------------------------------------------------------------------------
// MFMA GEMM: D[m,n] = epilogue( concat(A0,A1,A2)[m,:] @ W[:,n] + bias[n] )
// A: f32 (cvt to bf16 during staging); Wt: bf16, pre-transposed [128 n][K k].
// Block tile 128m x 128n; 4 waves x (32m x 128n); K-step 32.
// MODE 0: D = acc + b
// MODE 2: D = A0[m,n] + relu(acc + b)
// MODE 3: D = relu(A0[m,n] + acc + b) * mk[m]
// ---------------------------------------------------------------------------
template<int NSEG, int MODE>
__global__ __launch_bounds__(256)
void mgemm(const float* __restrict__ A0, const float* __restrict__ A1,
           const float* __restrict__ A2, const short* __restrict__ Wt,
           const float* __restrict__ bias, float* __restrict__ D,
           int M, const float* __restrict__ mkp)
{
    __shared__ short As[128][40];
    __shared__ short Bs[128][40];
    const int bm = blockIdx.x * 128;
    const int tid = threadIdx.x;
    const int wv = tid >> 6;
    const int lane = tid & 63;
    const int quad = lane >> 4;
    const int l16 = lane & 15;
    const int K = NSEG * 128;
    floatx4 acc[2][8];
    #pragma unroll
    for (int i = 0; i < 2; i++)
        #pragma unroll
        for (int j = 0; j < 8; j++) acc[i][j] = (floatx4){0.f,0.f,0.f,0.f};

    for (int k0 = 0; k0 < K; k0 += 32) {
        // stage A: 128 rows x 32 k (f32 -> bf16)
        {
            const float* Ap;
            if (NSEG == 1) Ap = A0;
            else if (NSEG == 2) Ap = (k0 < 128) ? A0 : A1;
            else Ap = (k0 < 128) ? A0 : ((k0 < 256) ? A1 : A2);
            const int ks = k0 & 127;
            int row = tid >> 1;
            int col = (tid & 1) * 16;
            int gm = bm + row;
            float4 a0 = {0,0,0,0}, a1 = a0, a2 = a0, a3 = a0;
            if (gm < M) {
                const float* src = Ap + (size_t)gm*NKD + ks + col;
                a0 = *(const float4*)(src);    a1 = *(const float4*)(src+4);
                a2 = *(const float4*)(src+8);  a3 = *(const float4*)(src+12);
            }
            short8 p0, p1;
            p0[0]=f2bf(a0.x); p0[1]=f2bf(a0.y); p0[2]=f2bf(a0.z); p0[3]=f2bf(a0.w);
            p0[4]=f2bf(a1.x); p0[5]=f2bf(a1.y); p0[6]=f2bf(a1.z); p0[7]=f2bf(a1.w);
            p1[0]=f2bf(a2.x); p1[1]=f2bf(a2.y); p1[2]=f2bf(a2.z); p1[3]=f2bf(a2.w);
            p1[4]=f2bf(a3.x); p1[5]=f2bf(a3.y); p1[6]=f2bf(a3.z); p1[7]=f2bf(a3.w);
            *(short8*)&As[row][col]   = p0;
            *(short8*)&As[row][col+8] = p1;
        }
        // stage B: Bs[n][kk] = Wt[n*K + k0 + kk]
        {
            int n = tid >> 1;
            int col = (tid & 1) * 16;
            const short* src = Wt + (size_t)n*K + k0 + col;
            *(short8*)&Bs[n][col]   = *(const short8*)(src);
            *(short8*)&Bs[n][col+8] = *(const short8*)(src+8);
        }
        __syncthreads();
        short8 af0 = *(short8*)&As[wv*32 + l16][quad*8];
        short8 af1 = *(short8*)&As[wv*32 + 16 + l16][quad*8];
        #pragma unroll
        for (int nf = 0; nf < 8; nf++) {
            short8 bf = *(short8*)&Bs[nf*16 + l16][quad*8];
            acc[0][nf] = __builtin_amdgcn_mfma_f32_16x16x32_bf16(af0, bf, acc[0][nf], 0, 0, 0);
            acc[1][nf] = __builtin_amdgcn_mfma_f32_16x16x32_bf16(af1, bf, acc[1][nf], 0, 0, 0);
        }
        __syncthreads();
    }
    // epilogue: D row = quad*4+reg, col = l16
    #pragma unroll
    for (int mf = 0; mf < 2; mf++) {
        #pragma unroll
        for (int r = 0; r < 4; r++) {
            int gm = bm + wv*32 + mf*16 + quad*4 + r;
            if (gm < M) {
                float resid = 0.f, mk = 0.f;
                if (MODE == 2 || MODE == 3) resid = 0.f;  // loaded per nf below
                if (MODE == 3) mk = mkp[gm];
                #pragma unroll
                for (int nf = 0; nf < 8; nf++) {
                    int gn = nf*16 + l16;
                    float val = acc[mf][nf][r] + bias[gn];
                    if (MODE == 2) val = A0[(size_t)gm*NKD + gn] + fmaxf(val, 0.f);
                    else if (MODE == 3) val = fmaxf(A0[(size_t)gm*NKD + gn] + val, 0.f) * mk;
                    D[(size_t)gm*NKD + gn] = val;
                }
            }
        }
    }
}

// ---------------------------------------------------------------------------
// Segmented attention: one wave per (b, q, h). Rows [lo,hi) (permuted for ct)
// are exactly the valid keys for query q. Online softmax, 2 rows/iter,
// lane = (half=row parity, d=dim). o = q + softmax(q.k/sqrt(128)) @ v.
// ---------------------------------------------------------------------------
__global__ __launch_bounds__(256)
void sattn_kernel(const float* __restrict__ q, const float* __restrict__ k,
                  const float* __restrict__ v, float* __restrict__ o,
                  int nq, int nkv, const int* __restrict__ lo_arr,
                  const int* __restrict__ hi_arr, const int* __restrict__ perm)
{
    int task = blockIdx.x * 4 + (threadIdx.x >> 6);
    if (task >= NB * nq * NHD) return;
    const int h = task & 3;
    const int bq = task >> 2;
    const int qi = bq % nq;
    const int b = bq / nq;
    const int lane = threadIdx.x & 63;
    const int d = lane & 31;
    const int half = lane >> 5;
    const int lo = lo_arr ? lo_arr[b*nq + qi] : 0;
    const int hi = hi_arr ? hi_arr[b*nq + qi] : nkv;
    const float scale = 0.088388347648318447f;   // 1/sqrt(128)

    const float qv = q[((size_t)(b*nq + qi))*NKD + h*DH + d];
    const float* kb = k + (size_t)b*nkv*NKD + h*DH + d;
    const float* vb = v + (size_t)b*nkv*NKD + h*DH + d;
    const int* pb = perm ? perm + (size_t)b*nkv : nullptr;

    float m = -INFINITY, ssum = 0.f, acc = 0.f;
    for (int l0 = lo; l0 < hi; l0 += 2) {
        int l = l0 + half;
        bool valid = (l < hi);
        int lr = valid ? (pb ? pb[l] : l) : 0;
        float kv = valid ? kb[(size_t)lr*NKD] : 0.f;
        float vv = valid ? vb[(size_t)lr*NKD] : 0.f;
        float partial = qv * kv;
        #pragma unroll
        for (int off = 16; off; off >>= 1) partial += __shfl_xor(partial, off);
        float s = partial * scale;
        if (valid) {
            float mn = fmaxf(m, s);
            float corr = __expf(m - mn);
            float p = __expf(s - mn);
            ssum = ssum * corr + p;
            acc  = acc  * corr + p * vv;
            m = mn;
        }
    }
    float mo = __shfl_xor(m, 32);
    float M = fmaxf(m, mo);
    float corr = (m > -1e30f) ? __expf(m - M) : 0.f;
    ssum *= corr; acc *= corr;
    ssum += __shfl_xor(ssum, 32);
    acc  += __shfl_xor(acc, 32);
    if (half == 0) {
        float res = (ssum > 0.f) ? acc / ssum : 0.f;
        o[((size_t)(b*nq + qi))*NKD + h*DH + d] = qv + res;
    }
}

// ---------------------------------------------------------------------------
// Final head
// ---------------------------------------------------------------------------
__global__ __launch_bounds__(256)
void out_kernel(const float* __restrict__ U, const float* __restrict__ kt,
                const float* __restrict__ kc, const float* __restrict__ ow,
                const float* __restrict__ obp, float* __restrict__ out, int BL)
{
    int row = blockIdx.x * 4 + (threadIdx.x >> 6);
    int lane = threadIdx.x & 63;
    if (row >= BL) return;
    const float* u = U + (size_t)row*NKD;
    const float* a = kt + (size_t)row*NKD;
    const float* c = kc + (size_t)row*NKD;
    float s = u[lane]*ow[lane]       + u[lane+64]*ow[lane+64]
            + a[lane]*ow[128+lane]   + a[lane+64]*ow[192+lane]
            + c[lane]*ow[256+lane]   + c[lane+64]*ow[320+lane];
    #pragma unroll
    for (int off = 32; off; off >>= 1) s += __shfl_down(s, off);
    if (lane == 0) out[row] = s + obp[0];
}

// ---------------------------------------------------------------------------
extern "C" void kernel_launch(void* const* d_in, const int* in_sizes, int n_in,
                              void* d_out, int out_size, void* d_ws, size_t ws_size,
                              hipStream_t stream)
{
    const float* cx     = (const float*)d_in[0];
    const float* value  = (const float*)d_in[1];
    const float* maskp  = (const float*)d_in[2];
    const float* tval   = (const float*)d_in[3];
    const float* tmaskp = (const float*)d_in[4];
    const float* w0     = (const float*)d_in[5];
    const float* b0     = (const float*)d_in[6];
    const float* edge_w = (const float*)d_in[7];
    const float* edge_b = (const float*)d_in[8];
    const float* chan_w = (const float*)d_in[9];
    const float* chan_b = (const float*)d_in[10];
    const float* time_w = (const float*)d_in[11];
    const float* time_b = (const float*)d_in[12];
    const float* ct_wq = (const float*)d_in[13];
    const float* ct_bq = (const float*)d_in[14];
    const float* ct_wk = (const float*)d_in[15];
    const float* ct_bk = (const float*)d_in[16];
    const float* ct_wv = (const float*)d_in[17];
    const float* ct_bv = (const float*)d_in[18];
    const float* ct_wo = (const float*)d_in[19];
    const float* ct_bo = (const float*)d_in[20];
    const float* tc_wq = (const float*)d_in[21];
    const float* tc_bq = (const float*)d_in[22];
    const float* tc_wk = (const float*)d_in[23];
    const float* tc_bk = (const float*)d_in[24];
    const float* tc_wv = (const float*)d_in[25];
    const float* tc_bv = (const float*)d_in[26];
    const float* tc_wo = (const float*)d_in[27];
    const float* tc_bo = (const float*)d_in[28];
    const float* ca_wq = (const float*)d_in[29];
    const float* ca_bq = (const float*)d_in[30];
    const float* ca_wk = (const float*)d_in[31];
    const float* ca_bk = (const float*)d_in[32];
    const float* ca_wv = (const float*)d_in[33];
    const float* ca_bv = (const float*)d_in[34];
    const float* ca_wo = (const float*)d_in[35];
    const float* ca_bo = (const float*)d_in[36];
    const float* en_w  = (const float*)d_in[37];
    const float* en_b  = (const float*)d_in[38];
    const float* out_w = (const float*)d_in[39];
    const float* out_b = (const float*)d_in[40];

    const int BL = out_size / 3;     // B * full_len
    const int L  = BL / NB;

    char* p = (char*)d_ws;
    auto alloc = [&](size_t n) { char* r = p; p += (n + 255) & ~(size_t)255; return r; };
    int*   tind = (int*)  alloc((size_t)BL*4);
    int*   cind = (int*)  alloc((size_t)BL*4);
    float* mkb  = (float*)alloc((size_t)BL*4);
    float* uval = (float*)alloc((size_t)BL*4);
    float* uind = (float*)alloc((size_t)BL*4);
    int*   lo_t = (int*)  alloc((size_t)NB*SS*4);
    int*   hi_t = (int*)  alloc((size_t)NB*SS*4);
    int*   clo  = (int*)  alloc((size_t)NB*NDV*4);
    int*   chi  = (int*)  alloc((size_t)NB*NDV*4);
    int*   permc= (int*)  alloc((size_t)BL*4);
    short* waren= (short*)alloc((size_t)W_TOTAL*2);
    float* U    = (float*)alloc((size_t)BL*NKD*4);
    float* Unew = (float*)alloc((size_t)BL*NKD*4);
    float* kt   = (float*)alloc((size_t)BL*NKD*4);
    float* kc   = (float*)alloc((size_t)BL*NKD*4);
    float* Kb   = (float*)alloc((size_t)BL*NKD*4);
    float* Vb   = (float*)alloc((size_t)BL*NKD*4);
    float* T1   = (float*)alloc((size_t)NB*SS*NKD*4);
    float* T2b  = (float*)alloc((size_t)NB*SS*NKD*4);
    float* qT   = (float*)alloc((size_t)NB*SS*NKD*4);
    float* oT   = (float*)alloc((size_t)NB*SS*NKD*4);
    float* C1   = (float*)alloc((size_t)NB*NDV*NKD*4);
    float* C2   = (float*)alloc((size_t)NB*NDV*NKD*4);
    float* qC   = (float*)alloc((size_t)NB*NDV*NKD*4);
    float* kCa  = (float*)alloc((size_t)NB*NDV*NKD*4);
    float* vCa  = (float*)alloc((size_t)NB*NDV*NKD*4);
    float* oC   = (float*)alloc((size_t)NB*NDV*NKD*4);

    float* outMain = (float*)d_out;
    float* outTU = outMain + BL;
    float* outTM = outMain + 2*BL;

    // weight arena offsets (shorts)
    const size_t OCTQ=0, OCTK=49152, OCTV=147456, OCTO=245760;
    const size_t OTCQ=294912, OTCK=344064, OTCV=442368, OTCO=540672;
    const size_t OCAQ=589824, OCAK=638976, OCAV=688128, OCAO=737280, OEN=786432;

    compact_kernel<<<NB, 256, 0, stream>>>(cx, value, maskp, tval, tmaskp, w0, b0, L,
                                           tind, cind, mkb, uval, uind, outTU, outTM);
    zero_ranges<<<(NB*SS + 255)/256, 256, 0, stream>>>(lo_t, hi_t);
    trange_kernel<<<(NB*L + 255)/256, 256, 0, stream>>>(tind, lo_t, hi_t, L);
    cperm_kernel<<<NB, 256, 0, stream>>>(cind, permc, clo, chi, L);
    prep_weights<<<(W_TOTAL + 255)/256, 256, 0, stream>>>(
        ct_wq, ct_wk, ct_wv, ct_wo, tc_wq, tc_wk, tc_wv, tc_wo,
        ca_wq, ca_wk, ca_wv, ca_wo, en_w, waren);
    initT_kernel<<<(NB*SS*32 + 255)/256, 256, 0, stream>>>(cx, time_w, time_b, T1);
    initC_kernel<<<(NB*NDV*32 + 255)/256, 256, 0, stream>>>(chan_w, chan_b, C1);
    initU_kernel<<<(BL*32 + 255)/256, 256, 0, stream>>>(uval, uind, mkb, edge_w, edge_b, U, BL);

    const int gGather = (int)(((size_t)BL*32 + 255)/256);
    const int gBL = (BL + 127)/128;
    const int gC  = (NB*NDV + 127)/128;
    const int gT  = (NB*SS + 127)/128;
    const int aCT = (NB*NDV*NHD + 3)/4;   // 672
    const int aTC = (NB*SS*NHD + 3)/4;    // 4096

    for (int i = 0; i < NLAY; i++) {
        const size_t bOff = (size_t)i*NKD;
        const short* wq_ct = waren + OCTQ + (size_t)i*128*128;
        const short* wk_ct = waren + OCTK + (size_t)i*256*128;
        const short* wv_ct = waren + OCTV + (size_t)i*256*128;
        const short* wo_ct = waren + OCTO + (size_t)i*128*128;
        const short* wq_tc = waren + OTCQ + (size_t)i*128*128;
        const short* wk_tc = waren + OTCK + (size_t)i*256*128;
        const short* wv_tc = waren + OTCV + (size_t)i*256*128;
        const short* wo_tc = waren + OTCO + (size_t)i*128*128;
        const short* wq_ca = waren + OCAQ + (size_t)i*128*128;
        const short* wk_ca = waren + OCAK + (size_t)i*128*128;
        const short* wv_ca = waren + OCAV + (size_t)i*128*128;
        const short* wo_ca = waren + OCAO + (size_t)i*128*128;
        const short* w_en  = waren + OEN  + (size_t)i*384*128;

        // ct: C2 = mab2(C_, [k_t|U])
        gather_kernel<<<gGather, 256, 0, stream>>>(T1, kt, tind, L, SS);
        mgemm<2,0><<<gBL, 256, 0, stream>>>(kt, U, nullptr, wk_ct, ct_bk + bOff, Kb, BL, nullptr);
        mgemm<2,0><<<gBL, 256, 0, stream>>>(kt, U, nullptr, wv_ct, ct_bv + bOff, Vb, BL, nullptr);
        mgemm<1,0><<<gC, 256, 0, stream>>>(C1, nullptr, nullptr, wq_ct, ct_bq + bOff, qC, NB*NDV, nullptr);
        sattn_kernel<<<aCT, 256, 0, stream>>>(qC, Kb, Vb, oC, NDV, L, clo, chi, permc);
        mgemm<1,2><<<gC, 256, 0, stream>>>(oC, nullptr, nullptr, wo_ct, ct_bo + bOff, C2, NB*NDV, nullptr);

        // tc: T2 = mab2(T_, [k_c|U])
        gather_kernel<<<gGather, 256, 0, stream>>>(C1, kc, cind, L, NDV);
        mgemm<2,0><<<gBL, 256, 0, stream>>>(kc, U, nullptr, wk_tc, tc_bk + bOff, Kb, BL, nullptr);
        mgemm<2,0><<<gBL, 256, 0, stream>>>(kc, U, nullptr, wv_tc, tc_bv + bOff, Vb, BL, nullptr);
        mgemm<1,0><<<gT, 256, 0, stream>>>(T1, nullptr, nullptr, wq_tc, tc_bq + bOff, qT, NB*SS, nullptr);
        sattn_kernel<<<aTC, 256, 0, stream>>>(qT, Kb, Vb, oT, SS, L, lo_t, hi_t, nullptr);
        mgemm<1,2><<<gT, 256, 0, stream>>>(oT, nullptr, nullptr, wo_tc, tc_bo + bOff, T2b, NB*SS, nullptr);

        // U = relu(U + [U|k_t|k_c]@en_w + en_b) * mk
        mgemm<3,3><<<gBL, 256, 0, stream>>>(U, kt, kc, w_en, en_b + bOff, Unew, BL, mkb);

        // ca: C_ = mab2(C2, C2)
        mgemm<1,0><<<gC, 256, 0, stream>>>(C2, nullptr, nullptr, wq_ca, ca_bq + bOff, qC, NB*NDV, nullptr);
        mgemm<1,0><<<gC, 256, 0, stream>>>(C2, nullptr, nullptr, wk_ca, ca_bk + bOff, kCa, NB*NDV, nullptr);
        mgemm<1,0><<<gC, 256, 0, stream>>>(C2, nullptr, nullptr, wv_ca, ca_bv + bOff, vCa, NB*NDV, nullptr);
        sattn_kernel<<<aCT, 256, 0, stream>>>(qC, kCa, vCa, oC, NDV, NDV, nullptr, nullptr, nullptr);
        mgemm<1,2><<<gC, 256, 0, stream>>>(oC, nullptr, nullptr, wo_ca, ca_bo + bOff, C1, NB*NDV, nullptr);

        float* t = U;  U = Unew; Unew = t;
        t = T1; T1 = T2b; T2b = t;
    }

    gather_kernel<<<gGather, 256, 0, stream>>>(T1, kt, tind, L, SS);
    gather_kernel<<<gGather, 256, 0, stream>>>(C1, kc, cind, L, NDV);
    out_kernel<<<(BL + 3)/4, 256, 0, stream>>>(U, kt, kc, out_w, out_b, outMain, BL);
}

// Round 4
// 866.622 us; speedup vs baseline: 6.4694x; 1.2167x over previous
//
#include <hip/hip_runtime.h>
#include <math.h>

#define NB   16
#define SS   256
#define DIMV 41
#define NDV  42
#define NKD  128
#define NHD  4
#define DH   32
#define NLAY 3
#define TOT  (SS*NDV)   // 10752 = 42 chunks of 256
#define NCH  42

typedef __attribute__((ext_vector_type(8))) short short8;
typedef __attribute__((ext_vector_type(4))) float floatx4;

__device__ __forceinline__ short f2bf(float x) {
    unsigned u = __float_as_uint(x);
    u += 0x7fff + ((u >> 16) & 1);          // RNE f32 -> bf16
    return (short)(u >> 16);
}

struct Seg    { const float* ptr; const int* ind; int ns; };
struct OutSpec{ const short* Wt; const float* bias; float* D; };

__device__ __forceinline__ const float* seg_row(const Seg s, int gm, int Lb) {
    if (s.ind) {
        int b = gm / Lb;
        int id = s.ind[gm]; if (id < 0) id = 0;
        return s.ptr + ((size_t)b * s.ns + (size_t)id) * NKD;
    }
    return s.ptr + (size_t)gm * NKD;
}

// ---------------------------------------------------------------------------
// Parallel compaction (3 phases). Phase A: per-256-chunk valid counts.
// ---------------------------------------------------------------------------
__global__ __launch_bounds__(256)
void compactA(const float* __restrict__ maskp, int* __restrict__ chunkcnt)
{
    const int blk = blockIdx.x;            // b*NCH + ch
    const int b = blk / NCH, ch = blk % NCH;
    const int tid = threadIdx.x;
    const int idx = ch * 256 + tid;
    const int s = idx / NDV, c = idx % NDV;
    float m = (c < DIMV) ? maskp[((size_t)b*SS + s)*DIMV + c] : 1.0f;
    int x = (m != 0.0f) ? 1 : 0;
    #pragma unroll
    for (int off = 32; off; off >>= 1) x += __shfl_down(x, off);
    __shared__ int ws4[4];
    if ((tid & 63) == 0) ws4[tid >> 6] = x;
    __syncthreads();
    if (tid == 0) chunkcnt[blk] = ws4[0] + ws4[1] + ws4[2] + ws4[3];
}

// Phase B: per-batch exclusive scan of chunk counts (one wave per batch).
__global__ __launch_bounds__(64)
void compactB(const int* __restrict__ chunkcnt, int* __restrict__ chunkoff,
              int* __restrict__ cntb)
{
    const int b = blockIdx.x, lane = threadIdx.x;
    int v = (lane < NCH) ? chunkcnt[b*NCH + lane] : 0;
    int x = v;
    #pragma unroll
    for (int off = 1; off < 64; off <<= 1) {
        int y = __shfl_up(x, off);
        if (lane >= off) x += y;
    }
    if (lane < NCH) chunkoff[b*NCH + lane] = x - v;
    if (lane == 63) cntb[b] = x;
}

// Phase C: stable scatter (valids first, then invalids, index order).
__global__ __launch_bounds__(256)
void compactC(const float* __restrict__ cx, const float* __restrict__ value,
              const float* __restrict__ maskp, const float* __restrict__ tval,
              const float* __restrict__ tmaskp, const float* __restrict__ w0p,
              const float* __restrict__ b0p,
              const int* __restrict__ chunkoff, const int* __restrict__ cntb, int L,
              int* __restrict__ tind, int* __restrict__ cind,
              float* __restrict__ mkb, float* __restrict__ uval,
              float* __restrict__ uind,
              float* __restrict__ outTU, float* __restrict__ outTM)
{
    const int blk = blockIdx.x;
    const int b = blk / NCH, ch = blk % NCH;
    const int tid = threadIdx.x, lane = tid & 63, wv = tid >> 6;
    const int idx = ch * 256 + tid;
    const int s = idx / NDV, c = idx % NDV;
    float mval = (c < DIMV) ? maskp[((size_t)b*SS + s)*DIMV + c] : 1.0f;
    int m = (mval != 0.0f) ? 1 : 0;
    int x = m;
    #pragma unroll
    for (int off = 1; off < 64; off <<= 1) {
        int y = __shfl_up(x, off);
        if (lane >= off) x += y;
    }
    __shared__ int wsum[4];
    if (lane == 63) wsum[wv] = x;
    __syncthreads();
    int wbase = 0;
    for (int w = 0; w < wv; w++) wbase += wsum[w];
    const int excl = x - m + wbase;
    const int vbefore = chunkoff[b*NCH + ch] + excl;
    const int cnt = cntb[b];
    const int pos = m ? vbefore : (cnt + (idx - vbefore));
    if (pos < L) {
        const float w0 = w0p[0], b0 = b0p[0];
        float te = w0 * cx[(size_t)b*SS + s] + b0;
        float vf, tvf, tmf;
        if (c < DIMV) {
            size_t o = ((size_t)b*SS + s)*DIMV + c;
            vf = value[o]; tvf = tval[o]; tmf = tmaskp[o];
        } else { vf = te; tvf = te; tmf = 0.0f; }
        size_t p = (size_t)b*L + pos;
        if (m) {
            tind[p] = s; cind[p] = c; mkb[p] = 1.0f;
            uval[p] = vf; uind[p] = tmf;
            outTU[p] = tvf; outTM[p] = tmf;
        } else {
            tind[p] = -1; cind[p] = -1; mkb[p] = 0.0f;
            uval[p] = 0.0f; uind[p] = 1.0f;
            outTU[p] = 0.0f; outTM[p] = 0.0f;
        }
    }
}

// ---------------------------------------------------------------------------
// Segment ranges for tc (tind is sorted -> contiguous runs)
// ---------------------------------------------------------------------------
__global__ __launch_bounds__(256)
void zero_ranges(int* __restrict__ lo_t, int* __restrict__ hi_t)
{
    int i = blockIdx.x*256 + threadIdx.x;
    if (i < NB*SS) { lo_t[i] = 0; hi_t[i] = 0; }
}

__global__ __launch_bounds__(256)
void trange_kernel(const int* __restrict__ tind, int* __restrict__ lo_t,
                   int* __restrict__ hi_t, int L)
{
    int p = blockIdx.x*256 + threadIdx.x;
    if (p >= NB*L) return;
    int b = p / L, l = p - b*L;
    int t = tind[p];
    if (t < 0) return;
    int tp = (l > 0) ? tind[p-1] : -999;
    int tn = (l+1 < L) ? tind[p+1] : -999;
    if (tp != t) lo_t[b*SS + t] = l;
    if (tn != t) hi_t[b*SS + t] = l+1;
}

// counting-sort by channel: invp[flat_row] = flat destination (channel-sorted).
// Per-channel ranges [clo,chi). Padding rows fill [cnt, L).
__global__ __launch_bounds__(256)
void cperm_kernel(const int* __restrict__ cind, int* __restrict__ invp,
                  int* __restrict__ clo, int* __restrict__ chi, int L)
{
    __shared__ int hist[NDV];
    __shared__ int base[NDV];
    __shared__ int padc, cntsh;
    const int b = blockIdx.x, tid = threadIdx.x;
    if (tid < NDV) hist[tid] = 0;
    if (tid == 0) padc = 0;
    __syncthreads();
    for (int l = tid; l < L; l += 256) {
        int c = cind[(size_t)b*L + l];
        if (c >= 0) atomicAdd(&hist[c], 1);
    }
    __syncthreads();
    if (tid == 0) {
        int run = 0;
        for (int c = 0; c < NDV; c++) {
            base[c] = run; clo[b*NDV + c] = run;
            run += hist[c]; chi[b*NDV + c] = run;
        }
        cntsh = run;
    }
    __syncthreads();
    if (tid < NDV) hist[tid] = 0;
    __syncthreads();
    const int cnt = cntsh;
    for (int l = tid; l < L; l += 256) {
        int c = cind[(size_t)b*L + l];
        int pos;
        if (c >= 0) pos = base[c] + atomicAdd(&hist[c], 1);
        else        pos = cnt + atomicAdd(&padc, 1);
        invp[(size_t)b*L + l] = b*L + pos;
    }
}

// ---------------------------------------------------------------------------
// Init kernels
// ---------------------------------------------------------------------------
__global__ __launch_bounds__(256)
void initT_kernel(const float* __restrict__ cx, const float* __restrict__ tw,
                  const float* __restrict__ tb, float* __restrict__ T)
{
    int i = blockIdx.x * 256 + threadIdx.x;
    if (i >= NB*SS*32) return;
    int row = i >> 5;
    int k = (i & 31) << 2;
    float t = cx[row];
    float4 r;
    r.x = sinf(t*tw[k+0] + tb[k+0]);
    r.y = sinf(t*tw[k+1] + tb[k+1]);
    r.z = sinf(t*tw[k+2] + tb[k+2]);
    r.w = sinf(t*tw[k+3] + tb[k+3]);
    *(float4*)(T + (size_t)row*NKD + k) = r;
}

__global__ __launch_bounds__(256)
void initC_kernel(const float* __restrict__ cw, const float* __restrict__ cb,
                  float* __restrict__ C)
{
    int i = blockIdx.x * 256 + threadIdx.x;
    if (i >= NB*NDV*32) return;
    int row = i >> 5;
    int c = row % NDV;
    int k = (i & 31) << 2;
    float4 r;
    r.x = fmaxf(cw[(size_t)c*NKD + k+0] + cb[k+0], 0.f);
    r.y = fmaxf(cw[(size_t)c*NKD + k+1] + cb[k+1], 0.f);
    r.z = fmaxf(cw[(size_t)c*NKD + k+2] + cb[k+2], 0.f);
    r.w = fmaxf(cw[(size_t)c*NKD + k+3] + cb[k+3], 0.f);
    *(float4*)(C + (size_t)row*NKD + k) = r;
}

__global__ __launch_bounds__(256)
void initU_kernel(const float* __restrict__ uval, const float* __restrict__ uind,
                  const float* __restrict__ mkb, const float* __restrict__ ew,
                  const float* __restrict__ eb, float* __restrict__ U, int BL)
{
    int i = blockIdx.x * 256 + threadIdx.x;
    if (i >= BL*32) return;
    int row = i >> 5;
    int k = (i & 31) << 2;
    float uv = uval[row], ui = uind[row], m = mkb[row];
    float4 r;
    r.x = fmaxf(uv*ew[k+0] + ui*ew[NKD+k+0] + eb[k+0], 0.f) * m;
    r.y = fmaxf(uv*ew[k+1] + ui*ew[NKD+k+1] + eb[k+1], 0.f) * m;
    r.z = fmaxf(uv*ew[k+2] + ui*ew[NKD+k+2] + eb[k+2], 0.f) * m;
    r.w = fmaxf(uv*ew[k+3] + ui*ew[NKD+k+3] + eb[k+3], 0.f) * m;
    *(float4*)(U + (size_t)row*NKD + k) = r;
}

// ---------------------------------------------------------------------------
// Weight prep: f32 [NL][K][128] -> bf16 transposed [NL][128][K] arena
// ---------------------------------------------------------------------------
template<int Kg>
__device__ __forceinline__ void prep1(const float* __restrict__ src,
                                      short* __restrict__ dst, int rel)
{
    const int per = Kg*128;
    int i = rel / per; int r2 = rel - i*per;
    int n = r2 / Kg;   int k = r2 - n*Kg;
    dst[rel] = f2bf(src[(size_t)i*per + (size_t)k*128 + n]);
}

#define W_TOTAL 933888
__global__ __launch_bounds__(256)
void prep_weights(const float* ctq, const float* ctk, const float* ctv, const float* cto,
                  const float* tcq, const float* tck, const float* tcv, const float* tco,
                  const float* caq, const float* cak, const float* cav, const float* cao,
                  const float* enw, short* __restrict__ arena)
{
    int idx = blockIdx.x*256 + threadIdx.x;
    if (idx >= W_TOTAL) return;
    if      (idx < 49152 ) prep1<128>(ctq, arena + 0,      idx - 0);
    else if (idx < 147456) prep1<256>(ctk, arena + 49152,  idx - 49152);
    else if (idx < 245760) prep1<256>(ctv, arena + 147456, idx - 147456);
    else if (idx < 294912) prep1<128>(cto, arena + 245760, idx - 245760);
    else if (idx < 344064) prep1<128>(tcq, arena + 294912, idx - 294912);
    else if (idx < 442368) prep1<256>(tck, arena + 344064, idx - 344064);
    else if (idx < 540672) prep1<256>(tcv, arena + 442368, idx - 442368);
    else if (idx < 589824) prep1<128>(tco, arena + 540672, idx - 540672);
    else if (idx < 638976) prep1<128>(caq, arena + 589824, idx - 589824);
    else if (idx < 688128) prep1<128>(cak, arena + 638976, idx - 638976);
    else if (idx < 737280) prep1<128>(cav, arena + 688128, idx - 688128);
    else if (idx < 786432) prep1<128>(cao, arena + 737280, idx - 737280);
    else                   prep1<384>(enw, arena + 786432, idx - 786432);
}

// ---------------------------------------------------------------------------
// MFMA GEMM with indirect A-segments, multi-output batching (gridDim.y),
// and optional permuted row store (rmap).
// MODE 0: D = acc + b ; MODE 2: D = A0 + relu(acc+b) ;
// MODE 3: D = relu(A0 + acc + b) * mk[m]
// ---------------------------------------------------------------------------
template<int NSEG, int MODE, int NOUT>
__global__ __launch_bounds__(256)
void mgemm(Seg s0, Seg s1, Seg s2,
           OutSpec os0, OutSpec os1, OutSpec os2,
           int M, int Lb, const float* __restrict__ mkp, const int* __restrict__ rmap)
{
    const short* Wt; const float* bias; float* D;
    if (NOUT == 1) { Wt = os0.Wt; bias = os0.bias; D = os0.D; }
    else {
        OutSpec arr[3] = {os0, os1, os2};
        OutSpec sel = arr[blockIdx.y];
        Wt = sel.Wt; bias = sel.bias; D = sel.D;
    }
    __shared__ short As[128][40];
    __shared__ short Bs[128][40];
    const int bm = blockIdx.x * 128;
    const int tid = threadIdx.x;
    const int wv = tid >> 6;
    const int lane = tid & 63;
    const int quad = lane >> 4;
    const int l16 = lane & 15;
    const int K = NSEG * 128;
    floatx4 acc[2][8];
    #pragma unroll
    for (int i = 0; i < 2; i++)
        #pragma unroll
        for (int j = 0; j < 8; j++) acc[i][j] = (floatx4){0.f,0.f,0.f,0.f};

    // staging row for this thread (fixed across the K loop)
    const int arow = tid >> 1;
    const int acol = (tid & 1) * 16;
    int gmc = bm + arow; if (gmc > M-1) gmc = M-1;
    const float* rowp0 = seg_row(s0, gmc, Lb);
    const float* rowp1 = (NSEG > 1) ? seg_row(s1, gmc, Lb) : nullptr;
    const float* rowp2 = (NSEG > 2) ? seg_row(s2, gmc, Lb) : nullptr;

    for (int k0 = 0; k0 < K; k0 += 32) {
        {
            const float* rp;
            if (NSEG == 1) rp = rowp0;
            else if (NSEG == 2) rp = (k0 < 128) ? rowp0 : rowp1;
            else rp = (k0 < 128) ? rowp0 : ((k0 < 256) ? rowp1 : rowp2);
            const int ks = k0 & 127;
            const float* src = rp + ks + acol;
            float4 a0 = *(const float4*)(src);
            float4 a1 = *(const float4*)(src+4);
            float4 a2 = *(const float4*)(src+8);
            float4 a3 = *(const float4*)(src+12);
            short8 p0, p1;
            p0[0]=f2bf(a0.x); p0[1]=f2bf(a0.y); p0[2]=f2bf(a0.z); p0[3]=f2bf(a0.w);
            p0[4]=f2bf(a1.x); p0[5]=f2bf(a1.y); p0[6]=f2bf(a1.z); p0[7]=f2bf(a1.w);
            p1[0]=f2bf(a2.x); p1[1]=f2bf(a2.y); p1[2]=f2bf(a2.z); p1[3]=f2bf(a2.w);
            p1[4]=f2bf(a3.x); p1[5]=f2bf(a3.y); p1[6]=f2bf(a3.z); p1[7]=f2bf(a3.w);
            *(short8*)&As[arow][acol]   = p0;
            *(short8*)&As[arow][acol+8] = p1;
        }
        {
            const short* src = Wt + (size_t)arow*K + k0 + acol;
            *(short8*)&Bs[arow][acol]   = *(const short8*)(src);
            *(short8*)&Bs[arow][acol+8] = *(const short8*)(src+8);
        }
        __syncthreads();
        short8 af0 = *(short8*)&As[wv*32 + l16][quad*8];
        short8 af1 = *(short8*)&As[wv*32 + 16 + l16][quad*8];
        #pragma unroll
        for (int nf = 0; nf < 8; nf++) {
            short8 bf = *(short8*)&Bs[nf*16 + l16][quad*8];
            acc[0][nf] = __builtin_amdgcn_mfma_f32_16x16x32_bf16(af0, bf, acc[0][nf], 0, 0, 0);
            acc[1][nf] = __builtin_amdgcn_mfma_f32_16x16x32_bf16(af1, bf, acc[1][nf], 0, 0, 0);
        }
        __syncthreads();
    }
    #pragma unroll
    for (int mf = 0; mf < 2; mf++) {
        #pragma unroll
        for (int r = 0; r < 4; r++) {
            int gm = bm + wv*32 + mf*16 + quad*4 + r;
            if (gm < M) {
                int orow = rmap ? rmap[gm] : gm;
                float mk = (MODE == 3) ? mkp[gm] : 0.f;
                const float* res = (MODE == 2 || MODE == 3) ? seg_row(s0, gm, Lb) : nullptr;
                #pragma unroll
                for (int nf = 0; nf < 8; nf++) {
                    int gn = nf*16 + l16;
                    float val = acc[mf][nf][r] + bias[gn];
                    if (MODE == 2) val = res[gn] + fmaxf(val, 0.f);
                    else if (MODE == 3) val = fmaxf(res[gn] + val, 0.f) * mk;
                    D[(size_t)orow*NKD + gn] = val;
                }
            }
        }
    }
}

// ---------------------------------------------------------------------------
// Segmented attention. SPLIT waves per (b,q,h); each wave covers half the
// segment [lo,hi) with unroll-4 prefetched online softmax; LDS merge.
// lane = (half = row parity, d = dim). o = q + softmax(q.k/sqrt(128)) @ v.
// ---------------------------------------------------------------------------
template<int SPLIT>
__global__ __launch_bounds__(256)
void sattn_kernel(const float* __restrict__ q, const float* __restrict__ k,
                  const float* __restrict__ v, float* __restrict__ o,
                  int nq, int nkv, const int* __restrict__ lo_arr,
                  const int* __restrict__ hi_arr)
{
    __shared__ float sm_m[4], sm_s[4], sm_a[4][DH];
    const int wvid = threadIdx.x >> 6;
    int gtask = blockIdx.x * 4 + wvid;
    int task = gtask / SPLIT;
    int part = gtask % SPLIT;
    if (task >= NB * nq * NHD) return;
    const int h = task & 3;
    const int bq = task >> 2;
    const int qi = bq % nq;
    const int b = bq / nq;
    const int lane = threadIdx.x & 63;
    const int d = lane & 31;
    const int half = lane >> 5;
    int lo = lo_arr ? lo_arr[b*nq + qi] : 0;
    int hi = hi_arr ? hi_arr[b*nq + qi] : nkv;
    if (SPLIT == 2) {
        int mid = lo + ((hi - lo + 1) >> 1);
        if (part == 0) hi = mid; else lo = mid;
    }
    const float scale = 0.088388347648318447f;   // 1/sqrt(128)

    const float qv = q[((size_t)(b*nq + qi))*NKD + h*DH + d];
    const float* kb = k + (size_t)b*nkv*NKD + h*DH + d;
    const float* vb = v + (size_t)b*nkv*NKD + h*DH + d;

    float m = -INFINITY, ssum = 0.f, acc = 0.f;
    for (int l0 = lo; l0 < hi; l0 += 8) {
        float kr[4], vr[4];
        #pragma unroll
        for (int j = 0; j < 4; j++) {
            int l = l0 + 2*j + half;
            bool ok = (l < hi);
            size_t off = (size_t)(ok ? l : lo) * NKD;
            kr[j] = ok ? kb[off] : 0.f;
            vr[j] = ok ? vb[off] : 0.f;
        }
        #pragma unroll
        for (int j = 0; j < 4; j++) {
            int l = l0 + 2*j + half;
            float partial = qv * kr[j];
            #pragma unroll
            for (int off = 16; off; off >>= 1) partial += __shfl_xor(partial, off);
            float s = partial * scale;
            if (l < hi) {
                float mn = fmaxf(m, s);
                float corr = __expf(m - mn);
                float p = __expf(s - mn);
                ssum = ssum * corr + p;
                acc  = acc  * corr + p * vr[j];
                m = mn;
            }
        }
    }
    // combine the two halves of the wave
    float mo = __shfl_xor(m, 32);
    float M = fmaxf(m, mo);
    float corr = (m > -1e30f) ? __expf(m - M) : 0.f;
    ssum *= corr; acc *= corr;
    ssum += __shfl_xor(ssum, 32);
    acc  += __shfl_xor(acc, 32);

    if (SPLIT == 1) {
        if (half == 0) {
            float res = (ssum > 0.f) ? acc / ssum : 0.f;
            o[((size_t)(b*nq + qi))*NKD + h*DH + d] = qv + res;
        }
    } else {
        if (lane == 0) { sm_m[wvid] = M; sm_s[wvid] = ssum; }
        if (lane < DH) sm_a[wvid][lane] = acc;
        __syncthreads();
        if (part == 0 && lane < DH) {
            float m2 = sm_m[wvid+1], s2 = sm_s[wvid+1], a2 = sm_a[wvid+1][lane];
            float M2 = fmaxf(M, m2);
            float c1 = (M  > -1e30f) ? __expf(M  - M2) : 0.f;
            float c2 = (m2 > -1e30f) ? __expf(m2 - M2) : 0.f;
            float S = ssum * c1 + s2 * c2;
            float A = acc  * c1 + a2 * c2;
            float res = (S > 0.f) ? A / S : 0.f;
            o[((size_t)(b*nq + qi))*NKD + h*DH + lane] = qv + res;
        }
    }
}

// ---------------------------------------------------------------------------
// Final head with inline gathers of k_t, k_c
// ---------------------------------------------------------------------------
__global__ __launch_bounds__(256)
void out_kernel(const float* __restrict__ U, const float* __restrict__ T1,
                const float* __restrict__ C1, const int* __restrict__ tind,
                const int* __restrict__ cind, const float* __restrict__ ow,
                const float* __restrict__ obp, float* __restrict__ out,
                int BL, int L)
{
    int row = blockIdx.x * 4 + (threadIdx.x >> 6);
    int lane = threadIdx.x & 63;
    if (row >= BL) return;
    int b = row / L;
    int ti = tind[row]; if (ti < 0) ti = 0;
    int ci = cind[row]; if (ci < 0) ci = 0;
    const float* u = U + (size_t)row*NKD;
    const float* a = T1 + ((size_t)(b*SS + ti))*NKD;
    const float* c = C1 + ((size_t)(b*NDV + ci))*NKD;
    float s = u[lane]*ow[lane]       + u[lane+64]*ow[lane+64]
            + a[lane]*ow[128+lane]   + a[lane+64]*ow[192+lane]
            + c[lane]*ow[256+lane]   + c[lane+64]*ow[320+lane];
    #pragma unroll
    for (int off = 32; off; off >>= 1) s += __shfl_down(s, off);
    if (lane == 0) out[row] = s + obp[0];
}

// ---------------------------------------------------------------------------
extern "C" void kernel_launch(void* const* d_in, const int* in_sizes, int n_in,
                              void* d_out, int out_size, void* d_ws, size_t ws_size,
                              hipStream_t stream)
{
    const float* cx     = (const float*)d_in[0];
    const float* value  = (const float*)d_in[1];
    const float* maskp  = (const float*)d_in[2];
    const float* tval   = (const float*)d_in[3];
    const float* tmaskp = (const float*)d_in[4];
    const float* w0     = (const float*)d_in[5];
    const float* b0     = (const float*)d_in[6];
    const float* edge_w = (const float*)d_in[7];
    const float* edge_b = (const float*)d_in[8];
    const float* chan_w = (const float*)d_in[9];
    const float* chan_b = (const float*)d_in[10];
    const float* time_w = (const float*)d_in[11];
    const float* time_b = (const float*)d_in[12];
    const float* ct_wq = (const float*)d_in[13];
    const float* ct_bq = (const float*)d_in[14];
    const float* ct_wk = (const float*)d_in[15];
    const float* ct_bk = (const float*)d_in[16];
    const float* ct_wv = (const float*)d_in[17];
    const float* ct_bv = (const float*)d_in[18];
    const float* ct_wo = (const float*)d_in[19];
    const float* ct_bo = (const float*)d_in[20];
    const float* tc_wq = (const float*)d_in[21];
    const float* tc_bq = (const float*)d_in[22];
    const float* tc_wk = (const float*)d_in[23];
    const float* tc_bk = (const float*)d_in[24];
    const float* tc_wv = (const float*)d_in[25];
    const float* tc_bv = (const float*)d_in[26];
    const float* tc_wo = (const float*)d_in[27];
    const float* tc_bo = (const float*)d_in[28];
    const float* ca_wq = (const float*)d_in[29];
    const float* ca_bq = (const float*)d_in[30];
    const float* ca_wk = (const float*)d_in[31];
    const float* ca_bk = (const float*)d_in[32];
    const float* ca_wv = (const float*)d_in[33];
    const float* ca_bv = (const float*)d_in[34];
    const float* ca_wo = (const float*)d_in[35];
    const float* ca_bo = (const float*)d_in[36];
    const float* en_w  = (const float*)d_in[37];
    const float* en_b  = (const float*)d_in[38];
    const float* out_w = (const float*)d_in[39];
    const float* out_b = (const float*)d_in[40];

    const int BL = out_size / 3;     // B * full_len
    const int L  = BL / NB;

    char* p = (char*)d_ws;
    auto alloc = [&](size_t n) { char* r = p; p += (n + 255) & ~(size_t)255; return r; };
    int*   tind   = (int*)  alloc((size_t)BL*4);
    int*   cind   = (int*)  alloc((size_t)BL*4);
    float* mkb    = (float*)alloc((size_t)BL*4);
    float* uval   = (float*)alloc((size_t)BL*4);
    float* uind   = (float*)alloc((size_t)BL*4);
    int*   lo_t   = (int*)  alloc((size_t)NB*SS*4);
    int*   hi_t   = (int*)  alloc((size_t)NB*SS*4);
    int*   clo    = (int*)  alloc((size_t)NB*NDV*4);
    int*   chi    = (int*)  alloc((size_t)NB*NDV*4);
    int*   invp   = (int*)  alloc((size_t)BL*4);
    int*   chunkc = (int*)  alloc((size_t)NB*NCH*4);
    int*   chunko = (int*)  alloc((size_t)NB*NCH*4);
    int*   cntb   = (int*)  alloc((size_t)NB*4);
    short* waren  = (short*)alloc((size_t)W_TOTAL*2);
    float* U    = (float*)alloc((size_t)BL*NKD*4);
    float* Unew = (float*)alloc((size_t)BL*NKD*4);
    float* Kb   = (float*)alloc((size_t)BL*NKD*4);
    float* Vb   = (float*)alloc((size_t)BL*NKD*4);
    float* T1   = (float*)alloc((size_t)NB*SS*NKD*4);
    float* T2b  = (float*)alloc((size_t)NB*SS*NKD*4);
    float* qT   = (float*)alloc((size_t)NB*SS*NKD*4);
    float* oT   = (float*)alloc((size_t)NB*SS*NKD*4);
    float* C1   = (float*)alloc((size_t)NB*NDV*NKD*4);
    float* C2   = (float*)alloc((size_t)NB*NDV*NKD*4);
    float* qC   = (float*)alloc((size_t)NB*NDV*NKD*4);
    float* kCa  = (float*)alloc((size_t)NB*NDV*NKD*4);
    float* vCa  = (float*)alloc((size_t)NB*NDV*NKD*4);
    float* oC   = (float*)alloc((size_t)NB*NDV*NKD*4);

    float* outMain = (float*)d_out;
    float* outTU = outMain + BL;
    float* outTM = outMain + 2*BL;

    // weight arena offsets (shorts)
    const size_t OCTQ=0, OCTK=49152, OCTV=147456, OCTO=245760;
    const size_t OTCQ=294912, OTCK=344064, OTCV=442368, OTCO=540672;
    const size_t OCAQ=589824, OCAK=638976, OCAV=688128, OCAO=737280, OEN=786432;

    compactA<<<NB*NCH, 256, 0, stream>>>(maskp, chunkc);
    compactB<<<NB, 64, 0, stream>>>(chunkc, chunko, cntb);
    compactC<<<NB*NCH, 256, 0, stream>>>(cx, value, maskp, tval, tmaskp, w0, b0,
                                         chunko, cntb, L, tind, cind, mkb, uval, uind,
                                         outTU, outTM);
    zero_ranges<<<(NB*SS + 255)/256, 256, 0, stream>>>(lo_t, hi_t);
    trange_kernel<<<(NB*L + 255)/256, 256, 0, stream>>>(tind, lo_t, hi_t, L);
    cperm_kernel<<<NB, 256, 0, stream>>>(cind, invp, clo, chi, L);
    prep_weights<<<(W_TOTAL + 255)/256, 256, 0, stream>>>(
        ct_wq, ct_wk, ct_wv, ct_wo, tc_wq, tc_wk, tc_wv, tc_wo,
        ca_wq, ca_wk, ca_wv, ca_wo, en_w, waren);
    initT_kernel<<<(NB*SS*32 + 255)/256, 256, 0, stream>>>(cx, time_w, time_b, T1);
    initC_kernel<<<(NB*NDV*32 + 255)/256, 256, 0, stream>>>(chan_w, chan_b, C1);
    initU_kernel<<<(BL*32 + 255)/256, 256, 0, stream>>>(uval, uind, mkb, edge_w, edge_b, U, BL);

    const int gBL = (BL + 127)/128;
    const int gC  = (NB*NDV + 127)/128;
    const int gT  = (NB*SS + 127)/128;
    const int aC2 = NB*NDV*NHD*2/4;      // 1344 (SPLIT=2, exact)
    const int aTC = NB*SS*NHD/4;         // 4096 (SPLIT=1)
    const Seg segN{nullptr, nullptr, 0};
    const OutSpec osN{nullptr, nullptr, nullptr};

    for (int i = 0; i < NLAY; i++) {
        const size_t bOff = (size_t)i*NKD;
        const short* wq_ct = waren + OCTQ + (size_t)i*128*128;
        const short* wk_ct = waren + OCTK + (size_t)i*256*128;
        const short* wv_ct = waren + OCTV + (size_t)i*256*128;
        const short* wo_ct = waren + OCTO + (size_t)i*128*128;
        const short* wq_tc = waren + OTCQ + (size_t)i*128*128;
        const short* wk_tc = waren + OTCK + (size_t)i*256*128;
        const short* wv_tc = waren + OTCV + (size_t)i*256*128;
        const short* wo_tc = waren + OTCO + (size_t)i*128*128;
        const short* wq_ca = waren + OCAQ + (size_t)i*128*128;
        const short* wk_ca = waren + OCAK + (size_t)i*128*128;
        const short* wv_ca = waren + OCAV + (size_t)i*128*128;
        const short* wo_ca = waren + OCAO + (size_t)i*128*128;
        const short* w_en  = waren + OEN  + (size_t)i*384*128;

        // ct: K/V = [gather(T1,tind) | U] @ wk/wv, stored channel-sorted (invp)
        mgemm<2,0,2><<<dim3(gBL,2), 256, 0, stream>>>(
            Seg{T1, tind, SS}, Seg{U, nullptr, 0}, segN,
            OutSpec{wk_ct, ct_bk + bOff, Kb}, OutSpec{wv_ct, ct_bv + bOff, Vb}, osN,
            BL, L, nullptr, invp);
        mgemm<1,0,1><<<gC, 256, 0, stream>>>(
            Seg{C1, nullptr, 0}, segN, segN,
            OutSpec{wq_ct, ct_bq + bOff, qC}, osN, osN, NB*NDV, 1, nullptr, nullptr);
        sattn_kernel<2><<<aC2, 256, 0, stream>>>(qC, Kb, Vb, oC, NDV, L, clo, chi);
        mgemm<1,2,1><<<gC, 256, 0, stream>>>(
            Seg{oC, nullptr, 0}, segN, segN,
            OutSpec{wo_ct, ct_bo + bOff, C2}, osN, osN, NB*NDV, 1, nullptr, nullptr);

        // tc: K/V = [gather(C1,cind) | U] @ wk/wv (natural order)
        mgemm<2,0,2><<<dim3(gBL,2), 256, 0, stream>>>(
            Seg{C1, cind, NDV}, Seg{U, nullptr, 0}, segN,
            OutSpec{wk_tc, tc_bk + bOff, Kb}, OutSpec{wv_tc, tc_bv + bOff, Vb}, osN,
            BL, L, nullptr, nullptr);
        mgemm<1,0,1><<<gT, 256, 0, stream>>>(
            Seg{T1, nullptr, 0}, segN, segN,
            OutSpec{wq_tc, tc_bq + bOff, qT}, osN, osN, NB*SS, 1, nullptr, nullptr);
        sattn_kernel<1><<<aTC, 256, 0, stream>>>(qT, Kb, Vb, oT, SS, L, lo_t, hi_t);
        mgemm<1,2,1><<<gT, 256, 0, stream>>>(
            Seg{oT, nullptr, 0}, segN, segN,
            OutSpec{wo_tc, tc_bo + bOff, T2b}, osN, osN, NB*SS, 1, nullptr, nullptr);

        // U = relu(U + [U | k_t | k_c] @ en_w + en_b) * mk   (gathers fused)
        mgemm<3,3,1><<<gBL, 256, 0, stream>>>(
            Seg{U, nullptr, 0}, Seg{T1, tind, SS}, Seg{C1, cind, NDV},
            OutSpec{w_en, en_b + bOff, Unew}, osN, osN, BL, L, mkb, nullptr);

        // ca: C_ = mab2(C2, C2) — q/k/v in one dispatch
        mgemm<1,0,3><<<dim3(gC,3), 256, 0, stream>>>(
            Seg{C2, nullptr, 0}, segN, segN,
            OutSpec{wq_ca, ca_bq + bOff, qC},
            OutSpec{wk_ca, ca_bk + bOff, kCa},
            OutSpec{wv_ca, ca_bv + bOff, vCa}, NB*NDV, 1, nullptr, nullptr);
        sattn_kernel<2><<<aC2, 256, 0, stream>>>(qC, kCa, vCa, oC, NDV, NDV, nullptr, nullptr);
        mgemm<1,2,1><<<gC, 256, 0, stream>>>(
            Seg{oC, nullptr, 0}, segN, segN,
            OutSpec{wo_ca, ca_bo + bOff, C1}, osN, osN, NB*NDV, 1, nullptr, nullptr);

        float* t = U;  U = Unew; Unew = t;
        t = T1; T1 = T2b; T2b = t;
    }

    out_kernel<<<(BL + 3)/4, 256, 0, stream>>>(U, T1, C1, tind, cind,
                                               out_w, out_b, outMain, BL, L);
}

// Round 6
// 747.018 us; speedup vs baseline: 7.5052x; 1.1601x over previous
//
#include <hip/hip_runtime.h>
#include <math.h>

#define NB   16
#define SS   256
#define DIMV 41
#define NDV  42
#define NKD  128
#define NHD  4
#define DH   32
#define NLAY 3
#define TOT  (SS*NDV)   // 10752 = 42 chunks of 256
#define NCH  42

typedef __attribute__((ext_vector_type(8))) short short8;
typedef __attribute__((ext_vector_type(4))) float floatx4;

__device__ __forceinline__ short f2bf(float x) {
    unsigned u = __float_as_uint(x);
    u += 0x7fff + ((u >> 16) & 1);          // RNE f32 -> bf16
    return (short)(u >> 16);
}
__device__ __forceinline__ float bf2f(unsigned s) {
    return __uint_as_float(s << 16);
}

struct Seg { const float* ptr; const int* ind; int ns; };

__device__ __forceinline__ const float* seg_row(const Seg s, int gm, int Lb) {
    if (s.ind) {
        int b = gm / Lb;
        int id = s.ind[gm]; if (id < 0) id = 0;
        return s.ptr + ((size_t)b * s.ns + (size_t)id) * NKD;
    }
    return s.ptr + (size_t)gm * NKD;
}

// ---------------------------------------------------------------------------
// Parallel compaction (3 phases)
// ---------------------------------------------------------------------------
__global__ __launch_bounds__(256)
void compactA(const float* __restrict__ maskp, int* __restrict__ chunkcnt)
{
    const int blk = blockIdx.x;
    const int b = blk / NCH, ch = blk % NCH;
    const int tid = threadIdx.x;
    const int idx = ch * 256 + tid;
    const int s = idx / NDV, c = idx % NDV;
    float m = (c < DIMV) ? maskp[((size_t)b*SS + s)*DIMV + c] : 1.0f;
    int x = (m != 0.0f) ? 1 : 0;
    #pragma unroll
    for (int off = 32; off; off >>= 1) x += __shfl_down(x, off);
    __shared__ int ws4[4];
    if ((tid & 63) == 0) ws4[tid >> 6] = x;
    __syncthreads();
    if (tid == 0) chunkcnt[blk] = ws4[0] + ws4[1] + ws4[2] + ws4[3];
}

__global__ __launch_bounds__(64)
void compactB(const int* __restrict__ chunkcnt, int* __restrict__ chunkoff,
              int* __restrict__ cntb)
{
    const int b = blockIdx.x, lane = threadIdx.x;
    int v = (lane < NCH) ? chunkcnt[b*NCH + lane] : 0;
    int x = v;
    #pragma unroll
    for (int off = 1; off < 64; off <<= 1) {
        int y = __shfl_up(x, off);
        if (lane >= off) x += y;
    }
    if (lane < NCH) chunkoff[b*NCH + lane] = x - v;
    if (lane == 63) cntb[b] = x;
}

__global__ __launch_bounds__(256)
void compactC(const float* __restrict__ cx, const float* __restrict__ value,
              const float* __restrict__ maskp, const float* __restrict__ tval,
              const float* __restrict__ tmaskp, const float* __restrict__ w0p,
              const float* __restrict__ b0p,
              const int* __restrict__ chunkoff, const int* __restrict__ cntb, int L,
              int* __restrict__ tind, int* __restrict__ cind,
              float* __restrict__ mkb, float* __restrict__ uval,
              float* __restrict__ uind,
              float* __restrict__ outTU, float* __restrict__ outTM)
{
    const int blk = blockIdx.x;
    const int b = blk / NCH, ch = blk % NCH;
    const int tid = threadIdx.x, lane = tid & 63, wv = tid >> 6;
    const int idx = ch * 256 + tid;
    const int s = idx / NDV, c = idx % NDV;
    float mval = (c < DIMV) ? maskp[((size_t)b*SS + s)*DIMV + c] : 1.0f;
    int m = (mval != 0.0f) ? 1 : 0;
    int x = m;
    #pragma unroll
    for (int off = 1; off < 64; off <<= 1) {
        int y = __shfl_up(x, off);
        if (lane >= off) x += y;
    }
    __shared__ int wsum[4];
    if (lane == 63) wsum[wv] = x;
    __syncthreads();
    int wbase = 0;
    for (int w = 0; w < wv; w++) wbase += wsum[w];
    const int excl = x - m + wbase;
    const int vbefore = chunkoff[b*NCH + ch] + excl;
    const int cnt = cntb[b];
    const int pos = m ? vbefore : (cnt + (idx - vbefore));
    if (pos < L) {
        const float w0 = w0p[0], b0 = b0p[0];
        float te = w0 * cx[(size_t)b*SS + s] + b0;
        float vf, tvf, tmf;
        if (c < DIMV) {
            size_t o = ((size_t)b*SS + s)*DIMV + c;
            vf = value[o]; tvf = tval[o]; tmf = tmaskp[o];
        } else { vf = te; tvf = te; tmf = 0.0f; }
        size_t p = (size_t)b*L + pos;
        if (m) {
            tind[p] = s; cind[p] = c; mkb[p] = 1.0f;
            uval[p] = vf; uind[p] = tmf;
            outTU[p] = tvf; outTM[p] = tmf;
        } else {
            tind[p] = -1; cind[p] = -1; mkb[p] = 0.0f;
            uval[p] = 0.0f; uind[p] = 1.0f;
            outTU[p] = 0.0f; outTM[p] = 0.0f;
        }
    }
}

// ---------------------------------------------------------------------------
// Segment ranges
// ---------------------------------------------------------------------------
__global__ __launch_bounds__(256)
void zero_ranges(int* __restrict__ lo_t, int* __restrict__ hi_t)
{
    int i = blockIdx.x*256 + threadIdx.x;
    if (i < NB*SS) { lo_t[i] = 0; hi_t[i] = 0; }
}

__global__ __launch_bounds__(256)
void trange_kernel(const int* __restrict__ tind, int* __restrict__ lo_t,
                   int* __restrict__ hi_t, int L)
{
    int p = blockIdx.x*256 + threadIdx.x;
    if (p >= NB*L) return;
    int b = p / L, l = p - b*L;
    int t = tind[p];
    if (t < 0) return;
    int tp = (l > 0) ? tind[p-1] : -999;
    int tn = (l+1 < L) ? tind[p+1] : -999;
    if (tp != t) lo_t[b*SS + t] = l;
    if (tn != t) hi_t[b*SS + t] = l+1;
}

__global__ __launch_bounds__(256)
void cperm_kernel(const int* __restrict__ cind, int* __restrict__ invp,
                  int* __restrict__ clo, int* __restrict__ chi, int L)
{
    __shared__ int hist[NDV];
    __shared__ int base[NDV];
    __shared__ int padc, cntsh;
    const int b = blockIdx.x, tid = threadIdx.x;
    if (tid < NDV) hist[tid] = 0;
    if (tid == 0) padc = 0;
    __syncthreads();
    for (int l = tid; l < L; l += 256) {
        int c = cind[(size_t)b*L + l];
        if (c >= 0) atomicAdd(&hist[c], 1);
    }
    __syncthreads();
    if (tid == 0) {
        int run = 0;
        for (int c = 0; c < NDV; c++) {
            base[c] = run; clo[b*NDV + c] = run;
            run += hist[c]; chi[b*NDV + c] = run;
        }
        cntsh = run;
    }
    __syncthreads();
    if (tid < NDV) hist[tid] = 0;
    __syncthreads();
    const int cnt = cntsh;
    for (int l = tid; l < L; l += 256) {
        int c = cind[(size_t)b*L + l];
        int pos;
        if (c >= 0) pos = base[c] + atomicAdd(&hist[c], 1);
        else        pos = cnt + atomicAdd(&padc, 1);
        invp[(size_t)b*L + l] = b*L + pos;
    }
}

// ---------------------------------------------------------------------------
// Fused init: T_, C_, U in one dispatch
// ---------------------------------------------------------------------------
__global__ __launch_bounds__(256)
void initAll(const float* __restrict__ cx, const float* __restrict__ tw,
             const float* __restrict__ tb, const float* __restrict__ cw,
             const float* __restrict__ cb, const float* __restrict__ uval,
             const float* __restrict__ uind, const float* __restrict__ mkb,
             const float* __restrict__ ew, const float* __restrict__ eb,
             float* __restrict__ T, float* __restrict__ C, float* __restrict__ U,
             int BL)
{
    const int n1 = NB*SS*32, n2 = NB*NDV*32;
    int i = blockIdx.x * 256 + threadIdx.x;
    if (i < n1) {
        int row = i >> 5;
        int k = (i & 31) << 2;
        float t = cx[row];
        float4 r;
        r.x = sinf(t*tw[k+0] + tb[k+0]);
        r.y = sinf(t*tw[k+1] + tb[k+1]);
        r.z = sinf(t*tw[k+2] + tb[k+2]);
        r.w = sinf(t*tw[k+3] + tb[k+3]);
        *(float4*)(T + (size_t)row*NKD + k) = r;
    } else if (i < n1 + n2) {
        i -= n1;
        int row = i >> 5;
        int c = row % NDV;
        int k = (i & 31) << 2;
        float4 r;
        r.x = fmaxf(cw[(size_t)c*NKD + k+0] + cb[k+0], 0.f);
        r.y = fmaxf(cw[(size_t)c*NKD + k+1] + cb[k+1], 0.f);
        r.z = fmaxf(cw[(size_t)c*NKD + k+2] + cb[k+2], 0.f);
        r.w = fmaxf(cw[(size_t)c*NKD + k+3] + cb[k+3], 0.f);
        *(float4*)(C + (size_t)row*NKD + k) = r;
    } else {
        i -= n1 + n2;
        if (i >= BL*32) return;
        int row = i >> 5;
        int k = (i & 31) << 2;
        float uv = uval[row], ui = uind[row], m = mkb[row];
        float4 r;
        r.x = fmaxf(uv*ew[k+0] + ui*ew[NKD+k+0] + eb[k+0], 0.f) * m;
        r.y = fmaxf(uv*ew[k+1] + ui*ew[NKD+k+1] + eb[k+1], 0.f) * m;
        r.z = fmaxf(uv*ew[k+2] + ui*ew[NKD+k+2] + eb[k+2], 0.f) * m;
        r.w = fmaxf(uv*ew[k+3] + ui*ew[NKD+k+3] + eb[k+3], 0.f) * m;
        *(float4*)(U + (size_t)row*NKD + k) = r;
    }
}

// ---------------------------------------------------------------------------
// Weight prep: f32 [NL][K][128] -> bf16 transposed [NL][128][K] arena
// ---------------------------------------------------------------------------
template<int Kg>
__device__ __forceinline__ void prep1(const float* __restrict__ src,
                                      short* __restrict__ dst, int rel)
{
    const int per = Kg*128;
    int i = rel / per; int r2 = rel - i*per;
    int n = r2 / Kg;   int k = r2 - n*Kg;
    dst[rel] = f2bf(src[(size_t)i*per + (size_t)k*128 + n]);
}

#define W_TOTAL 933888
__global__ __launch_bounds__(256)
void prep_weights(const float* ctq, const float* ctk, const float* ctv, const float* cto,
                  const float* tcq, const float* tck, const float* tcv, const float* tco,
                  const float* caq, const float* cak, const float* cav, const float* cao,
                  const float* enw, short* __restrict__ arena)
{
    int idx = blockIdx.x*256 + threadIdx.x;
    if (idx >= W_TOTAL) return;
    if      (idx < 49152 ) prep1<128>(ctq, arena + 0,      idx - 0);
    else if (idx < 147456) prep1<256>(ctk, arena + 49152,  idx - 49152);
    else if (idx < 245760) prep1<256>(ctv, arena + 147456, idx - 147456);
    else if (idx < 294912) prep1<128>(cto, arena + 245760, idx - 245760);
    else if (idx < 344064) prep1<128>(tcq, arena + 294912, idx - 294912);
    else if (idx < 442368) prep1<256>(tck, arena + 344064, idx - 344064);
    else if (idx < 540672) prep1<256>(tcv, arena + 442368, idx - 442368);
    else if (idx < 589824) prep1<128>(tco, arena + 540672, idx - 540672);
    else if (idx < 638976) prep1<128>(caq, arena + 589824, idx - 589824);
    else if (idx < 688128) prep1<128>(cak, arena + 638976, idx - 638976);
    else if (idx < 737280) prep1<128>(cav, arena + 688128, idx - 688128);
    else if (idx < 786432) prep1<128>(cao, arena + 737280, idx - 737280);
    else                   prep1<384>(enw, arena + 786432, idx - 786432);
}

// ---------------------------------------------------------------------------
// Generic MFMA GEMM (M-tile 128): D = epilogue(concat(segs) @ Wt + bias)
// MODE 0: D = acc+b ; MODE 2: D = A0 + relu(acc+b) ; MODE 3: relu(A0+acc+b)*mk
// ---------------------------------------------------------------------------
template<int NSEG, int MODE>
__global__ __launch_bounds__(256)
void mgemm(Seg s0, Seg s1, Seg s2, const short* __restrict__ Wt,
           const float* __restrict__ bias, float* __restrict__ D,
           int M, int Lb, const float* __restrict__ mkp)
{
    __shared__ short As[128][40];
    __shared__ short Bs[128][40];
    const int bm = blockIdx.x * 128;
    const int tid = threadIdx.x;
    const int wv = tid >> 6;
    const int lane = tid & 63;
    const int quad = lane >> 4;
    const int l16 = lane & 15;
    const int K = NSEG * 128;
    floatx4 acc[2][8];
    #pragma unroll
    for (int i = 0; i < 2; i++)
        #pragma unroll
        for (int j = 0; j < 8; j++) acc[i][j] = (floatx4){0.f,0.f,0.f,0.f};

    const int arow = tid >> 1;
    const int acol = (tid & 1) * 16;
    int gmc = bm + arow; if (gmc > M-1) gmc = M-1;
    const float* rowp0 = seg_row(s0, gmc, Lb);
    const float* rowp1 = (NSEG > 1) ? seg_row(s1, gmc, Lb) : nullptr;
    const float* rowp2 = (NSEG > 2) ? seg_row(s2, gmc, Lb) : nullptr;

    for (int k0 = 0; k0 < K; k0 += 32) {
        {
            const float* rp;
            if (NSEG == 1) rp = rowp0;
            else if (NSEG == 2) rp = (k0 < 128) ? rowp0 : rowp1;
            else rp = (k0 < 128) ? rowp0 : ((k0 < 256) ? rowp1 : rowp2);
            const int ks = k0 & 127;
            const float* src = rp + ks + acol;
            float4 a0 = *(const float4*)(src);
            float4 a1 = *(const float4*)(src+4);
            float4 a2 = *(const float4*)(src+8);
            float4 a3 = *(const float4*)(src+12);
            short8 p0, p1;
            p0[0]=f2bf(a0.x); p0[1]=f2bf(a0.y); p0[2]=f2bf(a0.z); p0[3]=f2bf(a0.w);
            p0[4]=f2bf(a1.x); p0[5]=f2bf(a1.y); p0[6]=f2bf(a1.z); p0[7]=f2bf(a1.w);
            p1[0]=f2bf(a2.x); p1[1]=f2bf(a2.y); p1[2]=f2bf(a2.z); p1[3]=f2bf(a2.w);
            p1[4]=f2bf(a3.x); p1[5]=f2bf(a3.y); p1[6]=f2bf(a3.z); p1[7]=f2bf(a3.w);
            *(short8*)&As[arow][acol]   = p0;
            *(short8*)&As[arow][acol+8] = p1;
        }
        {
            const short* src = Wt + (size_t)arow*K + k0 + acol;
            *(short8*)&Bs[arow][acol]   = *(const short8*)(src);
            *(short8*)&Bs[arow][acol+8] = *(const short8*)(src+8);
        }
        __syncthreads();
        short8 af0 = *(short8*)&As[wv*32 + l16][quad*8];
        short8 af1 = *(short8*)&As[wv*32 + 16 + l16][quad*8];
        #pragma unroll
        for (int nf = 0; nf < 8; nf++) {
            short8 bf = *(short8*)&Bs[nf*16 + l16][quad*8];
            acc[0][nf] = __builtin_amdgcn_mfma_f32_16x16x32_bf16(af0, bf, acc[0][nf], 0, 0, 0);
            acc[1][nf] = __builtin_amdgcn_mfma_f32_16x16x32_bf16(af1, bf, acc[1][nf], 0, 0, 0);
        }
        __syncthreads();
    }
    #pragma unroll
    for (int mf = 0; mf < 2; mf++) {
        #pragma unroll
        for (int r = 0; r < 4; r++) {
            int gm = bm + wv*32 + mf*16 + quad*4 + r;
            if (gm < M) {
                float mk = (MODE == 3) ? mkp[gm] : 0.f;
                const float* res = (MODE == 2 || MODE == 3) ? seg_row(s0, gm, Lb) : nullptr;
                #pragma unroll
                for (int nf = 0; nf < 8; nf++) {
                    int gn = nf*16 + l16;
                    float val = acc[mf][nf][r] + bias[gn];
                    if (MODE == 2) val = res[gn] + fmaxf(val, 0.f);
                    else if (MODE == 3) val = fmaxf(res[gn] + val, 0.f) * mk;
                    D[(size_t)gm*NKD + gn] = val;
                }
            }
        }
    }
}

// ---------------------------------------------------------------------------
// Dual-output MFMA GEMM (M-tile 64): K and V in ONE pass over A, stored as
// packed bf16 (k | v<<16) per (row, dim). Optional third output Q (f32).
// rmap permutes output rows (channel-sorted store for ct).
// ---------------------------------------------------------------------------
template<int NSEG, bool HASQ>
__global__ __launch_bounds__(256)
void mgemm_kv(Seg s0, Seg s1,
              const short* __restrict__ Wk, const float* __restrict__ bk,
              const short* __restrict__ Wv, const float* __restrict__ bv,
              const short* __restrict__ Wq, const float* __restrict__ bq,
              float* __restrict__ Qd,
              unsigned* __restrict__ KV, int M, int Lb, const int* __restrict__ rmap)
{
    __shared__ short As[64][40];
    __shared__ short Bk[128][40];
    __shared__ short Bv[128][40];
    __shared__ short Bq[HASQ ? 128 : 1][40];
    const int bm = blockIdx.x * 64;
    const int tid = threadIdx.x;
    const int wv = tid >> 6;
    const int lane = tid & 63;
    const int quad = lane >> 4;
    const int l16 = lane & 15;
    const int K = NSEG * 128;
    floatx4 acck[8], accv[8], accq[8];
    #pragma unroll
    for (int j = 0; j < 8; j++) {
        acck[j] = (floatx4){0.f,0.f,0.f,0.f};
        accv[j] = (floatx4){0.f,0.f,0.f,0.f};
        if (HASQ) accq[j] = (floatx4){0.f,0.f,0.f,0.f};
    }

    const int arow = tid >> 2;            // 64 rows, 4 threads/row
    const int acol = (tid & 3) * 8;       // 8 floats each
    const int brow = tid >> 1;            // 128 rows, 2 threads/row
    const int bcol = (tid & 1) * 16;      // 16 shorts each
    int gmc = bm + arow; if (gmc > M-1) gmc = M-1;
    const float* rowp0 = seg_row(s0, gmc, Lb);
    const float* rowp1 = (NSEG > 1) ? seg_row(s1, gmc, Lb) : nullptr;

    for (int k0 = 0; k0 < K; k0 += 32) {
        {
            const float* rp = (NSEG == 1) ? rowp0 : ((k0 < 128) ? rowp0 : rowp1);
            const int ks = k0 & 127;
            const float* src = rp + ks + acol;
            float4 a0 = *(const float4*)(src);
            float4 a1 = *(const float4*)(src+4);
            short8 p0;
            p0[0]=f2bf(a0.x); p0[1]=f2bf(a0.y); p0[2]=f2bf(a0.z); p0[3]=f2bf(a0.w);
            p0[4]=f2bf(a1.x); p0[5]=f2bf(a1.y); p0[6]=f2bf(a1.z); p0[7]=f2bf(a1.w);
            *(short8*)&As[arow][acol] = p0;
        }
        {
            const short* sk = Wk + (size_t)brow*K + k0 + bcol;
            *(short8*)&Bk[brow][bcol]   = *(const short8*)(sk);
            *(short8*)&Bk[brow][bcol+8] = *(const short8*)(sk+8);
            const short* sv = Wv + (size_t)brow*K + k0 + bcol;
            *(short8*)&Bv[brow][bcol]   = *(const short8*)(sv);
            *(short8*)&Bv[brow][bcol+8] = *(const short8*)(sv+8);
            if (HASQ) {
                const short* sq = Wq + (size_t)brow*K + k0 + bcol;
                *(short8*)&Bq[brow][bcol]   = *(const short8*)(sq);
                *(short8*)&Bq[brow][bcol+8] = *(const short8*)(sq+8);
            }
        }
        __syncthreads();
        short8 af = *(short8*)&As[wv*16 + l16][quad*8];
        #pragma unroll
        for (int nf = 0; nf < 8; nf++) {
            short8 bfk = *(short8*)&Bk[nf*16 + l16][quad*8];
            acck[nf] = __builtin_amdgcn_mfma_f32_16x16x32_bf16(af, bfk, acck[nf], 0, 0, 0);
            short8 bfv = *(short8*)&Bv[nf*16 + l16][quad*8];
            accv[nf] = __builtin_amdgcn_mfma_f32_16x16x32_bf16(af, bfv, accv[nf], 0, 0, 0);
            if (HASQ) {
                short8 bfq = *(short8*)&Bq[nf*16 + l16][quad*8];
                accq[nf] = __builtin_amdgcn_mfma_f32_16x16x32_bf16(af, bfq, accq[nf], 0, 0, 0);
            }
        }
        __syncthreads();
    }
    #pragma unroll
    for (int r = 0; r < 4; r++) {
        int gm = bm + wv*16 + quad*4 + r;
        if (gm < M) {
            int orow = rmap ? rmap[gm] : gm;
            #pragma unroll
            for (int nf = 0; nf < 8; nf++) {
                int gn = nf*16 + l16;
                float kf = acck[nf][r] + bk[gn];
                float vf = accv[nf][r] + bv[gn];
                unsigned pk = (unsigned)(unsigned short)f2bf(kf)
                            | ((unsigned)(unsigned short)f2bf(vf) << 16);
                KV[(size_t)orow*NKD + gn] = pk;
                if (HASQ) Qd[(size_t)gm*NKD + gn] = accq[nf][r] + bq[gn];
            }
        }
    }
}

// ---------------------------------------------------------------------------
// Segmented attention on packed bf16 KV. SPLIT waves per (b,q,h).
// ---------------------------------------------------------------------------
template<int SPLIT>
__global__ __launch_bounds__(256)
void sattn_kernel(const float* __restrict__ q, const unsigned* __restrict__ kvb,
                  float* __restrict__ o, int nq, int nkv,
                  const int* __restrict__ lo_arr, const int* __restrict__ hi_arr)
{
    __shared__ float sm_m[4], sm_s[4], sm_a[4][DH];
    const int wvid = threadIdx.x >> 6;
    int gtask = blockIdx.x * 4 + wvid;
    int task = gtask / SPLIT;
    int part = gtask % SPLIT;
    if (task >= NB * nq * NHD) return;
    const int h = task & 3;
    const int bq = task >> 2;
    const int qi = bq % nq;
    const int b = bq / nq;
    const int lane = threadIdx.x & 63;
    const int d = lane & 31;
    const int half = lane >> 5;
    int lo = lo_arr ? lo_arr[b*nq + qi] : 0;
    int hi = hi_arr ? hi_arr[b*nq + qi] : nkv;
    if (SPLIT == 2) {
        int mid = lo + ((hi - lo + 1) >> 1);
        if (part == 0) hi = mid; else lo = mid;
    }
    const float scale = 0.088388347648318447f;   // 1/sqrt(128)

    const float qv = q[((size_t)(b*nq + qi))*NKD + h*DH + d];
    const unsigned* kb = kvb + (size_t)b*nkv*NKD + h*DH + d;

    float m = -INFINITY, ssum = 0.f, acc = 0.f;
    for (int l0 = lo; l0 < hi; l0 += 8) {
        unsigned ur[4];
        #pragma unroll
        for (int j = 0; j < 4; j++) {
            int l = l0 + 2*j + half;
            bool ok = (l < hi);
            ur[j] = ok ? kb[(size_t)l*NKD] : 0u;
        }
        #pragma unroll
        for (int j = 0; j < 4; j++) {
            int l = l0 + 2*j + half;
            float kr = bf2f(ur[j] & 0xffffu);
            float vr = bf2f(ur[j] >> 16);
            float partial = qv * kr;
            #pragma unroll
            for (int off = 16; off; off >>= 1) partial += __shfl_xor(partial, off);
            float s = partial * scale;
            if (l < hi) {
                float mn = fmaxf(m, s);
                float corr = __expf(m - mn);
                float p = __expf(s - mn);
                ssum = ssum * corr + p;
                acc  = acc  * corr + p * vr;
                m = mn;
            }
        }
    }
    float mo = __shfl_xor(m, 32);
    float M = fmaxf(m, mo);
    float corr = (m > -1e30f) ? __expf(m - M) : 0.f;
    ssum *= corr; acc *= corr;
    ssum += __shfl_xor(ssum, 32);
    acc  += __shfl_xor(acc, 32);

    if (SPLIT == 1) {
        if (half == 0) {
            float res = (ssum > 0.f) ? acc / ssum : 0.f;
            o[((size_t)(b*nq + qi))*NKD + h*DH + d] = qv + res;
        }
    } else {
        if (lane == 0) { sm_m[wvid] = M; sm_s[wvid] = ssum; }
        if (lane < DH) sm_a[wvid][lane] = acc;
        __syncthreads();
        if (part == 0 && lane < DH) {
            float m2 = sm_m[wvid+1], s2 = sm_s[wvid+1], a2 = sm_a[wvid+1][lane];
            float M2 = fmaxf(M, m2);
            float c1 = (M  > -1e30f) ? __expf(M  - M2) : 0.f;
            float c2 = (m2 > -1e30f) ? __expf(m2 - M2) : 0.f;
            float S = ssum * c1 + s2 * c2;
            float A = acc  * c1 + a2 * c2;
            float res = (S > 0.f) ? A / S : 0.f;
            o[((size_t)(b*nq + qi))*NKD + h*DH + lane] = qv + res;
        }
    }
}

// ---------------------------------------------------------------------------
// Final head with inline gathers of k_t, k_c
// ---------------------------------------------------------------------------
__global__ __launch_bounds__(256)
void out_kernel(const float* __restrict__ U, const float* __restrict__ T1,
                const float* __restrict__ C1, const int* __restrict__ tind,
                const int* __restrict__ cind, const float* __restrict__ ow,
                const float* __restrict__ obp, float* __restrict__ out,
                int BL, int L)
{
    int row = blockIdx.x * 4 + (threadIdx.x >> 6);
    int lane = threadIdx.x & 63;
    if (row >= BL) return;
    int b = row / L;
    int ti = tind[row]; if (ti < 0) ti = 0;
    int ci = cind[row]; if (ci < 0) ci = 0;
    const float* u = U + (size_t)row*NKD;
    const float* a = T1 + ((size_t)(b*SS + ti))*NKD;
    const float* c = C1 + ((size_t)(b*NDV + ci))*NKD;
    float s = u[lane]*ow[lane]       + u[lane+64]*ow[lane+64]
            + a[lane]*ow[128+lane]   + a[lane+64]*ow[192+lane]
            + c[lane]*ow[256+lane]   + c[lane+64]*ow[320+lane];
    #pragma unroll
    for (int off = 32; off; off >>= 1) s += __shfl_down(s, off);
    if (lane == 0) out[row] = s + obp[0];
}

// ---------------------------------------------------------------------------
extern "C" void kernel_launch(void* const* d_in, const int* in_sizes, int n_in,
                              void* d_out, int out_size, void* d_ws, size_t ws_size,
                              hipStream_t stream)
{
    const float* cx     = (const float*)d_in[0];
    const float* value  = (const float*)d_in[1];
    const float* maskp  = (const float*)d_in[2];
    const float* tval   = (const float*)d_in[3];
    const float* tmaskp = (const float*)d_in[4];
    const float* w0     = (const float*)d_in[5];
    const float* b0     = (const float*)d_in[6];
    const float* edge_w = (const float*)d_in[7];
    const float* edge_b = (const float*)d_in[8];
    const float* chan_w = (const float*)d_in[9];
    const float* chan_b = (const float*)d_in[10];
    const float* time_w = (const float*)d_in[11];
    const float* time_b = (const float*)d_in[12];
    const float* ct_wq = (const float*)d_in[13];
    const float* ct_bq = (const float*)d_in[14];
    const float* ct_wk = (const float*)d_in[15];
    const float* ct_bk = (const float*)d_in[16];
    const float* ct_wv = (const float*)d_in[17];
    const float* ct_bv = (const float*)d_in[18];
    const float* ct_wo = (const float*)d_in[19];
    const float* ct_bo = (const float*)d_in[20];
    const float* tc_wq = (const float*)d_in[21];
    const float* tc_bq = (const float*)d_in[22];
    const float* tc_wk = (const float*)d_in[23];
    const float* tc_bk = (const float*)d_in[24];
    const float* tc_wv = (const float*)d_in[25];
    const float* tc_bv = (const float*)d_in[26];
    const float* tc_wo = (const float*)d_in[27];
    const float* tc_bo = (const float*)d_in[28];
    const float* ca_wq = (const float*)d_in[29];
    const float* ca_bq = (const float*)d_in[30];
    const float* ca_wk = (const float*)d_in[31];
    const float* ca_bk = (const float*)d_in[32];
    const float* ca_wv = (const float*)d_in[33];
    const float* ca_bv = (const float*)d_in[34];
    const float* ca_wo = (const float*)d_in[35];
    const float* ca_bo = (const float*)d_in[36];
    const float* en_w  = (const float*)d_in[37];
    const float* en_b  = (const float*)d_in[38];
    const float* out_w = (const float*)d_in[39];
    const float* out_b = (const float*)d_in[40];

    const int BL = out_size / 3;     // B * full_len
    const int L  = BL / NB;

    char* p = (char*)d_ws;
    auto alloc = [&](size_t n) { char* r = p; p += (n + 255) & ~(size_t)255; return r; };
    int*      tind   = (int*)  alloc((size_t)BL*4);
    int*      cind   = (int*)  alloc((size_t)BL*4);
    float*    mkb    = (float*)alloc((size_t)BL*4);
    float*    uval   = (float*)alloc((size_t)BL*4);
    float*    uind   = (float*)alloc((size_t)BL*4);
    int*      lo_t   = (int*)  alloc((size_t)NB*SS*4);
    int*      hi_t   = (int*)  alloc((size_t)NB*SS*4);
    int*      clo    = (int*)  alloc((size_t)NB*NDV*4);
    int*      chi    = (int*)  alloc((size_t)NB*NDV*4);
    int*      invp   = (int*)  alloc((size_t)BL*4);
    int*      chunkc = (int*)  alloc((size_t)NB*NCH*4);
    int*      chunko = (int*)  alloc((size_t)NB*NCH*4);
    int*      cntb   = (int*)  alloc((size_t)NB*4);
    short*    waren  = (short*)alloc((size_t)W_TOTAL*2);
    float*    U    = (float*)alloc((size_t)BL*NKD*4);
    float*    Unew = (float*)alloc((size_t)BL*NKD*4);
    unsigned* KVb  = (unsigned*)alloc((size_t)BL*NKD*4);
    unsigned* kvCa = (unsigned*)alloc((size_t)NB*NDV*NKD*4);
    float*    T1   = (float*)alloc((size_t)NB*SS*NKD*4);
    float*    T2b  = (float*)alloc((size_t)NB*SS*NKD*4);
    float*    qT   = (float*)alloc((size_t)NB*SS*NKD*4);
    float*    oT   = (float*)alloc((size_t)NB*SS*NKD*4);
    float*    C1   = (float*)alloc((size_t)NB*NDV*NKD*4);
    float*    C2   = (float*)alloc((size_t)NB*NDV*NKD*4);
    float*    qC   = (float*)alloc((size_t)NB*NDV*NKD*4);
    float*    oC   = (float*)alloc((size_t)NB*NDV*NKD*4);

    float* outMain = (float*)d_out;
    float* outTU = outMain + BL;
    float* outTM = outMain + 2*BL;

    // weight arena offsets (shorts)
    const size_t OCTQ=0, OCTK=49152, OCTV=147456, OCTO=245760;
    const size_t OTCQ=294912, OTCK=344064, OTCV=442368, OTCO=540672;
    const size_t OCAQ=589824, OCAK=638976, OCAV=688128, OCAO=737280, OEN=786432;

    compactA<<<NB*NCH, 256, 0, stream>>>(maskp, chunkc);
    compactB<<<NB, 64, 0, stream>>>(chunkc, chunko, cntb);
    compactC<<<NB*NCH, 256, 0, stream>>>(cx, value, maskp, tval, tmaskp, w0, b0,
                                         chunko, cntb, L, tind, cind, mkb, uval, uind,
                                         outTU, outTM);
    zero_ranges<<<(NB*SS + 255)/256, 256, 0, stream>>>(lo_t, hi_t);
    trange_kernel<<<(NB*L + 255)/256, 256, 0, stream>>>(tind, lo_t, hi_t, L);
    cperm_kernel<<<NB, 256, 0, stream>>>(cind, invp, clo, chi, L);
    prep_weights<<<(W_TOTAL + 255)/256, 256, 0, stream>>>(
        ct_wq, ct_wk, ct_wv, ct_wo, tc_wq, tc_wk, tc_wv, tc_wo,
        ca_wq, ca_wk, ca_wv, ca_wo, en_w, waren);
    {
        int nInit = NB*SS*32 + NB*NDV*32 + BL*32;
        initAll<<<(nInit + 255)/256, 256, 0, stream>>>(
            cx, time_w, time_b, chan_w, chan_b, uval, uind, mkb, edge_w, edge_b,
            T1, C1, U, BL);
    }

    const int gBL  = (BL + 127)/128;
    const int gKV  = (BL + 63)/64;
    const int gC   = (NB*NDV + 127)/128;
    const int gT   = (NB*SS + 127)/128;
    const int gCa  = (NB*NDV + 63)/64;
    const int aC2  = NB*NDV*NHD*2/4;     // SPLIT=2
    const int aTC  = NB*SS*NHD/4;        // SPLIT=1
    const Seg segN{nullptr, nullptr, 0};

    for (int i = 0; i < NLAY; i++) {
        const size_t bOff = (size_t)i*NKD;
        const short* wq_ct = waren + OCTQ + (size_t)i*128*128;
        const short* wk_ct = waren + OCTK + (size_t)i*256*128;
        const short* wv_ct = waren + OCTV + (size_t)i*256*128;
        const short* wo_ct = waren + OCTO + (size_t)i*128*128;
        const short* wq_tc = waren + OTCQ + (size_t)i*128*128;
        const short* wk_tc = waren + OTCK + (size_t)i*256*128;
        const short* wv_tc = waren + OTCV + (size_t)i*256*128;
        const short* wo_tc = waren + OTCO + (size_t)i*128*128;
        const short* wq_ca = waren + OCAQ + (size_t)i*128*128;
        const short* wk_ca = waren + OCAK + (size_t)i*128*128;
        const short* wv_ca = waren + OCAV + (size_t)i*128*128;
        const short* wo_ca = waren + OCAO + (size_t)i*128*128;
        const short* w_en  = waren + OEN  + (size_t)i*384*128;

        // ct: packed K/V = [gather(T1,tind)|U] @ wk/wv, stored channel-sorted
        mgemm_kv<2,false><<<gKV, 256, 0, stream>>>(
            Seg{T1, tind, SS}, Seg{U, nullptr, 0},
            wk_ct, ct_bk + bOff, wv_ct, ct_bv + bOff,
            nullptr, nullptr, nullptr, KVb, BL, L, invp);
        mgemm<1,0><<<gC, 256, 0, stream>>>(
            Seg{C1, nullptr, 0}, segN, segN, wq_ct, ct_bq + bOff, qC, NB*NDV, 1, nullptr);
        sattn_kernel<2><<<aC2, 256, 0, stream>>>(qC, KVb, oC, NDV, L, clo, chi);
        mgemm<1,2><<<gC, 256, 0, stream>>>(
            Seg{oC, nullptr, 0}, segN, segN, wo_ct, ct_bo + bOff, C2, NB*NDV, 1, nullptr);

        // tc: packed K/V = [gather(C1,cind)|U] @ wk/wv
        mgemm_kv<2,false><<<gKV, 256, 0, stream>>>(
            Seg{C1, cind, NDV}, Seg{U, nullptr, 0},
            wk_tc, tc_bk + bOff, wv_tc, tc_bv + bOff,
            nullptr, nullptr, nullptr, KVb, BL, L, nullptr);
        mgemm<1,0><<<gT, 256, 0, stream>>>(
            Seg{T1, nullptr, 0}, segN, segN, wq_tc, tc_bq + bOff, qT, NB*SS, 1, nullptr);
        sattn_kernel<1><<<aTC, 256, 0, stream>>>(qT, KVb, oT, SS, L, lo_t, hi_t);
        mgemm<1,2><<<gT, 256, 0, stream>>>(
            Seg{oT, nullptr, 0}, segN, segN, wo_tc, tc_bo + bOff, T2b, NB*SS, 1, nullptr);

        // U = relu(U + [U|k_t|k_c]@en_w + en_b) * mk (gathers fused)
        mgemm<3,3><<<gBL, 256, 0, stream>>>(
            Seg{U, nullptr, 0}, Seg{T1, tind, SS}, Seg{C1, cind, NDV},
            w_en, en_b + bOff, Unew, BL, L, mkb);

        // ca: q + packed k/v in one pass, then attention + o-proj
        mgemm_kv<1,true><<<gCa, 256, 0, stream>>>(
            Seg{C2, nullptr, 0}, segN,
            wk_ca, ca_bk + bOff, wv_ca, ca_bv + bOff,
            wq_ca, ca_bq + bOff, qC, kvCa, NB*NDV, 1, nullptr);
        sattn_kernel<2><<<aC2, 256, 0, stream>>>(qC, kvCa, oC, NDV, NDV, nullptr, nullptr);
        mgemm<1,2><<<gC, 256, 0, stream>>>(
            Seg{oC, nullptr, 0}, segN, segN, wo_ca, ca_bo + bOff, C1, NB*NDV, 1, nullptr);

        float* t = U;  U = Unew; Unew = t;
        t = T1; T1 = T2b; T2b = t;
    }

    out_kernel<<<(BL + 3)/4, 256, 0, stream>>>(U, T1, C1, tind, cind,
                                               out_w, out_b, outMain, BL, L);
}

// Round 7
// 490.065 us; speedup vs baseline: 11.4404x; 1.5243x over previous
//
#include <hip/hip_runtime.h>
#include <math.h>

#define NB   16
#define SS   256
#define DIMV 41
#define NDV  42
#define NKD  128
#define NHD  4
#define DH   32
#define NLAY 3
#define TOT  (SS*NDV)   // 10752 = 42 chunks of 256
#define NCH  42

typedef __attribute__((ext_vector_type(8))) short short8;
typedef __attribute__((ext_vector_type(4))) float floatx4;

__device__ __forceinline__ short f2bf(float x) {
    unsigned u = __float_as_uint(x);
    u += 0x7fff + ((u >> 16) & 1);          // RNE f32 -> bf16
    return (short)(u >> 16);
}
__device__ __forceinline__ float bf2f(unsigned s) {
    return __uint_as_float(s << 16);
}

struct Seg { const float* ptr; const int* ind; int ns; };

__device__ __forceinline__ const float* seg_row(const Seg s, int gm, int Lb) {
    if (s.ind) {
        int b = gm / Lb;
        int id = s.ind[gm]; if (id < 0) id = 0;
        return s.ptr + ((size_t)b * s.ns + (size_t)id) * NKD;
    }
    return s.ptr + (size_t)gm * NKD;
}

// ===========================================================================
// Device bodies (block-uniform branch targets; bx = local block id)
// ===========================================================================

__device__ __forceinline__ void compactA_body(int bx, const float* __restrict__ maskp,
                                              int* __restrict__ chunkcnt)
{
    const int b = bx / NCH, ch = bx % NCH;
    const int tid = threadIdx.x;
    const int idx = ch * 256 + tid;
    const int s = idx / NDV, c = idx % NDV;
    float m = (c < DIMV) ? maskp[((size_t)b*SS + s)*DIMV + c] : 1.0f;
    int x = (m != 0.0f) ? 1 : 0;
    #pragma unroll
    for (int off = 32; off; off >>= 1) x += __shfl_down(x, off);
    __shared__ int ws4[4];
    if ((tid & 63) == 0) ws4[tid >> 6] = x;
    __syncthreads();
    if (tid == 0) chunkcnt[bx] = ws4[0] + ws4[1] + ws4[2] + ws4[3];
}

__device__ __forceinline__ void zero_body(int bx, int* __restrict__ lo_t,
                                          int* __restrict__ hi_t)
{
    int i = bx*256 + threadIdx.x;
    if (i < NB*SS) { lo_t[i] = 0; hi_t[i] = 0; }
}

__device__ __forceinline__ void initT_body(int bx, const float* __restrict__ cx,
                                           const float* __restrict__ tw,
                                           const float* __restrict__ tb,
                                           float* __restrict__ T)
{
    int i = bx * 256 + threadIdx.x;
    if (i >= NB*SS*32) return;
    int row = i >> 5;
    int k = (i & 31) << 2;
    float t = cx[row];
    float4 r;
    r.x = sinf(t*tw[k+0] + tb[k+0]);
    r.y = sinf(t*tw[k+1] + tb[k+1]);
    r.z = sinf(t*tw[k+2] + tb[k+2]);
    r.w = sinf(t*tw[k+3] + tb[k+3]);
    *(float4*)(T + (size_t)row*NKD + k) = r;
}

__device__ __forceinline__ void initC_body(int bx, const float* __restrict__ cw,
                                           const float* __restrict__ cb,
                                           float* __restrict__ C)
{
    int i = bx * 256 + threadIdx.x;
    if (i >= NB*NDV*32) return;
    int row = i >> 5;
    int c = row % NDV;
    int k = (i & 31) << 2;
    float4 r;
    r.x = fmaxf(cw[(size_t)c*NKD + k+0] + cb[k+0], 0.f);
    r.y = fmaxf(cw[(size_t)c*NKD + k+1] + cb[k+1], 0.f);
    r.z = fmaxf(cw[(size_t)c*NKD + k+2] + cb[k+2], 0.f);
    r.w = fmaxf(cw[(size_t)c*NKD + k+3] + cb[k+3], 0.f);
    *(float4*)(C + (size_t)row*NKD + k) = r;
}

template<int Kg>
__device__ __forceinline__ void prep1(const float* __restrict__ src,
                                      short* __restrict__ dst, int rel)
{
    const int per = Kg*128;
    int i = rel / per; int r2 = rel - i*per;
    int n = r2 / Kg;   int k = r2 - n*Kg;
    dst[rel] = f2bf(src[(size_t)i*per + (size_t)k*128 + n]);
}

#define W_TOTAL 933888
__device__ __forceinline__ void prepw_body(int bx,
    const float* ctq, const float* ctk, const float* ctv, const float* cto,
    const float* tcq, const float* tck, const float* tcv, const float* tco,
    const float* caq, const float* cak, const float* cav, const float* cao,
    const float* enw, short* __restrict__ arena)
{
    int idx = bx*256 + threadIdx.x;
    if (idx >= W_TOTAL) return;
    if      (idx < 49152 ) prep1<128>(ctq, arena + 0,      idx - 0);
    else if (idx < 147456) prep1<256>(ctk, arena + 49152,  idx - 49152);
    else if (idx < 245760) prep1<256>(ctv, arena + 147456, idx - 147456);
    else if (idx < 294912) prep1<128>(cto, arena + 245760, idx - 245760);
    else if (idx < 344064) prep1<128>(tcq, arena + 294912, idx - 294912);
    else if (idx < 442368) prep1<256>(tck, arena + 344064, idx - 344064);
    else if (idx < 540672) prep1<256>(tcv, arena + 442368, idx - 442368);
    else if (idx < 589824) prep1<128>(tco, arena + 540672, idx - 540672);
    else if (idx < 638976) prep1<128>(caq, arena + 589824, idx - 589824);
    else if (idx < 688128) prep1<128>(cak, arena + 638976, idx - 638976);
    else if (idx < 737280) prep1<128>(cav, arena + 688128, idx - 688128);
    else if (idx < 786432) prep1<128>(cao, arena + 737280, idx - 737280);
    else                   prep1<384>(enw, arena + 786432, idx - 786432);
}

__device__ __forceinline__ void trange_body(int bx, const int* __restrict__ tind,
                                            int* __restrict__ lo_t,
                                            int* __restrict__ hi_t, int L)
{
    int p = bx*256 + threadIdx.x;
    if (p >= NB*L) return;
    int b = p / L, l = p - b*L;
    int t = tind[p];
    if (t < 0) return;
    int tp = (l > 0) ? tind[p-1] : -999;
    int tn = (l+1 < L) ? tind[p+1] : -999;
    if (tp != t) lo_t[b*SS + t] = l;
    if (tn != t) hi_t[b*SS + t] = l+1;
}

__device__ __forceinline__ void cperm_body(int b, const int* __restrict__ cind,
                                           int* __restrict__ invp,
                                           int* __restrict__ clo,
                                           int* __restrict__ chi, int L)
{
    __shared__ int hist[NDV];
    __shared__ int base[NDV];
    __shared__ int padc, cntsh;
    const int tid = threadIdx.x;
    if (tid < NDV) hist[tid] = 0;
    if (tid == 0) padc = 0;
    __syncthreads();
    for (int l = tid; l < L; l += 256) {
        int c = cind[(size_t)b*L + l];
        if (c >= 0) atomicAdd(&hist[c], 1);
    }
    __syncthreads();
    if (tid == 0) {
        int run = 0;
        for (int c = 0; c < NDV; c++) {
            base[c] = run; clo[b*NDV + c] = run;
            run += hist[c]; chi[b*NDV + c] = run;
        }
        cntsh = run;
    }
    __syncthreads();
    if (tid < NDV) hist[tid] = 0;
    __syncthreads();
    const int cnt = cntsh;
    for (int l = tid; l < L; l += 256) {
        int c = cind[(size_t)b*L + l];
        int pos;
        if (c >= 0) pos = base[c] + atomicAdd(&hist[c], 1);
        else        pos = cnt + atomicAdd(&padc, 1);
        invp[(size_t)b*L + l] = b*L + pos;
    }
}

__device__ __forceinline__ void initU_body(int bx, const float* __restrict__ uval,
                                           const float* __restrict__ uind,
                                           const float* __restrict__ mkb,
                                           const float* __restrict__ ew,
                                           const float* __restrict__ eb,
                                           float* __restrict__ U, int BL)
{
    int i = bx * 256 + threadIdx.x;
    if (i >= BL*32) return;
    int row = i >> 5;
    int k = (i & 31) << 2;
    float uv = uval[row], ui = uind[row], m = mkb[row];
    float4 r;
    r.x = fmaxf(uv*ew[k+0] + ui*ew[NKD+k+0] + eb[k+0], 0.f) * m;
    r.y = fmaxf(uv*ew[k+1] + ui*ew[NKD+k+1] + eb[k+1], 0.f) * m;
    r.z = fmaxf(uv*ew[k+2] + ui*ew[NKD+k+2] + eb[k+2], 0.f) * m;
    r.w = fmaxf(uv*ew[k+3] + ui*ew[NKD+k+3] + eb[k+3], 0.f) * m;
    *(float4*)(U + (size_t)row*NKD + k) = r;
}

// ---------------------------------------------------------------------------
// MFMA GEMM body (M-tile 128): D = epilogue(concat(segs) @ Wt + bias)
// MODE 0: D = acc+b ; MODE 2: D = A0 + relu(acc+b) ; MODE 3: relu(A0+acc+b)*mk
// smem: >= 20480 bytes
// ---------------------------------------------------------------------------
template<int NSEG, int MODE>
__device__ __forceinline__ void mgemm_body(char* smem, int bx,
           Seg s0, Seg s1, Seg s2, const short* __restrict__ Wt,
           const float* __restrict__ bias, float* __restrict__ D,
           int M, int Lb, const float* __restrict__ mkp)
{
    short (*As)[40] = (short (*)[40])smem;
    short (*Bs)[40] = (short (*)[40])(smem + 10240);
    const int bm = bx * 128;
    const int tid = threadIdx.x;
    const int wv = tid >> 6;
    const int lane = tid & 63;
    const int quad = lane >> 4;
    const int l16 = lane & 15;
    const int K = NSEG * 128;
    floatx4 acc[2][8];
    #pragma unroll
    for (int i = 0; i < 2; i++)
        #pragma unroll
        for (int j = 0; j < 8; j++) acc[i][j] = (floatx4){0.f,0.f,0.f,0.f};

    const int arow = tid >> 1;
    const int acol = (tid & 1) * 16;
    int gmc = bm + arow; if (gmc > M-1) gmc = M-1;
    const float* rowp0 = seg_row(s0, gmc, Lb);
    const float* rowp1 = (NSEG > 1) ? seg_row(s1, gmc, Lb) : nullptr;
    const float* rowp2 = (NSEG > 2) ? seg_row(s2, gmc, Lb) : nullptr;

    for (int k0 = 0; k0 < K; k0 += 32) {
        {
            const float* rp;
            if (NSEG == 1) rp = rowp0;
            else if (NSEG == 2) rp = (k0 < 128) ? rowp0 : rowp1;
            else rp = (k0 < 128) ? rowp0 : ((k0 < 256) ? rowp1 : rowp2);
            const int ks = k0 & 127;
            const float* src = rp + ks + acol;
            float4 a0 = *(const float4*)(src);
            float4 a1 = *(const float4*)(src+4);
            float4 a2 = *(const float4*)(src+8);
            float4 a3 = *(const float4*)(src+12);
            short8 p0, p1;
            p0[0]=f2bf(a0.x); p0[1]=f2bf(a0.y); p0[2]=f2bf(a0.z); p0[3]=f2bf(a0.w);
            p0[4]=f2bf(a1.x); p0[5]=f2bf(a1.y); p0[6]=f2bf(a1.z); p0[7]=f2bf(a1.w);
            p1[0]=f2bf(a2.x); p1[1]=f2bf(a2.y); p1[2]=f2bf(a2.z); p1[3]=f2bf(a2.w);
            p1[4]=f2bf(a3.x); p1[5]=f2bf(a3.y); p1[6]=f2bf(a3.z); p1[7]=f2bf(a3.w);
            *(short8*)&As[arow][acol]   = p0;
            *(short8*)&As[arow][acol+8] = p1;
        }
        {
            const short* src = Wt + (size_t)arow*K + k0 + acol;
            *(short8*)&Bs[arow][acol]   = *(const short8*)(src);
            *(short8*)&Bs[arow][acol+8] = *(const short8*)(src+8);
        }
        __syncthreads();
        short8 af0 = *(short8*)&As[wv*32 + l16][quad*8];
        short8 af1 = *(short8*)&As[wv*32 + 16 + l16][quad*8];
        #pragma unroll
        for (int nf = 0; nf < 8; nf++) {
            short8 bf = *(short8*)&Bs[nf*16 + l16][quad*8];
            acc[0][nf] = __builtin_amdgcn_mfma_f32_16x16x32_bf16(af0, bf, acc[0][nf], 0, 0, 0);
            acc[1][nf] = __builtin_amdgcn_mfma_f32_16x16x32_bf16(af1, bf, acc[1][nf], 0, 0, 0);
        }
        __syncthreads();
    }
    #pragma unroll
    for (int mf = 0; mf < 2; mf++) {
        #pragma unroll
        for (int r = 0; r < 4; r++) {
            int gm = bm + wv*32 + mf*16 + quad*4 + r;
            if (gm < M) {
                float mk = (MODE == 3) ? mkp[gm] : 0.f;
                const float* res = (MODE == 2 || MODE == 3) ? seg_row(s0, gm, Lb) : nullptr;
                #pragma unroll
                for (int nf = 0; nf < 8; nf++) {
                    int gn = nf*16 + l16;
                    float val = acc[mf][nf][r] + bias[gn];
                    if (MODE == 2) val = res[gn] + fmaxf(val, 0.f);
                    else if (MODE == 3) val = fmaxf(res[gn] + val, 0.f) * mk;
                    D[(size_t)gm*NKD + gn] = val;
                }
            }
        }
    }
}

// ---------------------------------------------------------------------------
// Dual-output KV GEMM body (M-tile 64): packed bf16 (k | v<<16); optional Q.
// smem: >= 25600 bytes (35840 if HASQ)
// ---------------------------------------------------------------------------
template<int NSEG, bool HASQ>
__device__ __forceinline__ void mgemm_kv_body(char* smem, int bx,
              Seg s0, Seg s1,
              const short* __restrict__ Wk, const float* __restrict__ bk,
              const short* __restrict__ Wv, const float* __restrict__ bv,
              const short* __restrict__ Wq, const float* __restrict__ bq,
              float* __restrict__ Qd,
              unsigned* __restrict__ KV, int M, int Lb, const int* __restrict__ rmap)
{
    short (*As)[40] = (short (*)[40])smem;
    short (*Bk_)[40] = (short (*)[40])(smem + 5120);
    short (*Bv_)[40] = (short (*)[40])(smem + 15360);
    short (*Bq_)[40] = (short (*)[40])(smem + 25600);
    const int bm = bx * 64;
    const int tid = threadIdx.x;
    const int wv = tid >> 6;
    const int lane = tid & 63;
    const int quad = lane >> 4;
    const int l16 = lane & 15;
    const int K = NSEG * 128;
    floatx4 acck[8], accv[8], accq[8];
    #pragma unroll
    for (int j = 0; j < 8; j++) {
        acck[j] = (floatx4){0.f,0.f,0.f,0.f};
        accv[j] = (floatx4){0.f,0.f,0.f,0.f};
        if (HASQ) accq[j] = (floatx4){0.f,0.f,0.f,0.f};
    }

    const int arow = tid >> 2;
    const int acol = (tid & 3) * 8;
    const int brow = tid >> 1;
    const int bcol = (tid & 1) * 16;
    int gmc = bm + arow; if (gmc > M-1) gmc = M-1;
    const float* rowp0 = seg_row(s0, gmc, Lb);
    const float* rowp1 = (NSEG > 1) ? seg_row(s1, gmc, Lb) : nullptr;

    for (int k0 = 0; k0 < K; k0 += 32) {
        {
            const float* rp = (NSEG == 1) ? rowp0 : ((k0 < 128) ? rowp0 : rowp1);
            const int ks = k0 & 127;
            const float* src = rp + ks + acol;
            float4 a0 = *(const float4*)(src);
            float4 a1 = *(const float4*)(src+4);
            short8 p0;
            p0[0]=f2bf(a0.x); p0[1]=f2bf(a0.y); p0[2]=f2bf(a0.z); p0[3]=f2bf(a0.w);
            p0[4]=f2bf(a1.x); p0[5]=f2bf(a1.y); p0[6]=f2bf(a1.z); p0[7]=f2bf(a1.w);
            *(short8*)&As[arow][acol] = p0;
        }
        {
            const short* sk = Wk + (size_t)brow*K + k0 + bcol;
            *(short8*)&Bk_[brow][bcol]   = *(const short8*)(sk);
            *(short8*)&Bk_[brow][bcol+8] = *(const short8*)(sk+8);
            const short* sv = Wv + (size_t)brow*K + k0 + bcol;
            *(short8*)&Bv_[brow][bcol]   = *(const short8*)(sv);
            *(short8*)&Bv_[brow][bcol+8] = *(const short8*)(sv+8);
            if (HASQ) {
                const short* sq = Wq + (size_t)brow*K + k0 + bcol;
                *(short8*)&Bq_[brow][bcol]   = *(const short8*)(sq);
                *(short8*)&Bq_[brow][bcol+8] = *(const short8*)(sq+8);
            }
        }
        __syncthreads();
        short8 af = *(short8*)&As[wv*16 + l16][quad*8];
        #pragma unroll
        for (int nf = 0; nf < 8; nf++) {
            short8 bfk = *(short8*)&Bk_[nf*16 + l16][quad*8];
            acck[nf] = __builtin_amdgcn_mfma_f32_16x16x32_bf16(af, bfk, acck[nf], 0, 0, 0);
            short8 bfv = *(short8*)&Bv_[nf*16 + l16][quad*8];
            accv[nf] = __builtin_amdgcn_mfma_f32_16x16x32_bf16(af, bfv, accv[nf], 0, 0, 0);
            if (HASQ) {
                short8 bfq = *(short8*)&Bq_[nf*16 + l16][quad*8];
                accq[nf] = __builtin_amdgcn_mfma_f32_16x16x32_bf16(af, bfq, accq[nf], 0, 0, 0);
            }
        }
        __syncthreads();
    }
    #pragma unroll
    for (int r = 0; r < 4; r++) {
        int gm = bm + wv*16 + quad*4 + r;
        if (gm < M) {
            int orow = rmap ? rmap[gm] : gm;
            #pragma unroll
            for (int nf = 0; nf < 8; nf++) {
                int gn = nf*16 + l16;
                float kf = acck[nf][r] + bk[gn];
                float vf = accv[nf][r] + bv[gn];
                unsigned pk = (unsigned)(unsigned short)f2bf(kf)
                            | ((unsigned)(unsigned short)f2bf(vf) << 16);
                KV[(size_t)orow*NKD + gn] = pk;
                if (HASQ) Qd[(size_t)gm*NKD + gn] = accq[nf][r] + bq[gn];
            }
        }
    }
}

// ---------------------------------------------------------------------------
// Segmented attention body on packed bf16 KV. SPLIT waves per (b,q,h).
// ---------------------------------------------------------------------------
template<int SPLIT>
__device__ __forceinline__ void sattn_body(int bx,
                  const float* __restrict__ q, const unsigned* __restrict__ kvb,
                  float* __restrict__ o, int nq, int nkv,
                  const int* __restrict__ lo_arr, const int* __restrict__ hi_arr)
{
    __shared__ float sm_m[4], sm_s[4], sm_a[4][DH];
    const int wvid = threadIdx.x >> 6;
    int gtask = bx * 4 + wvid;
    int task = gtask / SPLIT;
    int part = gtask % SPLIT;
    if (task >= NB * nq * NHD) return;
    const int h = task & 3;
    const int bq = task >> 2;
    const int qi = bq % nq;
    const int b = bq / nq;
    const int lane = threadIdx.x & 63;
    const int d = lane & 31;
    const int half = lane >> 5;
    int lo = lo_arr ? lo_arr[b*nq + qi] : 0;
    int hi = hi_arr ? hi_arr[b*nq + qi] : nkv;
    if (SPLIT == 2) {
        int mid = lo + ((hi - lo + 1) >> 1);
        if (part == 0) hi = mid; else lo = mid;
    }
    const float scale = 0.088388347648318447f;   // 1/sqrt(128)

    const float qv = q[((size_t)(b*nq + qi))*NKD + h*DH + d];
    const unsigned* kb = kvb + (size_t)b*nkv*NKD + h*DH + d;

    float m = -INFINITY, ssum = 0.f, acc = 0.f;
    for (int l0 = lo; l0 < hi; l0 += 8) {
        unsigned ur[4];
        #pragma unroll
        for (int j = 0; j < 4; j++) {
            int l = l0 + 2*j + half;
            bool ok = (l < hi);
            ur[j] = ok ? kb[(size_t)l*NKD] : 0u;
        }
        #pragma unroll
        for (int j = 0; j < 4; j++) {
            int l = l0 + 2*j + half;
            float kr = bf2f(ur[j] & 0xffffu);
            float vr = bf2f(ur[j] >> 16);
            float partial = qv * kr;
            #pragma unroll
            for (int off = 16; off; off >>= 1) partial += __shfl_xor(partial, off);
            float s = partial * scale;
            if (l < hi) {
                float mn = fmaxf(m, s);
                float corr = __expf(m - mn);
                float p = __expf(s - mn);
                ssum = ssum * corr + p;
                acc  = acc  * corr + p * vr;
                m = mn;
            }
        }
    }
    float mo = __shfl_xor(m, 32);
    float M = fmaxf(m, mo);
    float corr = (m > -1e30f) ? __expf(m - M) : 0.f;
    ssum *= corr; acc *= corr;
    ssum += __shfl_xor(ssum, 32);
    acc  += __shfl_xor(acc, 32);

    if (SPLIT == 1) {
        if (half == 0) {
            float res = (ssum > 0.f) ? acc / ssum : 0.f;
            o[((size_t)(b*nq + qi))*NKD + h*DH + d] = qv + res;
        }
    } else {
        if (lane == 0) { sm_m[wvid] = M; sm_s[wvid] = ssum; }
        if (lane < DH) sm_a[wvid][lane] = acc;
        __syncthreads();
        if (part == 0 && lane < DH) {
            float m2 = sm_m[wvid+1], s2 = sm_s[wvid+1], a2 = sm_a[wvid+1][lane];
            float M2 = fmaxf(M, m2);
            float c1 = (M  > -1e30f) ? __expf(M  - M2) : 0.f;
            float c2 = (m2 > -1e30f) ? __expf(m2 - M2) : 0.f;
            float S = ssum * c1 + s2 * c2;
            float A = acc  * c1 + a2 * c2;
            float res = (S > 0.f) ? A / S : 0.f;
            o[((size_t)(b*nq + qi))*NKD + h*DH + lane] = qv + res;
        }
    }
}

// ===========================================================================
// Kernels
// ===========================================================================

// Pre-phase 1: compactA + zero_ranges + initT + initC + prep_weights
__global__ __launch_bounds__(256)
void k_pre1(const float* maskp, int* chunkcnt, int* lo_t, int* hi_t,
            const float* cx, const float* tw, const float* tb, float* T,
            const float* cw, const float* cb, float* C,
            const float* ctq, const float* ctk, const float* ctv, const float* cto,
            const float* tcq, const float* tck, const float* tcv, const float* tco,
            const float* caq, const float* cak, const float* cav, const float* cao,
            const float* enw, short* arena)
{
    int bx = blockIdx.x;
    if (bx < NB*NCH)            compactA_body(bx, maskp, chunkcnt);
    else if (bx < NB*NCH + 16)  zero_body(bx - NB*NCH, lo_t, hi_t);
    else if (bx < NB*NCH + 16 + 512) initT_body(bx - NB*NCH - 16, cx, tw, tb, T);
    else if (bx < NB*NCH + 16 + 512 + 84) initC_body(bx - NB*NCH - 16 - 512, cw, cb, C);
    else prepw_body(bx - NB*NCH - 16 - 512 - 84,
                    ctq, ctk, ctv, cto, tcq, tck, tcv, tco,
                    caq, cak, cav, cao, enw, arena);
}

__global__ __launch_bounds__(64)
void k_compactB(const int* __restrict__ chunkcnt, int* __restrict__ chunkoff,
                int* __restrict__ cntb)
{
    const int b = blockIdx.x, lane = threadIdx.x;
    int v = (lane < NCH) ? chunkcnt[b*NCH + lane] : 0;
    int x = v;
    #pragma unroll
    for (int off = 1; off < 64; off <<= 1) {
        int y = __shfl_up(x, off);
        if (lane >= off) x += y;
    }
    if (lane < NCH) chunkoff[b*NCH + lane] = x - v;
    if (lane == 63) cntb[b] = x;
}

__global__ __launch_bounds__(256)
void k_compactC(const float* __restrict__ cx, const float* __restrict__ value,
              const float* __restrict__ maskp, const float* __restrict__ tval,
              const float* __restrict__ tmaskp, const float* __restrict__ w0p,
              const float* __restrict__ b0p,
              const int* __restrict__ chunkoff, const int* __restrict__ cntb, int L,
              int* __restrict__ tind, int* __restrict__ cind,
              float* __restrict__ mkb, float* __restrict__ uval,
              float* __restrict__ uind,
              float* __restrict__ outTU, float* __restrict__ outTM)
{
    const int blk = blockIdx.x;
    const int b = blk / NCH, ch = blk % NCH;
    const int tid = threadIdx.x, lane = tid & 63, wv = tid >> 6;
    const int idx = ch * 256 + tid;
    const int s = idx / NDV, c = idx % NDV;
    float mval = (c < DIMV) ? maskp[((size_t)b*SS + s)*DIMV + c] : 1.0f;
    int m = (mval != 0.0f) ? 1 : 0;
    int x = m;
    #pragma unroll
    for (int off = 1; off < 64; off <<= 1) {
        int y = __shfl_up(x, off);
        if (lane >= off) x += y;
    }
    __shared__ int wsum[4];
    if (lane == 63) wsum[wv] = x;
    __syncthreads();
    int wbase = 0;
    for (int w = 0; w < wv; w++) wbase += wsum[w];
    const int excl = x - m + wbase;
    const int vbefore = chunkoff[b*NCH + ch] + excl;
    const int cnt = cntb[b];
    const int pos = m ? vbefore : (cnt + (idx - vbefore));
    if (pos < L) {
        const float w0 = w0p[0], b0 = b0p[0];
        float te = w0 * cx[(size_t)b*SS + s] + b0;
        float vf, tvf, tmf;
        if (c < DIMV) {
            size_t o = ((size_t)b*SS + s)*DIMV + c;
            vf = value[o]; tvf = tval[o]; tmf = tmaskp[o];
        } else { vf = te; tvf = te; tmf = 0.0f; }
        size_t p = (size_t)b*L + pos;
        if (m) {
            tind[p] = s; cind[p] = c; mkb[p] = 1.0f;
            uval[p] = vf; uind[p] = tmf;
            outTU[p] = tvf; outTM[p] = tmf;
        } else {
            tind[p] = -1; cind[p] = -1; mkb[p] = 0.0f;
            uval[p] = 0.0f; uind[p] = 1.0f;
            outTU[p] = 0.0f; outTM[p] = 0.0f;
        }
    }
}

// Pre-phase 4: trange + cperm + initU
__global__ __launch_bounds__(256)
void k_pre4(const int* tind, int* lo_t, int* hi_t, int L, int gTr,
            const int* cind, int* invp, int* clo, int* chi,
            const float* uval, const float* uind, const float* mkb,
            const float* ew, const float* eb, float* U, int BL)
{
    int bx = blockIdx.x;
    if (bx < gTr) trange_body(bx, tind, lo_t, hi_t, L);
    else if (bx < gTr + NB) cperm_body(bx - gTr, cind, invp, clo, chi, L);
    else initU_body(bx - gTr - NB, uval, uind, mkb, ew, eb, U, BL);
}

// Phase 1: ct-kv + ct-q + tc-kv + tc-q + en   (all read {T1,C1,U})
__global__ __launch_bounds__(256)
void k_phase1(int g0, int g1, int g2, int g3,
              const float* T1, const int* tind, const float* U,
              const short* wkct, const float* bkct, const short* wvct, const float* bvct,
              unsigned* KVct, const int* invp,
              const float* C1, const short* wqct, const float* bqct, float* qC,
              const int* cind,
              const short* wktc, const float* bktc, const short* wvtc, const float* bvtc,
              unsigned* KVtc,
              const short* wqtc, const float* bqtc, float* qT,
              const short* wen, const float* ben, float* Unew, const float* mkb,
              int BL, int L)
{
    __shared__ __align__(16) char smem[25600];
    int bx = blockIdx.x;
    if (bx < g0) {
        mgemm_kv_body<2,false>(smem, bx, Seg{T1,tind,SS}, Seg{U,nullptr,0},
            wkct, bkct, wvct, bvct, nullptr, nullptr, nullptr, KVct, BL, L, invp);
    } else if (bx < g0+g1) {
        mgemm_body<1,0>(smem, bx-g0, Seg{C1,nullptr,0}, Seg{nullptr,nullptr,0},
            Seg{nullptr,nullptr,0}, wqct, bqct, qC, NB*NDV, 1, nullptr);
    } else if (bx < g0+g1+g2) {
        mgemm_kv_body<2,false>(smem, bx-g0-g1, Seg{C1,cind,NDV}, Seg{U,nullptr,0},
            wktc, bktc, wvtc, bvtc, nullptr, nullptr, nullptr, KVtc, BL, L, nullptr);
    } else if (bx < g0+g1+g2+g3) {
        mgemm_body<1,0>(smem, bx-g0-g1-g2, Seg{T1,nullptr,0}, Seg{nullptr,nullptr,0},
            Seg{nullptr,nullptr,0}, wqtc, bqtc, qT, NB*SS, 1, nullptr);
    } else {
        mgemm_body<3,3>(smem, bx-g0-g1-g2-g3, Seg{U,nullptr,0}, Seg{T1,tind,SS},
            Seg{C1,cind,NDV}, wen, ben, Unew, BL, L, mkb);
    }
}

// Phase 2: sattn ct + sattn tc
__global__ __launch_bounds__(256)
void k_phase2(int g0, const float* qC, const unsigned* KVct, float* oC,
              const int* clo, const int* chi, int L,
              const float* qT, const unsigned* KVtc, float* oT,
              const int* lo_t, const int* hi_t)
{
    int bx = blockIdx.x;
    if (bx < g0) sattn_body<2>(bx, qC, KVct, oC, NDV, L, clo, chi);
    else         sattn_body<1>(bx-g0, qT, KVtc, oT, SS, L, lo_t, hi_t);
}

// Phase 3: o-proj ct (-> C2) + o-proj tc (-> T2)
__global__ __launch_bounds__(256)
void k_phase3(int g0, const float* oC, const short* woct, const float* boct, float* C2,
              const float* oT, const short* wotc, const float* botc, float* T2b)
{
    __shared__ __align__(16) char smem[20480];
    int bx = blockIdx.x;
    if (bx < g0)
        mgemm_body<1,2>(smem, bx, Seg{oC,nullptr,0}, Seg{nullptr,nullptr,0},
            Seg{nullptr,nullptr,0}, woct, boct, C2, NB*NDV, 1, nullptr);
    else
        mgemm_body<1,2>(smem, bx-g0, Seg{oT,nullptr,0}, Seg{nullptr,nullptr,0},
            Seg{nullptr,nullptr,0}, wotc, botc, T2b, NB*SS, 1, nullptr);
}

// ca phases
__global__ __launch_bounds__(256)
void k_ca_kvq(const float* C2, const short* wk, const float* bk,
              const short* wv, const float* bv, const short* wq, const float* bq,
              float* qC, unsigned* KV)
{
    __shared__ __align__(16) char smem[35840];
    mgemm_kv_body<1,true>(smem, blockIdx.x, Seg{C2,nullptr,0}, Seg{nullptr,nullptr,0},
                          wk, bk, wv, bv, wq, bq, qC, KV, NB*NDV, 1, nullptr);
}

__global__ __launch_bounds__(256)
void k_ca_attn(const float* qC, const unsigned* kv, float* oC)
{
    sattn_body<2>(blockIdx.x, qC, kv, oC, NDV, NDV, nullptr, nullptr);
}

__global__ __launch_bounds__(256)
void k_ca_oproj(const float* oC, const short* wo, const float* bo, float* C1)
{
    __shared__ __align__(16) char smem[20480];
    mgemm_body<1,2>(smem, blockIdx.x, Seg{oC,nullptr,0}, Seg{nullptr,nullptr,0},
                    Seg{nullptr,nullptr,0}, wo, bo, C1, NB*NDV, 1, nullptr);
}

// Final head with inline gathers of k_t, k_c
__global__ __launch_bounds__(256)
void k_out(const float* __restrict__ U, const float* __restrict__ T1,
           const float* __restrict__ C1, const int* __restrict__ tind,
           const int* __restrict__ cind, const float* __restrict__ ow,
           const float* __restrict__ obp, float* __restrict__ out,
           int BL, int L)
{
    int row = blockIdx.x * 4 + (threadIdx.x >> 6);
    int lane = threadIdx.x & 63;
    if (row >= BL) return;
    int b = row / L;
    int ti = tind[row]; if (ti < 0) ti = 0;
    int ci = cind[row]; if (ci < 0) ci = 0;
    const float* u = U + (size_t)row*NKD;
    const float* a = T1 + ((size_t)(b*SS + ti))*NKD;
    const float* c = C1 + ((size_t)(b*NDV + ci))*NKD;
    float s = u[lane]*ow[lane]       + u[lane+64]*ow[lane+64]
            + a[lane]*ow[128+lane]   + a[lane+64]*ow[192+lane]
            + c[lane]*ow[256+lane]   + c[lane+64]*ow[320+lane];
    #pragma unroll
    for (int off = 32; off; off >>= 1) s += __shfl_down(s, off);
    if (lane == 0) out[row] = s + obp[0];
}

// ---------------------------------------------------------------------------
extern "C" void kernel_launch(void* const* d_in, const int* in_sizes, int n_in,
                              void* d_out, int out_size, void* d_ws, size_t ws_size,
                              hipStream_t stream)
{
    const float* cx     = (const float*)d_in[0];
    const float* value  = (const float*)d_in[1];
    const float* maskp  = (const float*)d_in[2];
    const float* tval   = (const float*)d_in[3];
    const float* tmaskp = (const float*)d_in[4];
    const float* w0     = (const float*)d_in[5];
    const float* b0     = (const float*)d_in[6];
    const float* edge_w = (const float*)d_in[7];
    const float* edge_b = (const float*)d_in[8];
    const float* chan_w = (const float*)d_in[9];
    const float* chan_b = (const float*)d_in[10];
    const float* time_w = (const float*)d_in[11];
    const float* time_b = (const float*)d_in[12];
    const float* ct_wq = (const float*)d_in[13];
    const float* ct_bq = (const float*)d_in[14];
    const float* ct_wk = (const float*)d_in[15];
    const float* ct_bk = (const float*)d_in[16];
    const float* ct_wv = (const float*)d_in[17];
    const float* ct_bv = (const float*)d_in[18];
    const float* ct_wo = (const float*)d_in[19];
    const float* ct_bo = (const float*)d_in[20];
    const float* tc_wq = (const float*)d_in[21];
    const float* tc_bq = (const float*)d_in[22];
    const float* tc_wk = (const float*)d_in[23];
    const float* tc_bk = (const float*)d_in[24];
    const float* tc_wv = (const float*)d_in[25];
    const float* tc_bv = (const float*)d_in[26];
    const float* tc_wo = (const float*)d_in[27];
    const float* tc_bo = (const float*)d_in[28];
    const float* ca_wq = (const float*)d_in[29];
    const float* ca_bq = (const float*)d_in[30];
    const float* ca_wk = (const float*)d_in[31];
    const float* ca_bk = (const float*)d_in[32];
    const float* ca_wv = (const float*)d_in[33];
    const float* ca_bv = (const float*)d_in[34];
    const float* ca_wo = (const float*)d_in[35];
    const float* ca_bo = (const float*)d_in[36];
    const float* en_w  = (const float*)d_in[37];
    const float* en_b  = (const float*)d_in[38];
    const float* out_w = (const float*)d_in[39];
    const float* out_b = (const float*)d_in[40];

    const int BL = out_size / 3;     // B * full_len
    const int L  = BL / NB;

    char* p = (char*)d_ws;
    auto alloc = [&](size_t n) { char* r = p; p += (n + 255) & ~(size_t)255; return r; };
    int*      tind   = (int*)  alloc((size_t)BL*4);
    int*      cind   = (int*)  alloc((size_t)BL*4);
    float*    mkb    = (float*)alloc((size_t)BL*4);
    float*    uval   = (float*)alloc((size_t)BL*4);
    float*    uind   = (float*)alloc((size_t)BL*4);
    int*      lo_t   = (int*)  alloc((size_t)NB*SS*4);
    int*      hi_t   = (int*)  alloc((size_t)NB*SS*4);
    int*      clo    = (int*)  alloc((size_t)NB*NDV*4);
    int*      chi    = (int*)  alloc((size_t)NB*NDV*4);
    int*      invp   = (int*)  alloc((size_t)BL*4);
    int*      chunkc = (int*)  alloc((size_t)NB*NCH*4);
    int*      chunko = (int*)  alloc((size_t)NB*NCH*4);
    int*      cntb   = (int*)  alloc((size_t)NB*4);
    short*    waren  = (short*)alloc((size_t)W_TOTAL*2);
    float*    U    = (float*)alloc((size_t)BL*NKD*4);
    float*    Unew = (float*)alloc((size_t)BL*NKD*4);
    unsigned* KVct = (unsigned*)alloc((size_t)BL*NKD*4);
    unsigned* KVtc = (unsigned*)alloc((size_t)BL*NKD*4);
    unsigned* kvCa = (unsigned*)alloc((size_t)NB*NDV*NKD*4);
    float*    T1   = (float*)alloc((size_t)NB*SS*NKD*4);
    float*    T2b  = (float*)alloc((size_t)NB*SS*NKD*4);
    float*    qT   = (float*)alloc((size_t)NB*SS*NKD*4);
    float*    oT   = (float*)alloc((size_t)NB*SS*NKD*4);
    float*    C1   = (float*)alloc((size_t)NB*NDV*NKD*4);
    float*    C2   = (float*)alloc((size_t)NB*NDV*NKD*4);
    float*    qC   = (float*)alloc((size_t)NB*NDV*NKD*4);
    float*    oC   = (float*)alloc((size_t)NB*NDV*NKD*4);

    float* outMain = (float*)d_out;
    float* outTU = outMain + BL;
    float* outTM = outMain + 2*BL;

    // weight arena offsets (shorts)
    const size_t OCTQ=0, OCTK=49152, OCTV=147456, OCTO=245760;
    const size_t OTCQ=294912, OTCK=344064, OTCV=442368, OTCO=540672;
    const size_t OCAQ=589824, OCAK=638976, OCAV=688128, OCAO=737280, OEN=786432;

    // Pre-phases (4 dispatches)
    k_pre1<<<NB*NCH + 16 + 512 + 84 + W_TOTAL/256, 256, 0, stream>>>(
        maskp, chunkc, lo_t, hi_t, cx, time_w, time_b, T1, chan_w, chan_b, C1,
        ct_wq, ct_wk, ct_wv, ct_wo, tc_wq, tc_wk, tc_wv, tc_wo,
        ca_wq, ca_wk, ca_wv, ca_wo, en_w, waren);
    k_compactB<<<NB, 64, 0, stream>>>(chunkc, chunko, cntb);
    k_compactC<<<NB*NCH, 256, 0, stream>>>(cx, value, maskp, tval, tmaskp, w0, b0,
                                           chunko, cntb, L, tind, cind, mkb, uval, uind,
                                           outTU, outTM);
    {
        const int gTr = (NB*L + 255)/256;
        const int gU  = (BL*32 + 255)/256;
        k_pre4<<<gTr + NB + gU, 256, 0, stream>>>(
            tind, lo_t, hi_t, L, gTr, cind, invp, clo, chi,
            uval, uind, mkb, edge_w, edge_b, U, BL);
    }

    const int gBL  = (BL + 127)/128;
    const int gKV  = (BL + 63)/64;
    const int gC   = (NB*NDV + 127)/128;
    const int gT   = (NB*SS + 127)/128;
    const int gCa  = (NB*NDV + 63)/64;
    const int aC2  = NB*NDV*NHD*2/4;     // SPLIT=2
    const int aTC  = NB*SS*NHD/4;        // SPLIT=1

    for (int i = 0; i < NLAY; i++) {
        const size_t bOff = (size_t)i*NKD;
        const short* wq_ct = waren + OCTQ + (size_t)i*128*128;
        const short* wk_ct = waren + OCTK + (size_t)i*256*128;
        const short* wv_ct = waren + OCTV + (size_t)i*256*128;
        const short* wo_ct = waren + OCTO + (size_t)i*128*128;
        const short* wq_tc = waren + OTCQ + (size_t)i*128*128;
        const short* wk_tc = waren + OTCK + (size_t)i*256*128;
        const short* wv_tc = waren + OTCV + (size_t)i*256*128;
        const short* wo_tc = waren + OTCO + (size_t)i*128*128;
        const short* wq_ca = waren + OCAQ + (size_t)i*128*128;
        const short* wk_ca = waren + OCAK + (size_t)i*128*128;
        const short* wv_ca = waren + OCAV + (size_t)i*128*128;
        const short* wo_ca = waren + OCAO + (size_t)i*128*128;
        const short* w_en  = waren + OEN  + (size_t)i*384*128;

        // P1: all projections from (T1, C1, U)
        k_phase1<<<gKV + gC + gKV + gT + gBL, 256, 0, stream>>>(
            gKV, gC, gKV, gT,
            T1, tind, U,
            wk_ct, ct_bk + bOff, wv_ct, ct_bv + bOff, KVct, invp,
            C1, wq_ct, ct_bq + bOff, qC,
            cind, wk_tc, tc_bk + bOff, wv_tc, tc_bv + bOff, KVtc,
            wq_tc, tc_bq + bOff, qT,
            w_en, en_b + bOff, Unew, mkb, BL, L);
        // P2: both segmented attentions
        k_phase2<<<aC2 + aTC, 256, 0, stream>>>(
            aC2, qC, KVct, oC, clo, chi, L, qT, KVtc, oT, lo_t, hi_t);
        // P3: both o-projections
        k_phase3<<<gC + gT, 256, 0, stream>>>(
            gC, oC, wo_ct, ct_bo + bOff, C2, oT, wo_tc, tc_bo + bOff, T2b);
        // P4-P6: channel self-attention
        k_ca_kvq<<<gCa, 256, 0, stream>>>(C2, wk_ca, ca_bk + bOff,
            wv_ca, ca_bv + bOff, wq_ca, ca_bq + bOff, qC, kvCa);
        k_ca_attn<<<aC2, 256, 0, stream>>>(qC, kvCa, oC);
        k_ca_oproj<<<gC, 256, 0, stream>>>(oC, wo_ca, ca_bo + bOff, C1);

        float* t = U;  U = Unew; Unew = t;
        t = T1; T1 = T2b; T2b = t;
    }

    k_out<<<(BL + 3)/4, 256, 0, stream>>>(U, T1, C1, tind, cind,
                                          out_w, out_b, outMain, BL, L);
}

// Round 8
// 468.195 us; speedup vs baseline: 11.9748x; 1.0467x over previous
//
#include <hip/hip_runtime.h>
#include <math.h>

#define NB   16
#define SS   256
#define DIMV 41
#define NDV  42
#define NKD  128
#define NHD  4
#define DH   32
#define NLAY 3
#define TOT  (SS*NDV)   // 10752 = 42 chunks of 256
#define NCH  42

typedef __attribute__((ext_vector_type(8))) short short8;
typedef __attribute__((ext_vector_type(4))) float floatx4;

__device__ __forceinline__ short f2bf(float x) {
    unsigned u = __float_as_uint(x);
    u += 0x7fff + ((u >> 16) & 1);          // RNE f32 -> bf16
    return (short)(u >> 16);
}
__device__ __forceinline__ float bfs2f(short s) {
    return __uint_as_float(((unsigned)(unsigned short)s) << 16);
}
__device__ __forceinline__ float bf2f(unsigned s) {
    return __uint_as_float(s << 16);
}

struct Seg { const short* ptr; const int* ind; int ns; };

__device__ __forceinline__ const short* seg_row(const Seg s, int gm, int Lb) {
    if (s.ind) {
        int b = gm / Lb;
        int id = s.ind[gm]; if (id < 0) id = 0;
        return s.ptr + ((size_t)b * s.ns + (size_t)id) * NKD;
    }
    return s.ptr + (size_t)gm * NKD;
}

// ===========================================================================
// Device bodies
// ===========================================================================

__device__ __forceinline__ void compactA_body(int bx, const float* __restrict__ maskp,
                                              int* __restrict__ chunkcnt)
{
    const int b = bx / NCH, ch = bx % NCH;
    const int tid = threadIdx.x;
    const int idx = ch * 256 + tid;
    const int s = idx / NDV, c = idx % NDV;
    float m = (c < DIMV) ? maskp[((size_t)b*SS + s)*DIMV + c] : 1.0f;
    int x = (m != 0.0f) ? 1 : 0;
    #pragma unroll
    for (int off = 32; off; off >>= 1) x += __shfl_down(x, off);
    __shared__ int ws4[4];
    if ((tid & 63) == 0) ws4[tid >> 6] = x;
    __syncthreads();
    if (tid == 0) chunkcnt[bx] = ws4[0] + ws4[1] + ws4[2] + ws4[3];
}

__device__ __forceinline__ void zero_body(int bx, int* __restrict__ lo_t,
                                          int* __restrict__ hi_t)
{
    int i = bx*256 + threadIdx.x;
    if (i < NB*SS) { lo_t[i] = 0; hi_t[i] = 0; }
}

__device__ __forceinline__ void initT_body(int bx, const float* __restrict__ cx,
                                           const float* __restrict__ tw,
                                           const float* __restrict__ tb,
                                           short* __restrict__ T)
{
    int i = bx * 256 + threadIdx.x;
    if (i >= NB*SS*16) return;
    int row = i >> 4;
    int k = (i & 15) << 3;
    float t = cx[row];
    short8 r;
    #pragma unroll
    for (int j = 0; j < 8; j++) r[j] = f2bf(sinf(t*tw[k+j] + tb[k+j]));
    *(short8*)(T + (size_t)row*NKD + k) = r;
}

__device__ __forceinline__ void initC_body(int bx, const float* __restrict__ cw,
                                           const float* __restrict__ cb,
                                           short* __restrict__ C)
{
    int i = bx * 256 + threadIdx.x;
    if (i >= NB*NDV*16) return;
    int row = i >> 4;
    int c = row % NDV;
    int k = (i & 15) << 3;
    short8 r;
    #pragma unroll
    for (int j = 0; j < 8; j++) r[j] = f2bf(fmaxf(cw[(size_t)c*NKD + k+j] + cb[k+j], 0.f));
    *(short8*)(C + (size_t)row*NKD + k) = r;
}

template<int Kg>
__device__ __forceinline__ void prep1(const float* __restrict__ src,
                                      short* __restrict__ dst, int rel)
{
    const int per = Kg*128;
    int i = rel / per; int r2 = rel - i*per;
    int n = r2 / Kg;   int k = r2 - n*Kg;
    dst[rel] = f2bf(src[(size_t)i*per + (size_t)k*128 + n]);
}

#define W_TOTAL 933888
__device__ __forceinline__ void prepw_body(int bx,
    const float* ctq, const float* ctk, const float* ctv, const float* cto,
    const float* tcq, const float* tck, const float* tcv, const float* tco,
    const float* caq, const float* cak, const float* cav, const float* cao,
    const float* enw, short* __restrict__ arena)
{
    int idx = bx*256 + threadIdx.x;
    if (idx >= W_TOTAL) return;
    if      (idx < 49152 ) prep1<128>(ctq, arena + 0,      idx - 0);
    else if (idx < 147456) prep1<256>(ctk, arena + 49152,  idx - 49152);
    else if (idx < 245760) prep1<256>(ctv, arena + 147456, idx - 147456);
    else if (idx < 294912) prep1<128>(cto, arena + 245760, idx - 245760);
    else if (idx < 344064) prep1<128>(tcq, arena + 294912, idx - 294912);
    else if (idx < 442368) prep1<256>(tck, arena + 344064, idx - 344064);
    else if (idx < 540672) prep1<256>(tcv, arena + 442368, idx - 442368);
    else if (idx < 589824) prep1<128>(tco, arena + 540672, idx - 540672);
    else if (idx < 638976) prep1<128>(caq, arena + 589824, idx - 589824);
    else if (idx < 688128) prep1<128>(cak, arena + 638976, idx - 638976);
    else if (idx < 737280) prep1<128>(cav, arena + 688128, idx - 688128);
    else if (idx < 786432) prep1<128>(cao, arena + 737280, idx - 737280);
    else                   prep1<384>(enw, arena + 786432, idx - 786432);
}

__device__ __forceinline__ void trange_body(int bx, const int* __restrict__ tind,
                                            int* __restrict__ lo_t,
                                            int* __restrict__ hi_t, int L)
{
    int p = bx*256 + threadIdx.x;
    if (p >= NB*L) return;
    int b = p / L, l = p - b*L;
    int t = tind[p];
    if (t < 0) return;
    int tp = (l > 0) ? tind[p-1] : -999;
    int tn = (l+1 < L) ? tind[p+1] : -999;
    if (tp != t) lo_t[b*SS + t] = l;
    if (tn != t) hi_t[b*SS + t] = l+1;
}

__device__ __forceinline__ void cperm_body(int b, const int* __restrict__ cind,
                                           int* __restrict__ invp,
                                           int* __restrict__ clo,
                                           int* __restrict__ chi, int L)
{
    __shared__ int hist[NDV];
    __shared__ int base[NDV];
    __shared__ int padc, cntsh;
    const int tid = threadIdx.x;
    if (tid < NDV) hist[tid] = 0;
    if (tid == 0) padc = 0;
    __syncthreads();
    for (int l = tid; l < L; l += 256) {
        int c = cind[(size_t)b*L + l];
        if (c >= 0) atomicAdd(&hist[c], 1);
    }
    __syncthreads();
    if (tid == 0) {
        int run = 0;
        for (int c = 0; c < NDV; c++) {
            base[c] = run; clo[b*NDV + c] = run;
            run += hist[c]; chi[b*NDV + c] = run;
        }
        cntsh = run;
    }
    __syncthreads();
    if (tid < NDV) hist[tid] = 0;
    __syncthreads();
    const int cnt = cntsh;
    for (int l = tid; l < L; l += 256) {
        int c = cind[(size_t)b*L + l];
        int pos;
        if (c >= 0) pos = base[c] + atomicAdd(&hist[c], 1);
        else        pos = cnt + atomicAdd(&padc, 1);
        invp[(size_t)b*L + l] = b*L + pos;
    }
}

__device__ __forceinline__ void initU_body(int bx, const float* __restrict__ uval,
                                           const float* __restrict__ uind,
                                           const float* __restrict__ mkb,
                                           const float* __restrict__ ew,
                                           const float* __restrict__ eb,
                                           short* __restrict__ U, int BL)
{
    int i = bx * 256 + threadIdx.x;
    if (i >= BL*16) return;
    int row = i >> 4;
    int k = (i & 15) << 3;
    float uv = uval[row], ui = uind[row], m = mkb[row];
    short8 r;
    #pragma unroll
    for (int j = 0; j < 8; j++)
        r[j] = f2bf(fmaxf(uv*ew[k+j] + ui*ew[NKD+k+j] + eb[k+j], 0.f) * m);
    *(short8*)(U + (size_t)row*NKD + k) = r;
}

// ---------------------------------------------------------------------------
// MFMA GEMM body (M-tile 128), bf16 activations in/out.
// MODE 0: D = acc+b ; MODE 2: D = A0 + relu(acc+b) ; MODE 3: relu(A0+acc+b)*mk
// smem >= 20480
// ---------------------------------------------------------------------------
template<int NSEG, int MODE>
__device__ __forceinline__ void mgemm_body(char* smem, int bx,
           Seg s0, Seg s1, Seg s2, const short* __restrict__ Wt,
           const float* __restrict__ bias, short* __restrict__ D,
           int M, int Lb, const float* __restrict__ mkp)
{
    short (*As)[40] = (short (*)[40])smem;
    short (*Bs)[40] = (short (*)[40])(smem + 10240);
    const int bm = bx * 128;
    const int tid = threadIdx.x;
    const int wv = tid >> 6;
    const int lane = tid & 63;
    const int quad = lane >> 4;
    const int l16 = lane & 15;
    const int K = NSEG * 128;
    floatx4 acc[2][8];
    #pragma unroll
    for (int i = 0; i < 2; i++)
        #pragma unroll
        for (int j = 0; j < 8; j++) acc[i][j] = (floatx4){0.f,0.f,0.f,0.f};

    const int arow = tid >> 1;
    const int acol = (tid & 1) * 16;
    int gmc = bm + arow; if (gmc > M-1) gmc = M-1;
    const short* rowp0 = seg_row(s0, gmc, Lb);
    const short* rowp1 = (NSEG > 1) ? seg_row(s1, gmc, Lb) : nullptr;
    const short* rowp2 = (NSEG > 2) ? seg_row(s2, gmc, Lb) : nullptr;

    for (int k0 = 0; k0 < K; k0 += 32) {
        {
            const short* rp;
            if (NSEG == 1) rp = rowp0;
            else if (NSEG == 2) rp = (k0 < 128) ? rowp0 : rowp1;
            else rp = (k0 < 128) ? rowp0 : ((k0 < 256) ? rowp1 : rowp2);
            const int ks = k0 & 127;
            const short* src = rp + ks + acol;
            *(short8*)&As[arow][acol]   = *(const short8*)(src);
            *(short8*)&As[arow][acol+8] = *(const short8*)(src+8);
        }
        {
            const short* src = Wt + (size_t)arow*K + k0 + acol;
            *(short8*)&Bs[arow][acol]   = *(const short8*)(src);
            *(short8*)&Bs[arow][acol+8] = *(const short8*)(src+8);
        }
        __syncthreads();
        short8 af0 = *(short8*)&As[wv*32 + l16][quad*8];
        short8 af1 = *(short8*)&As[wv*32 + 16 + l16][quad*8];
        #pragma unroll
        for (int nf = 0; nf < 8; nf++) {
            short8 bf = *(short8*)&Bs[nf*16 + l16][quad*8];
            acc[0][nf] = __builtin_amdgcn_mfma_f32_16x16x32_bf16(af0, bf, acc[0][nf], 0, 0, 0);
            acc[1][nf] = __builtin_amdgcn_mfma_f32_16x16x32_bf16(af1, bf, acc[1][nf], 0, 0, 0);
        }
        __syncthreads();
    }
    #pragma unroll
    for (int mf = 0; mf < 2; mf++) {
        #pragma unroll
        for (int r = 0; r < 4; r++) {
            int gm = bm + wv*32 + mf*16 + quad*4 + r;
            if (gm < M) {
                float mk = (MODE == 3) ? mkp[gm] : 0.f;
                const short* res = (MODE == 2 || MODE == 3) ? seg_row(s0, gm, Lb) : nullptr;
                #pragma unroll
                for (int nf = 0; nf < 8; nf++) {
                    int gn = nf*16 + l16;
                    float val = acc[mf][nf][r] + bias[gn];
                    if (MODE == 2) val = bfs2f(res[gn]) + fmaxf(val, 0.f);
                    else if (MODE == 3) val = fmaxf(bfs2f(res[gn]) + val, 0.f) * mk;
                    D[(size_t)gm*NKD + gn] = f2bf(val);
                }
            }
        }
    }
}

// ---------------------------------------------------------------------------
// Dual-output KV GEMM body (M-tile 64): packed bf16 (k | v<<16); optional Q.
// smem >= 25600 (35840 if HASQ)
// ---------------------------------------------------------------------------
template<int NSEG, bool HASQ>
__device__ __forceinline__ void mgemm_kv_body(char* smem, int bx,
              Seg s0, Seg s1,
              const short* __restrict__ Wk, const float* __restrict__ bk,
              const short* __restrict__ Wv, const float* __restrict__ bv,
              const short* __restrict__ Wq, const float* __restrict__ bq,
              short* __restrict__ Qd,
              unsigned* __restrict__ KV, int M, int Lb, const int* __restrict__ rmap)
{
    short (*As)[40] = (short (*)[40])smem;
    short (*Bk_)[40] = (short (*)[40])(smem + 5120);
    short (*Bv_)[40] = (short (*)[40])(smem + 15360);
    short (*Bq_)[40] = (short (*)[40])(smem + 25600);
    const int bm = bx * 64;
    const int tid = threadIdx.x;
    const int wv = tid >> 6;
    const int lane = tid & 63;
    const int quad = lane >> 4;
    const int l16 = lane & 15;
    const int K = NSEG * 128;
    floatx4 acck[8], accv[8], accq[8];
    #pragma unroll
    for (int j = 0; j < 8; j++) {
        acck[j] = (floatx4){0.f,0.f,0.f,0.f};
        accv[j] = (floatx4){0.f,0.f,0.f,0.f};
        if (HASQ) accq[j] = (floatx4){0.f,0.f,0.f,0.f};
    }

    const int arow = tid >> 2;
    const int acol = (tid & 3) * 8;
    const int brow = tid >> 1;
    const int bcol = (tid & 1) * 16;
    int gmc = bm + arow; if (gmc > M-1) gmc = M-1;
    const short* rowp0 = seg_row(s0, gmc, Lb);
    const short* rowp1 = (NSEG > 1) ? seg_row(s1, gmc, Lb) : nullptr;

    for (int k0 = 0; k0 < K; k0 += 32) {
        {
            const short* rp = (NSEG == 1) ? rowp0 : ((k0 < 128) ? rowp0 : rowp1);
            const int ks = k0 & 127;
            *(short8*)&As[arow][acol] = *(const short8*)(rp + ks + acol);
        }
        {
            const short* sk = Wk + (size_t)brow*K + k0 + bcol;
            *(short8*)&Bk_[brow][bcol]   = *(const short8*)(sk);
            *(short8*)&Bk_[brow][bcol+8] = *(const short8*)(sk+8);
            const short* sv = Wv + (size_t)brow*K + k0 + bcol;
            *(short8*)&Bv_[brow][bcol]   = *(const short8*)(sv);
            *(short8*)&Bv_[brow][bcol+8] = *(const short8*)(sv+8);
            if (HASQ) {
                const short* sq = Wq + (size_t)brow*K + k0 + bcol;
                *(short8*)&Bq_[brow][bcol]   = *(const short8*)(sq);
                *(short8*)&Bq_[brow][bcol+8] = *(const short8*)(sq+8);
            }
        }
        __syncthreads();
        short8 af = *(short8*)&As[wv*16 + l16][quad*8];
        #pragma unroll
        for (int nf = 0; nf < 8; nf++) {
            short8 bfk = *(short8*)&Bk_[nf*16 + l16][quad*8];
            acck[nf] = __builtin_amdgcn_mfma_f32_16x16x32_bf16(af, bfk, acck[nf], 0, 0, 0);
            short8 bfv = *(short8*)&Bv_[nf*16 + l16][quad*8];
            accv[nf] = __builtin_amdgcn_mfma_f32_16x16x32_bf16(af, bfv, accv[nf], 0, 0, 0);
            if (HASQ) {
                short8 bfq = *(short8*)&Bq_[nf*16 + l16][quad*8];
                accq[nf] = __builtin_amdgcn_mfma_f32_16x16x32_bf16(af, bfq, accq[nf], 0, 0, 0);
            }
        }
        __syncthreads();
    }
    #pragma unroll
    for (int r = 0; r < 4; r++) {
        int gm = bm + wv*16 + quad*4 + r;
        if (gm < M) {
            int orow = rmap ? rmap[gm] : gm;
            #pragma unroll
            for (int nf = 0; nf < 8; nf++) {
                int gn = nf*16 + l16;
                float kf = acck[nf][r] + bk[gn];
                float vf = accv[nf][r] + bv[gn];
                unsigned pk = (unsigned)(unsigned short)f2bf(kf)
                            | ((unsigned)(unsigned short)f2bf(vf) << 16);
                KV[(size_t)orow*NKD + gn] = pk;
                if (HASQ) Qd[(size_t)gm*NKD + gn] = f2bf(accq[nf][r] + bq[gn]);
            }
        }
    }
}

// ---------------------------------------------------------------------------
// Segmented attention body on packed bf16 KV, bf16 q/o. SPLIT waves/(b,q,h).
// ---------------------------------------------------------------------------
template<int SPLIT>
__device__ __forceinline__ void sattn_body(int bx,
                  const short* __restrict__ q, const unsigned* __restrict__ kvb,
                  short* __restrict__ o, int nq, int nkv,
                  const int* __restrict__ lo_arr, const int* __restrict__ hi_arr)
{
    __shared__ float sm_m[4], sm_s[4], sm_a[4][DH];
    const int wvid = threadIdx.x >> 6;
    int gtask = bx * 4 + wvid;
    int task = gtask / SPLIT;
    int part = gtask % SPLIT;
    if (task >= NB * nq * NHD) return;
    const int h = task & 3;
    const int bq = task >> 2;
    const int qi = bq % nq;
    const int b = bq / nq;
    const int lane = threadIdx.x & 63;
    const int d = lane & 31;
    const int half = lane >> 5;
    int lo = lo_arr ? lo_arr[b*nq + qi] : 0;
    int hi = hi_arr ? hi_arr[b*nq + qi] : nkv;
    if (SPLIT == 2) {
        int mid = lo + ((hi - lo + 1) >> 1);
        if (part == 0) hi = mid; else lo = mid;
    }
    const float scale = 0.088388347648318447f;   // 1/sqrt(128)

    const float qv = bfs2f(q[((size_t)(b*nq + qi))*NKD + h*DH + d]);
    const unsigned* kb = kvb + (size_t)b*nkv*NKD + h*DH + d;

    float m = -INFINITY, ssum = 0.f, acc = 0.f;
    for (int l0 = lo; l0 < hi; l0 += 8) {
        unsigned ur[4];
        #pragma unroll
        for (int j = 0; j < 4; j++) {
            int l = l0 + 2*j + half;
            bool ok = (l < hi);
            ur[j] = ok ? kb[(size_t)l*NKD] : 0u;
        }
        #pragma unroll
        for (int j = 0; j < 4; j++) {
            int l = l0 + 2*j + half;
            float kr = bf2f(ur[j] & 0xffffu);
            float vr = bf2f(ur[j] >> 16);
            float partial = qv * kr;
            #pragma unroll
            for (int off = 16; off; off >>= 1) partial += __shfl_xor(partial, off);
            float s = partial * scale;
            if (l < hi) {
                float mn = fmaxf(m, s);
                float corr = __expf(m - mn);
                float p = __expf(s - mn);
                ssum = ssum * corr + p;
                acc  = acc  * corr + p * vr;
                m = mn;
            }
        }
    }
    float mo = __shfl_xor(m, 32);
    float M = fmaxf(m, mo);
    float corr = (m > -1e30f) ? __expf(m - M) : 0.f;
    ssum *= corr; acc *= corr;
    ssum += __shfl_xor(ssum, 32);
    acc  += __shfl_xor(acc, 32);

    if (SPLIT == 1) {
        if (half == 0) {
            float res = (ssum > 0.f) ? acc / ssum : 0.f;
            o[((size_t)(b*nq + qi))*NKD + h*DH + d] = f2bf(qv + res);
        }
    } else {
        if (lane == 0) { sm_m[wvid] = M; sm_s[wvid] = ssum; }
        if (lane < DH) sm_a[wvid][lane] = acc;
        __syncthreads();
        if (part == 0 && lane < DH) {
            float m2 = sm_m[wvid+1], s2 = sm_s[wvid+1], a2 = sm_a[wvid+1][lane];
            float M2 = fmaxf(M, m2);
            float c1 = (M  > -1e30f) ? __expf(M  - M2) : 0.f;
            float c2 = (m2 > -1e30f) ? __expf(m2 - M2) : 0.f;
            float S = ssum * c1 + s2 * c2;
            float A = acc  * c1 + a2 * c2;
            float res = (S > 0.f) ? A / S : 0.f;
            float qv2 = bfs2f(q[((size_t)(b*nq + qi))*NKD + h*DH + lane]);
            o[((size_t)(b*nq + qi))*NKD + h*DH + lane] = f2bf(qv2 + res);
        }
    }
}

// ===========================================================================
// Kernels
// ===========================================================================

// Pre-phase 1: compactA + zero_ranges + initT + initC + prep_weights
__global__ __launch_bounds__(256)
void k_pre1(const float* maskp, int* chunkcnt, int* lo_t, int* hi_t,
            const float* cx, const float* tw, const float* tb, short* T,
            const float* cw, const float* cb, short* C,
            const float* ctq, const float* ctk, const float* ctv, const float* cto,
            const float* tcq, const float* tck, const float* tcv, const float* tco,
            const float* caq, const float* cak, const float* cav, const float* cao,
            const float* enw, short* arena)
{
    int bx = blockIdx.x;
    if (bx < NB*NCH)            compactA_body(bx, maskp, chunkcnt);
    else if (bx < NB*NCH + 16)  zero_body(bx - NB*NCH, lo_t, hi_t);
    else if (bx < NB*NCH + 16 + 256) initT_body(bx - NB*NCH - 16, cx, tw, tb, T);
    else if (bx < NB*NCH + 16 + 256 + 42) initC_body(bx - NB*NCH - 16 - 256, cw, cb, C);
    else prepw_body(bx - NB*NCH - 16 - 256 - 42,
                    ctq, ctk, ctv, cto, tcq, tck, tcv, tco,
                    caq, cak, cav, cao, enw, arena);
}

__global__ __launch_bounds__(64)
void k_compactB(const int* __restrict__ chunkcnt, int* __restrict__ chunkoff,
                int* __restrict__ cntb)
{
    const int b = blockIdx.x, lane = threadIdx.x;
    int v = (lane < NCH) ? chunkcnt[b*NCH + lane] : 0;
    int x = v;
    #pragma unroll
    for (int off = 1; off < 64; off <<= 1) {
        int y = __shfl_up(x, off);
        if (lane >= off) x += y;
    }
    if (lane < NCH) chunkoff[b*NCH + lane] = x - v;
    if (lane == 63) cntb[b] = x;
}

__global__ __launch_bounds__(256)
void k_compactC(const float* __restrict__ cx, const float* __restrict__ value,
              const float* __restrict__ maskp, const float* __restrict__ tval,
              const float* __restrict__ tmaskp, const float* __restrict__ w0p,
              const float* __restrict__ b0p,
              const int* __restrict__ chunkoff, const int* __restrict__ cntb, int L,
              int* __restrict__ tind, int* __restrict__ cind,
              float* __restrict__ mkb, float* __restrict__ uval,
              float* __restrict__ uind,
              float* __restrict__ outTU, float* __restrict__ outTM)
{
    const int blk = blockIdx.x;
    const int b = blk / NCH, ch = blk % NCH;
    const int tid = threadIdx.x, lane = tid & 63, wv = tid >> 6;
    const int idx = ch * 256 + tid;
    const int s = idx / NDV, c = idx % NDV;
    float mval = (c < DIMV) ? maskp[((size_t)b*SS + s)*DIMV + c] : 1.0f;
    int m = (mval != 0.0f) ? 1 : 0;
    int x = m;
    #pragma unroll
    for (int off = 1; off < 64; off <<= 1) {
        int y = __shfl_up(x, off);
        if (lane >= off) x += y;
    }
    __shared__ int wsum[4];
    if (lane == 63) wsum[wv] = x;
    __syncthreads();
    int wbase = 0;
    for (int w = 0; w < wv; w++) wbase += wsum[w];
    const int excl = x - m + wbase;
    const int vbefore = chunkoff[b*NCH + ch] + excl;
    const int cnt = cntb[b];
    const int pos = m ? vbefore : (cnt + (idx - vbefore));
    if (pos < L) {
        const float w0 = w0p[0], b0 = b0p[0];
        float te = w0 * cx[(size_t)b*SS + s] + b0;
        float vf, tvf, tmf;
        if (c < DIMV) {
            size_t o = ((size_t)b*SS + s)*DIMV + c;
            vf = value[o]; tvf = tval[o]; tmf = tmaskp[o];
        } else { vf = te; tvf = te; tmf = 0.0f; }
        size_t p = (size_t)b*L + pos;
        if (m) {
            tind[p] = s; cind[p] = c; mkb[p] = 1.0f;
            uval[p] = vf; uind[p] = tmf;
            outTU[p] = tvf; outTM[p] = tmf;
        } else {
            tind[p] = -1; cind[p] = -1; mkb[p] = 0.0f;
            uval[p] = 0.0f; uind[p] = 1.0f;
            outTU[p] = 0.0f; outTM[p] = 0.0f;
        }
    }
}

// Pre-phase 4: trange + cperm + initU
__global__ __launch_bounds__(256)
void k_pre4(const int* tind, int* lo_t, int* hi_t, int L, int gTr,
            const int* cind, int* invp, int* clo, int* chi,
            const float* uval, const float* uind, const float* mkb,
            const float* ew, const float* eb, short* U, int BL)
{
    int bx = blockIdx.x;
    if (bx < gTr) trange_body(bx, tind, lo_t, hi_t, L);
    else if (bx < gTr + NB) cperm_body(bx - gTr, cind, invp, clo, chi, L);
    else initU_body(bx - gTr - NB, uval, uind, mkb, ew, eb, U, BL);
}

// Phase 1: ct-kv + ct-q + tc-kv + tc-q
__global__ __launch_bounds__(256)
void k_phase1(int g0, int g1, int g2,
              const short* T1, const int* tind, const short* U,
              const short* wkct, const float* bkct, const short* wvct, const float* bvct,
              unsigned* KVct, const int* invp,
              const short* C1, const short* wqct, const float* bqct, short* qC,
              const int* cind,
              const short* wktc, const float* bktc, const short* wvtc, const float* bvtc,
              unsigned* KVtc,
              const short* wqtc, const float* bqtc, short* qT,
              int BL, int L)
{
    __shared__ __align__(16) char smem[25600];
    int bx = blockIdx.x;
    if (bx < g0) {
        mgemm_kv_body<2,false>(smem, bx, Seg{T1,tind,SS}, Seg{U,nullptr,0},
            wkct, bkct, wvct, bvct, nullptr, nullptr, nullptr, KVct, BL, L, invp);
    } else if (bx < g0+g1) {
        mgemm_body<1,0>(smem, bx-g0, Seg{C1,nullptr,0}, Seg{nullptr,nullptr,0},
            Seg{nullptr,nullptr,0}, wqct, bqct, qC, NB*NDV, 1, nullptr);
    } else if (bx < g0+g1+g2) {
        mgemm_kv_body<2,false>(smem, bx-g0-g1, Seg{C1,cind,NDV}, Seg{U,nullptr,0},
            wktc, bktc, wvtc, bvtc, nullptr, nullptr, nullptr, KVtc, BL, L, nullptr);
    } else {
        mgemm_body<1,0>(smem, bx-g0-g1-g2, Seg{T1,nullptr,0}, Seg{nullptr,nullptr,0},
            Seg{nullptr,nullptr,0}, wqtc, bqtc, qT, NB*SS, 1, nullptr);
    }
}

// Phase 2: sattn ct + sattn tc
__global__ __launch_bounds__(256)
void k_phase2(int g0, const short* qC, const unsigned* KVct, short* oC,
              const int* clo, const int* chi, int L,
              const short* qT, const unsigned* KVtc, short* oT,
              const int* lo_t, const int* hi_t)
{
    int bx = blockIdx.x;
    if (bx < g0) sattn_body<2>(bx, qC, KVct, oC, NDV, L, clo, chi);
    else         sattn_body<1>(bx-g0, qT, KVtc, oT, SS, L, lo_t, hi_t);
}

// Phase 3: o-proj ct (-> C2) + o-proj tc (-> T2) + en (-> Unew)
__global__ __launch_bounds__(256)
void k_phase3(int g0, int g1,
              const short* oC, const short* woct, const float* boct, short* C2,
              const short* oT, const short* wotc, const float* botc, short* T2b,
              const short* U, const short* T1, const int* tind,
              const short* C1, const int* cind,
              const short* wen, const float* ben, short* Unew, const float* mkb,
              int BL, int L)
{
    __shared__ __align__(16) char smem[20480];
    int bx = blockIdx.x;
    if (bx < g0)
        mgemm_body<1,2>(smem, bx, Seg{oC,nullptr,0}, Seg{nullptr,nullptr,0},
            Seg{nullptr,nullptr,0}, woct, boct, C2, NB*NDV, 1, nullptr);
    else if (bx < g0+g1)
        mgemm_body<1,2>(smem, bx-g0, Seg{oT,nullptr,0}, Seg{nullptr,nullptr,0},
            Seg{nullptr,nullptr,0}, wotc, botc, T2b, NB*SS, 1, nullptr);
    else
        mgemm_body<3,3>(smem, bx-g0-g1, Seg{U,nullptr,0}, Seg{T1,tind,SS},
            Seg{C1,cind,NDV}, wen, ben, Unew, BL, L, mkb);
}

// ca phases
__global__ __launch_bounds__(256)
void k_ca_kvq(const short* C2, const short* wk, const float* bk,
              const short* wv, const float* bv, const short* wq, const float* bq,
              short* qC, unsigned* KV)
{
    __shared__ __align__(16) char smem[35840];
    mgemm_kv_body<1,true>(smem, blockIdx.x, Seg{C2,nullptr,0}, Seg{nullptr,nullptr,0},
                          wk, bk, wv, bv, wq, bq, qC, KV, NB*NDV, 1, nullptr);
}

__global__ __launch_bounds__(256)
void k_ca_attn(const short* qC, const unsigned* kv, short* oC)
{
    sattn_body<2>(blockIdx.x, qC, kv, oC, NDV, NDV, nullptr, nullptr);
}

__global__ __launch_bounds__(256)
void k_ca_oproj(const short* oC, const short* wo, const float* bo, short* C1)
{
    __shared__ __align__(16) char smem[20480];
    mgemm_body<1,2>(smem, blockIdx.x, Seg{oC,nullptr,0}, Seg{nullptr,nullptr,0},
                    Seg{nullptr,nullptr,0}, wo, bo, C1, NB*NDV, 1, nullptr);
}

// Final head with inline gathers of k_t, k_c (bf16 inputs)
__global__ __launch_bounds__(256)
void k_out(const short* __restrict__ U, const short* __restrict__ T1,
           const short* __restrict__ C1, const int* __restrict__ tind,
           const int* __restrict__ cind, const float* __restrict__ ow,
           const float* __restrict__ obp, float* __restrict__ out,
           int BL, int L)
{
    int row = blockIdx.x * 4 + (threadIdx.x >> 6);
    int lane = threadIdx.x & 63;
    if (row >= BL) return;
    int b = row / L;
    int ti = tind[row]; if (ti < 0) ti = 0;
    int ci = cind[row]; if (ci < 0) ci = 0;
    const short* u = U + (size_t)row*NKD;
    const short* a = T1 + ((size_t)(b*SS + ti))*NKD;
    const short* c = C1 + ((size_t)(b*NDV + ci))*NKD;
    float s = bfs2f(u[lane])*ow[lane]     + bfs2f(u[lane+64])*ow[lane+64]
            + bfs2f(a[lane])*ow[128+lane] + bfs2f(a[lane+64])*ow[192+lane]
            + bfs2f(c[lane])*ow[256+lane] + bfs2f(c[lane+64])*ow[320+lane];
    #pragma unroll
    for (int off = 32; off; off >>= 1) s += __shfl_down(s, off);
    if (lane == 0) out[row] = s + obp[0];
}

// ---------------------------------------------------------------------------
extern "C" void kernel_launch(void* const* d_in, const int* in_sizes, int n_in,
                              void* d_out, int out_size, void* d_ws, size_t ws_size,
                              hipStream_t stream)
{
    const float* cx     = (const float*)d_in[0];
    const float* value  = (const float*)d_in[1];
    const float* maskp  = (const float*)d_in[2];
    const float* tval   = (const float*)d_in[3];
    const float* tmaskp = (const float*)d_in[4];
    const float* w0     = (const float*)d_in[5];
    const float* b0     = (const float*)d_in[6];
    const float* edge_w = (const float*)d_in[7];
    const float* edge_b = (const float*)d_in[8];
    const float* chan_w = (const float*)d_in[9];
    const float* chan_b = (const float*)d_in[10];
    const float* time_w = (const float*)d_in[11];
    const float* time_b = (const float*)d_in[12];
    const float* ct_wq = (const float*)d_in[13];
    const float* ct_bq = (const float*)d_in[14];
    const float* ct_wk = (const float*)d_in[15];
    const float* ct_bk = (const float*)d_in[16];
    const float* ct_wv = (const float*)d_in[17];
    const float* ct_bv = (const float*)d_in[18];
    const float* ct_wo = (const float*)d_in[19];
    const float* ct_bo = (const float*)d_in[20];
    const float* tc_wq = (const float*)d_in[21];
    const float* tc_bq = (const float*)d_in[22];
    const float* tc_wk = (const float*)d_in[23];
    const float* tc_bk = (const float*)d_in[24];
    const float* tc_wv = (const float*)d_in[25];
    const float* tc_bv = (const float*)d_in[26];
    const float* tc_wo = (const float*)d_in[27];
    const float* tc_bo = (const float*)d_in[28];
    const float* ca_wq = (const float*)d_in[29];
    const float* ca_bq = (const float*)d_in[30];
    const float* ca_wk = (const float*)d_in[31];
    const float* ca_bk = (const float*)d_in[32];
    const float* ca_wv = (const float*)d_in[33];
    const float* ca_bv = (const float*)d_in[34];
    const float* ca_wo = (const float*)d_in[35];
    const float* ca_bo = (const float*)d_in[36];
    const float* en_w  = (const float*)d_in[37];
    const float* en_b  = (const float*)d_in[38];
    const float* out_w = (const float*)d_in[39];
    const float* out_b = (const float*)d_in[40];

    const int BL = out_size / 3;     // B * full_len
    const int L  = BL / NB;

    char* p = (char*)d_ws;
    auto alloc = [&](size_t n) { char* r = p; p += (n + 255) & ~(size_t)255; return r; };
    int*      tind   = (int*)  alloc((size_t)BL*4);
    int*      cind   = (int*)  alloc((size_t)BL*4);
    float*    mkb    = (float*)alloc((size_t)BL*4);
    float*    uval   = (float*)alloc((size_t)BL*4);
    float*    uind   = (float*)alloc((size_t)BL*4);
    int*      lo_t   = (int*)  alloc((size_t)NB*SS*4);
    int*      hi_t   = (int*)  alloc((size_t)NB*SS*4);
    int*      clo    = (int*)  alloc((size_t)NB*NDV*4);
    int*      chi    = (int*)  alloc((size_t)NB*NDV*4);
    int*      invp   = (int*)  alloc((size_t)BL*4);
    int*      chunkc = (int*)  alloc((size_t)NB*NCH*4);
    int*      chunko = (int*)  alloc((size_t)NB*NCH*4);
    int*      cntb   = (int*)  alloc((size_t)NB*4);
    short*    waren  = (short*)alloc((size_t)W_TOTAL*2);
    short*    U    = (short*)alloc((size_t)BL*NKD*2);
    short*    Unew = (short*)alloc((size_t)BL*NKD*2);
    unsigned* KVct = (unsigned*)alloc((size_t)BL*NKD*4);
    unsigned* KVtc = (unsigned*)alloc((size_t)BL*NKD*4);
    unsigned* kvCa = (unsigned*)alloc((size_t)NB*NDV*NKD*4);
    short*    T1   = (short*)alloc((size_t)NB*SS*NKD*2);
    short*    T2b  = (short*)alloc((size_t)NB*SS*NKD*2);
    short*    qT   = (short*)alloc((size_t)NB*SS*NKD*2);
    short*    oT   = (short*)alloc((size_t)NB*SS*NKD*2);
    short*    C1   = (short*)alloc((size_t)NB*NDV*NKD*2);
    short*    C2   = (short*)alloc((size_t)NB*NDV*NKD*2);
    short*    qC   = (short*)alloc((size_t)NB*NDV*NKD*2);
    short*    oC   = (short*)alloc((size_t)NB*NDV*NKD*2);

    float* outMain = (float*)d_out;
    float* outTU = outMain + BL;
    float* outTM = outMain + 2*BL;

    // weight arena offsets (shorts)
    const size_t OCTQ=0, OCTK=49152, OCTV=147456, OCTO=245760;
    const size_t OTCQ=294912, OTCK=344064, OTCV=442368, OTCO=540672;
    const size_t OCAQ=589824, OCAK=638976, OCAV=688128, OCAO=737280, OEN=786432;

    // Pre-phases (4 dispatches)
    k_pre1<<<NB*NCH + 16 + 256 + 42 + W_TOTAL/256, 256, 0, stream>>>(
        maskp, chunkc, lo_t, hi_t, cx, time_w, time_b, T1, chan_w, chan_b, C1,
        ct_wq, ct_wk, ct_wv, ct_wo, tc_wq, tc_wk, tc_wv, tc_wo,
        ca_wq, ca_wk, ca_wv, ca_wo, en_w, waren);
    k_compactB<<<NB, 64, 0, stream>>>(chunkc, chunko, cntb);
    k_compactC<<<NB*NCH, 256, 0, stream>>>(cx, value, maskp, tval, tmaskp, w0, b0,
                                           chunko, cntb, L, tind, cind, mkb, uval, uind,
                                           outTU, outTM);
    {
        const int gTr = (NB*L + 255)/256;
        const int gU  = (BL*16 + 255)/256;
        k_pre4<<<gTr + NB + gU, 256, 0, stream>>>(
            tind, lo_t, hi_t, L, gTr, cind, invp, clo, chi,
            uval, uind, mkb, edge_w, edge_b, U, BL);
    }

    const int gBL  = (BL + 127)/128;
    const int gKV  = (BL + 63)/64;
    const int gC   = (NB*NDV + 127)/128;
    const int gT   = (NB*SS + 127)/128;
    const int gCa  = (NB*NDV + 63)/64;
    const int aC2  = NB*NDV*NHD*2/4;     // SPLIT=2
    const int aTC  = NB*SS*NHD/4;        // SPLIT=1

    for (int i = 0; i < NLAY; i++) {
        const size_t bOff = (size_t)i*NKD;
        const short* wq_ct = waren + OCTQ + (size_t)i*128*128;
        const short* wk_ct = waren + OCTK + (size_t)i*256*128;
        const short* wv_ct = waren + OCTV + (size_t)i*256*128;
        const short* wo_ct = waren + OCTO + (size_t)i*128*128;
        const short* wq_tc = waren + OTCQ + (size_t)i*128*128;
        const short* wk_tc = waren + OTCK + (size_t)i*256*128;
        const short* wv_tc = waren + OTCV + (size_t)i*256*128;
        const short* wo_tc = waren + OTCO + (size_t)i*128*128;
        const short* wq_ca = waren + OCAQ + (size_t)i*128*128;
        const short* wk_ca = waren + OCAK + (size_t)i*128*128;
        const short* wv_ca = waren + OCAV + (size_t)i*128*128;
        const short* wo_ca = waren + OCAO + (size_t)i*128*128;
        const short* w_en  = waren + OEN  + (size_t)i*384*128;

        // P1: q/kv projections from (T1, C1, U)
        k_phase1<<<gKV + gC + gKV + gT, 256, 0, stream>>>(
            gKV, gC, gKV,
            T1, tind, U,
            wk_ct, ct_bk + bOff, wv_ct, ct_bv + bOff, KVct, invp,
            C1, wq_ct, ct_bq + bOff, qC,
            cind, wk_tc, tc_bk + bOff, wv_tc, tc_bv + bOff, KVtc,
            wq_tc, tc_bq + bOff, qT, BL, L);
        // P2: both segmented attentions
        k_phase2<<<aC2 + aTC, 256, 0, stream>>>(
            aC2, qC, KVct, oC, clo, chi, L, qT, KVtc, oT, lo_t, hi_t);
        // P3: both o-projections + en update
        k_phase3<<<gC + gT + gBL, 256, 0, stream>>>(
            gC, gT, oC, wo_ct, ct_bo + bOff, C2, oT, wo_tc, tc_bo + bOff, T2b,
            U, T1, tind, C1, cind, w_en, en_b + bOff, Unew, mkb, BL, L);
        // P4-P6: channel self-attention
        k_ca_kvq<<<gCa, 256, 0, stream>>>(C2, wk_ca, ca_bk + bOff,
            wv_ca, ca_bv + bOff, wq_ca, ca_bq + bOff, qC, kvCa);
        k_ca_attn<<<aC2, 256, 0, stream>>>(qC, kvCa, oC);
        k_ca_oproj<<<gC, 256, 0, stream>>>(oC, wo_ca, ca_bo + bOff, C1);

        short* t = U;  U = Unew; Unew = t;
        t = T1; T1 = T2b; T2b = t;
    }

    k_out<<<(BL + 3)/4, 256, 0, stream>>>(U, T1, C1, tind, cind,
                                          out_w, out_b, outMain, BL, L);
}